// Round 2
// baseline (1169.518 us; speedup 1.0000x reference)
//
#include <hip/hip_runtime.h>
#include <hip/hip_bf16.h>

#define B_TOK 16384
#define IN_DIM 128
#define D_DIM 512
#define DEPTH 3
#define NEXP 8
#define FF_DIM 2048
#define EH_DIM 256
#define MAXSLOT 33792   // 32768 + 8*127 rounded to 128
#define MAXTILE 264     // MAXSLOT/128

typedef __attribute__((ext_vector_type(8))) __bf16 bf16x8;
typedef __attribute__((ext_vector_type(4))) float f32x4;
typedef __attribute__((ext_vector_type(4))) unsigned short u16x4;
typedef __attribute__((ext_vector_type(8))) unsigned short u16x8;

__device__ __forceinline__ unsigned short f2bf(float f){
    unsigned int u = __float_as_uint(f);
    u += 0x7fffu + ((u >> 16) & 1u);
    return (unsigned short)(u >> 16);
}
__device__ __forceinline__ float bf2f(unsigned short u){
    return __uint_as_float(((unsigned int)u) << 16);
}
__device__ __forceinline__ float geluf(float x){
    return 0.5f * x * (1.0f + erff(x * 0.70710678118654752f));
}
__device__ __forceinline__ void gload_lds16(const void* g, void* l){
    __builtin_amdgcn_global_load_lds((const __attribute__((address_space(1))) unsigned int*)g,
                                     (__attribute__((address_space(3))) unsigned int*)l,
                                     16, 0, 0);
}

// ---------------- zero scratch control state ------------------------------
__global__ void zero_kernel(int* a, int na, int* b, int nb){
    const int i = blockIdx.x * blockDim.x + threadIdx.x;
    if (i < na) a[i] = 0;
    if (i < nb) b[i] = 0;
}

// ---------------- fp32 -> bf16 convert ------------------------------------
struct ConvSeg { const float* src; unsigned short* dst; int n4; };
struct ConvArgs { ConvSeg seg[2]; };

__global__ void convert_kernel(ConvArgs a){
    const int stride = gridDim.x * blockDim.x;
    const int tid = blockIdx.x * blockDim.x + threadIdx.x;
    for (int s = 0; s < 2; ++s){
        const f32x4* src = (const f32x4*)a.seg[s].src;
        u16x4* dst = (u16x4*)a.seg[s].dst;
        const int n4 = a.seg[s].n4;
        for (int i = tid; i < n4; i += stride){
            f32x4 v = src[i];
            u16x4 o;
            o[0] = f2bf(v[0]); o[1] = f2bf(v[1]); o[2] = f2bf(v[2]); o[3] = f2bf(v[3]);
            dst[i] = o;
        }
    }
}

// ------------- weight transpose-convert: (K,N) fp32 -> (N,K) bf16 ---------
struct TSeg { const float* src; unsigned short* dst; int K; int N; int tileStart; };
struct TArgs { TSeg seg[26]; };

__global__ void transpose_kernel(TArgs a){
    __shared__ float t[32][33];
    const int tile = blockIdx.x;
    int s = 0;
    #pragma unroll 1
    while (s < 25 && tile >= a.seg[s+1].tileStart) ++s;
    const TSeg sg = a.seg[s];
    const int local = tile - sg.tileStart;
    const int tilesN = sg.N >> 5;
    const int k0 = (local / tilesN) << 5;
    const int n0 = (local % tilesN) << 5;
    const int tx = threadIdx.x & 31;
    const int ty = threadIdx.x >> 5;
    #pragma unroll
    for (int j = 0; j < 4; ++j)
        t[ty + j*8][tx] = sg.src[(size_t)(k0 + ty + j*8) * sg.N + n0 + tx];
    __syncthreads();
    #pragma unroll
    for (int j = 0; j < 4; ++j){
        const int n = ty + j*8;
        sg.dst[(size_t)(n0 + n) * sg.K + k0 + tx] = f2bf(t[tx][n]);
    }
}

// ---------------- folded attention bias: bfold = Wo@bv + bo ---------------
__global__ void foldb_kernel(const float* __restrict__ outproj_w, const float* __restrict__ outproj_b,
                             const float* __restrict__ inproj_b, float* __restrict__ bfold){
    const int l = blockIdx.x, n = threadIdx.x;
    const float* Wo = outproj_w + ((size_t)l*D_DIM + n)*D_DIM;
    const float* bv = inproj_b + l*3*D_DIM + 2*D_DIM;
    float acc = outproj_b[l*D_DIM + n];
    for (int j = 0; j < D_DIM; ++j) acc += Wo[j]*bv[j];
    bfold[l*D_DIM + n] = acc;
}

// ---------------- GEMM: C(M,N) = A(M,K) @ Bt(N,K)^T -----------------------
#define EPI_BF16 0
#define EPI_BF16_GELU 1
#define EPI_F32_BIAS 2
#define EPI_F32_RESID 3

template<int EPI>
__global__ void __launch_bounds__(256, 2)
gemm_bt(const unsigned short* __restrict__ A, const unsigned short* __restrict__ Bt,
        const float* __restrict__ bias, const float* __restrict__ resid,
        void* __restrict__ out, int M, int N, int K)
{
    __shared__ unsigned short sh[16384];
    unsigned short* Al = sh;
    unsigned short* Bl = sh + 8192;
    const int tid  = threadIdx.x;
    const int lane = tid & 63;
    const int wave = tid >> 6;
    const int wm = (wave >> 1) << 6;
    const int wn = (wave & 1) << 6;
    const int bm = blockIdx.y, bn = blockIdx.x;

    f32x4 acc[4][4] = {};

    const unsigned short* Abase = A + (size_t)bm * 128 * K;
    const unsigned short* Bbase = Bt + (size_t)bn * 128 * K;
    const int soff = tid * 16;

    for (int kt = 0; kt < K; kt += 64){
        #pragma unroll
        for (int s = 0; s < 4; ++s){
            const int off = s*4096 + soff;
            const int row = off >> 7, colb = off & 127;
            gload_lds16((const char*)(Abase + (size_t)row*K + kt) + colb, (char*)Al + off);
        }
        #pragma unroll
        for (int s = 0; s < 4; ++s){
            const int off = s*4096 + soff;
            const int row = off >> 7, colb = off & 127;
            gload_lds16((const char*)(Bbase + (size_t)row*K + kt) + colb, (char*)Bl + off);
        }
        __syncthreads();
        #pragma unroll
        for (int ks = 0; ks < 2; ++ks){
            const int k0 = ks*32 + ((lane>>4)<<3);
            bf16x8 af[4], bfr[4];
            #pragma unroll
            for (int i=0;i<4;i++) af[i]  = *(const bf16x8*)&Al[(wm + i*16 + (lane&15))*64 + k0];
            #pragma unroll
            for (int j=0;j<4;j++) bfr[j] = *(const bf16x8*)&Bl[(wn + j*16 + (lane&15))*64 + k0];
            #pragma unroll
            for (int i=0;i<4;i++)
                #pragma unroll
                for (int j=0;j<4;j++)
                    acc[i][j] = __builtin_amdgcn_mfma_f32_16x16x32_bf16(af[i], bfr[j], acc[i][j], 0, 0, 0);
        }
        __syncthreads();
    }

    const int r0 = ((lane>>4)<<2);
    const int cc = lane & 15;

    if (EPI == EPI_F32_BIAS || EPI == EPI_F32_RESID){
        #pragma unroll
        for (int j=0;j<4;j++){
            const int col = bn*128 + wn + j*16 + cc;
            const float bv = bias[col];
            #pragma unroll
            for (int i=0;i<4;i++){
                #pragma unroll
                for (int r=0;r<4;r++){
                    const int row = bm*128 + wm + i*16 + r0 + r;
                    const size_t idx = (size_t)row * N + col;
                    float v = acc[i][j][r] + bv;
                    if (EPI == EPI_F32_BIAS) ((float*)out)[idx] = v;
                    else                     ((float*)out)[idx] = resid[idx] + v;
                }
            }
        }
    } else {
        // LDS-assembled coalesced bf16 store
        unsigned short* Ct = sh;   // 128x128 u16 (K-loop done, sh free)
        float bcol[4];
        #pragma unroll
        for (int j=0;j<4;j++) bcol[j] = bias[bn*128 + wn + j*16 + cc];
        #pragma unroll
        for (int i=0;i<4;i++){
            #pragma unroll
            for (int r=0;r<4;r++){
                const int rl = wm + i*16 + r0 + r;
                #pragma unroll
                for (int j=0;j<4;j++){
                    float v = acc[i][j][r] + bcol[j];
                    if (EPI == EPI_BF16_GELU) v = geluf(v);
                    Ct[rl*128 + wn + j*16 + cc] = f2bf(v);
                }
            }
        }
        __syncthreads();
        const int orow = tid >> 4;
        const int ocol = (tid & 15) * 8;
        unsigned short* op = (unsigned short*)out;
        #pragma unroll
        for (int p = 0; p < 8; ++p){
            const int row = p*16 + orow;
            *(u16x4*)(&op[(size_t)(bm*128 + row)*N + bn*128 + ocol])     = *(u16x4*)&Ct[row*128 + ocol];
            *(u16x4*)(&op[(size_t)(bm*128 + row)*N + bn*128 + ocol + 4]) = *(u16x4*)&Ct[row*128 + ocol + 4];
        }
    }
}

// ---------------- MoE GEMM over compacted slot space ----------------------
#define MEPI_GELU 0
#define MEPI_GATED 1

template<int MEPI, int INDIRECT>
__global__ void __launch_bounds__(256, 2)
gemm_moe(const unsigned short* __restrict__ A, const int* __restrict__ tok,
         const int* __restrict__ offs, const unsigned short* __restrict__ wbase,
         int wstride, const float* __restrict__ bbase, int bstride,
         const float* __restrict__ gslot, unsigned short* __restrict__ out,
         int N, int K)
{
    __shared__ unsigned short sh[16384];
    unsigned short* Al = sh;
    unsigned short* Bl = sh + 8192;
    const int tid  = threadIdx.x;
    const int lane = tid & 63;
    const int wave = tid >> 6;
    const int wm = (wave >> 1) << 6;
    const int wn = (wave & 1) << 6;
    const int bm = blockIdx.y, bn = blockIdx.x;
    const int m0 = bm * 128;
    if (m0 >= offs[8]) return;
    int e = 0;
    #pragma unroll 1
    while (offs[e+1] <= m0) ++e;

    const unsigned short* Bt = wbase + (size_t)e*wstride;
    const float* bias = bbase + (size_t)e*bstride;

    f32x4 acc[4][4] = {};
    const int soff = tid * 16;

    // per-thread A row base pointers (indirect for e1: gather tokens)
    const unsigned short* Arow[4];
    int colb_[4];
    #pragma unroll
    for (int s = 0; s < 4; ++s){
        const int off = s*4096 + soff;
        const int row = off >> 7;
        colb_[s] = off & 127;
        if (INDIRECT){
            const int t = tok[m0 + row];
            Arow[s] = A + (size_t)t*K;
        } else {
            Arow[s] = A + (size_t)(m0 + row)*K;
        }
    }
    const unsigned short* Bbase = Bt + (size_t)bn * 128 * K;

    for (int kt = 0; kt < K; kt += 64){
        #pragma unroll
        for (int s = 0; s < 4; ++s){
            const int off = s*4096 + soff;
            gload_lds16((const char*)(Arow[s] + kt) + colb_[s], (char*)Al + off);
        }
        #pragma unroll
        for (int s = 0; s < 4; ++s){
            const int off = s*4096 + soff;
            const int row = off >> 7, colb = off & 127;
            gload_lds16((const char*)(Bbase + (size_t)row*K + kt) + colb, (char*)Bl + off);
        }
        __syncthreads();
        #pragma unroll
        for (int ks = 0; ks < 2; ++ks){
            const int k0 = ks*32 + ((lane>>4)<<3);
            bf16x8 af[4], bfr[4];
            #pragma unroll
            for (int i=0;i<4;i++) af[i]  = *(const bf16x8*)&Al[(wm + i*16 + (lane&15))*64 + k0];
            #pragma unroll
            for (int j=0;j<4;j++) bfr[j] = *(const bf16x8*)&Bl[(wn + j*16 + (lane&15))*64 + k0];
            #pragma unroll
            for (int i=0;i<4;i++)
                #pragma unroll
                for (int j=0;j<4;j++)
                    acc[i][j] = __builtin_amdgcn_mfma_f32_16x16x32_bf16(af[i], bfr[j], acc[i][j], 0, 0, 0);
        }
        __syncthreads();
    }

    const int r0 = ((lane>>4)<<2);
    const int cc = lane & 15;
    unsigned short* Ct = sh;
    float bcol[4];
    #pragma unroll
    for (int j=0;j<4;j++) bcol[j] = bias[bn*128 + wn + j*16 + cc];
    #pragma unroll
    for (int i=0;i<4;i++){
        #pragma unroll
        for (int r=0;r<4;r++){
            const int rl = wm + i*16 + r0 + r;
            float g = 1.0f;
            if (MEPI == MEPI_GATED) g = gslot[m0 + rl];
            #pragma unroll
            for (int j=0;j<4;j++){
                float v = acc[i][j][r] + bcol[j];
                if (MEPI == MEPI_GELU) v = geluf(v);
                else                   v = v * g;
                Ct[rl*128 + wn + j*16 + cc] = f2bf(v);
            }
        }
    }
    __syncthreads();
    const int orow = tid >> 4;
    const int ocol = (tid & 15) * 8;
    #pragma unroll
    for (int p = 0; p < 8; ++p){
        const int row = p*16 + orow;
        *(u16x4*)(&out[(size_t)(m0 + row)*N + bn*128 + ocol])     = *(u16x4*)&Ct[row*128 + ocol];
        *(u16x4*)(&out[(size_t)(m0 + row)*N + bn*128 + ocol + 4]) = *(u16x4*)&Ct[row*128 + ocol + 4];
    }
}

// ---------------- LayerNorm (fp32 in, bf16 out), one wave per row ---------
__global__ void ln_kernel(const float* __restrict__ x, const float* __restrict__ w,
                          const float* __restrict__ b, unsigned short* __restrict__ out)
{
    const int lane = threadIdx.x & 63;
    const int wave = threadIdx.x >> 6;
    const int row  = blockIdx.x * 4 + wave;
    const float* xr = x + (size_t)row * D_DIM;
    f32x4 v0 = *(const f32x4*)(xr + lane*8);
    f32x4 v1 = *(const f32x4*)(xr + lane*8 + 4);
    float s  = v0[0]+v0[1]+v0[2]+v0[3] + v1[0]+v1[1]+v1[2]+v1[3];
    float s2 = v0[0]*v0[0]+v0[1]*v0[1]+v0[2]*v0[2]+v0[3]*v0[3]
             + v1[0]*v1[0]+v1[1]*v1[1]+v1[2]*v1[2]+v1[3]*v1[3];
    #pragma unroll
    for (int o = 32; o > 0; o >>= 1){ s += __shfl_xor(s, o); s2 += __shfl_xor(s2, o); }
    const float mean = s * (1.0f/512.0f);
    const float var  = s2 * (1.0f/512.0f) - mean*mean;
    const float inv  = 1.0f / sqrtf(var + 1e-5f);
    const int k = lane*8;
    u16x4 o0, o1;
    #pragma unroll
    for (int j=0;j<4;j++) o0[j] = f2bf((v0[j]-mean)*inv*w[k+j]   + b[k+j]);
    #pragma unroll
    for (int j=0;j<4;j++) o1[j] = f2bf((v1[j]-mean)*inv*w[k+4+j] + b[k+4+j]);
    *(u16x4*)(out + (size_t)row*D_DIM + k)     = o0;
    *(u16x4*)(out + (size_t)row*D_DIM + k + 4) = o1;
}

// ------- Router: softmax+eps-mix+top2, emit zbf, counts, prob sums --------
__global__ void router_kernel(const float* __restrict__ z, const float* __restrict__ rw,
                              const float* __restrict__ rb, unsigned short* __restrict__ zbf,
                              int2* __restrict__ idx2, float2* __restrict__ wts2,
                              int* __restrict__ counts, float* __restrict__ bsums)
{
    __shared__ float ps[4][8];
    const int lane = threadIdx.x & 63;
    const int wave = threadIdx.x >> 6;
    const int row  = blockIdx.x * 4 + wave;
    const float* zr = z + (size_t)row * D_DIM;
    f32x4 z0 = *(const f32x4*)(zr + lane*8);
    f32x4 z1 = *(const f32x4*)(zr + lane*8 + 4);
    // write bf16 copy of z
    {
        u16x4 o0, o1;
        #pragma unroll
        for (int j=0;j<4;j++){ o0[j] = f2bf(z0[j]); o1[j] = f2bf(z1[j]); }
        *(u16x4*)(zbf + (size_t)row*D_DIM + lane*8)     = o0;
        *(u16x4*)(zbf + (size_t)row*D_DIM + lane*8 + 4) = o1;
    }
    float acc[8] = {0,0,0,0,0,0,0,0};
    #pragma unroll
    for (int j = 0; j < 8; ++j){
        const float zv = (j < 4) ? z0[j] : z1[j-4];
        const float* wr = rw + (size_t)(lane*8 + j) * 8;
        f32x4 w0 = *(const f32x4*)wr;
        f32x4 w1 = *(const f32x4*)(wr + 4);
        acc[0] += zv*w0[0]; acc[1] += zv*w0[1]; acc[2] += zv*w0[2]; acc[3] += zv*w0[3];
        acc[4] += zv*w1[0]; acc[5] += zv*w1[1]; acc[6] += zv*w1[2]; acc[7] += zv*w1[3];
    }
    #pragma unroll
    for (int o = 32; o > 0; o >>= 1){
        #pragma unroll
        for (int e = 0; e < 8; ++e) acc[e] += __shfl_xor(acc[e], o);
    }
    if (lane == 0){
        float p[8]; float mx = -1e30f;
        #pragma unroll
        for (int e=0;e<8;e++){ p[e] = acc[e] + rb[e]; mx = fmaxf(mx, p[e]); }
        float se = 0.f;
        #pragma unroll
        for (int e=0;e<8;e++){ p[e] = expf(p[e]-mx); se += p[e]; }
        const float sc = 0.9f / se;
        #pragma unroll
        for (int e=0;e<8;e++) p[e] = p[e]*sc + 0.0125f;
        int i1 = 0;
        #pragma unroll
        for (int e=1;e<8;e++) if (p[e] > p[i1]) i1 = e;
        int i2 = (i1 == 0) ? 1 : 0;
        for (int e=i2+1;e<8;e++) if (e != i1 && p[e] > p[i2]) i2 = e;
        idx2[row] = make_int2(i1, i2);
        wts2[row] = make_float2(p[i1], p[i2]);
        atomicAdd(&counts[i1], 1);
        atomicAdd(&counts[i2], 1);
        #pragma unroll
        for (int e=0;e<8;e++) ps[wave][e] = p[e];
    }
    __syncthreads();
    if (threadIdx.x < 8){
        bsums[blockIdx.x*8 + threadIdx.x] =
            ps[0][threadIdx.x] + ps[1][threadIdx.x] + ps[2][threadIdx.x] + ps[3][threadIdx.x];
    }
}

// ---------------- padded per-expert offsets -------------------------------
__global__ void offsets_kernel(const int* __restrict__ counts, int* __restrict__ offs){
    if (threadIdx.x == 0){
        int o = 0; offs[0] = 0;
        for (int e = 0; e < 8; ++e){ o += (counts[e] + 127) & ~127; offs[e+1] = o; }
    }
}

// ---------------- slot assignment -----------------------------------------
__global__ void gather_kernel(const int2* __restrict__ idx2, const float2* __restrict__ wts2,
                              const int* __restrict__ offs, int* __restrict__ cursor,
                              int2* __restrict__ slot_map, float* __restrict__ gslot,
                              int* __restrict__ tok)
{
    const int t = blockIdx.x * blockDim.x + threadIdx.x;
    if (t >= B_TOK) return;
    const int2 ii = idx2[t];
    const float2 ww = wts2[t];
    const int s1 = offs[ii.x] + atomicAdd(&cursor[ii.x], 1);
    const int s2 = offs[ii.y] + atomicAdd(&cursor[ii.y], 1);
    slot_map[t] = make_int2(s1, s2);
    gslot[s1] = ww.x; gslot[s2] = ww.y;
    tok[s1] = t; tok[s2] = t;
}

// ---------------- aux loss ------------------------------------------------
__global__ void aux_kernel(const float* __restrict__ bsums, float* __restrict__ out_aux)
{
    __shared__ float part[256];
    const int t = threadIdx.x;
    const int e = t & 7, chunk = t >> 3;
    float s = 0.f;
    for (int blk = chunk*128; blk < chunk*128 + 128; ++blk) s += bsums[blk*8 + e];
    part[t] = s;
    __syncthreads();
    if (t < 8){
        float tot = 0.f;
        for (int c = 0; c < 32; ++c) tot += part[c*8 + t];
        part[t] = tot;
    }
    __syncthreads();
    if (t == 0){
        float aux = 0.f;
        for (int e2 = 0; e2 < 8; ++e2){
            float load = part[e2] * (1.0f/16384.0f);
            aux += load * logf(load * 8.0f + 1e-9f);
        }
        out_aux[0] = aux / 2.0794415416798357f;
    }
}

// -------- head: z = h + eo[s1] + eo[s2]; LN; dot; one wave per row --------
__global__ void head_kernel(const float* __restrict__ h, const unsigned short* __restrict__ eog,
                            const int2* __restrict__ slot_map,
                            const float* __restrict__ w, const float* __restrict__ b,
                            const float* __restrict__ hw, const float* __restrict__ hb,
                            float* __restrict__ out)
{
    const int lane = threadIdx.x & 63;
    const int wave = threadIdx.x >> 6;
    const int row  = blockIdx.x * 4 + wave;
    const int2 sm = slot_map[row];
    const float* zr = h + (size_t)row * D_DIM;
    f32x4 v0 = *(const f32x4*)(zr + lane*8);
    f32x4 v1 = *(const f32x4*)(zr + lane*8 + 4);
    u16x8 e1 = *(const u16x8*)(eog + (size_t)sm.x * D_DIM + lane*8);
    u16x8 e2 = *(const u16x8*)(eog + (size_t)sm.y * D_DIM + lane*8);
    #pragma unroll
    for (int j=0;j<4;j++){ v0[j] += bf2f(e1[j]) + bf2f(e2[j]); }
    #pragma unroll
    for (int j=0;j<4;j++){ v1[j] += bf2f(e1[4+j]) + bf2f(e2[4+j]); }
    float s  = v0[0]+v0[1]+v0[2]+v0[3] + v1[0]+v1[1]+v1[2]+v1[3];
    float s2 = v0[0]*v0[0]+v0[1]*v0[1]+v0[2]*v0[2]+v0[3]*v0[3]
             + v1[0]*v1[0]+v1[1]*v1[1]+v1[2]*v1[2]+v1[3]*v1[3];
    #pragma unroll
    for (int o = 32; o > 0; o >>= 1){ s += __shfl_xor(s, o); s2 += __shfl_xor(s2, o); }
    const float mean = s * (1.0f/512.0f);
    const float var  = s2 * (1.0f/512.0f) - mean*mean;
    const float inv  = 1.0f / sqrtf(var + 1e-5f);
    const int k = lane*8;
    float dot = 0.f;
    #pragma unroll
    for (int j=0;j<4;j++) dot += ((v0[j]-mean)*inv*w[k+j]   + b[k+j])   * hw[k+j];
    #pragma unroll
    for (int j=0;j<4;j++) dot += ((v1[j]-mean)*inv*w[k+4+j] + b[k+4+j]) * hw[k+4+j];
    #pragma unroll
    for (int o = 32; o > 0; o >>= 1) dot += __shfl_xor(dot, o);
    if (lane == 0) out[row] = dot + hb[0];
}

// ===========================================================================
extern "C" void kernel_launch(void* const* d_in, const int* in_sizes, int n_in,
                              void* d_out, int out_size, void* d_ws, size_t ws_size,
                              hipStream_t stream)
{
    (void)in_sizes; (void)n_in; (void)out_size; (void)ws_size;
    const float* x         = (const float*)d_in[0];
    const float* embed_w   = (const float*)d_in[1];
    const float* embed_b   = (const float*)d_in[2];
    const float* ln1_w     = (const float*)d_in[3];
    const float* ln1_b     = (const float*)d_in[4];
    const float* inproj_w  = (const float*)d_in[5];
    const float* inproj_b  = (const float*)d_in[6];
    const float* outproj_w = (const float*)d_in[7];
    const float* outproj_b = (const float*)d_in[8];
    const float* ln2_w     = (const float*)d_in[9];
    const float* ln2_b     = (const float*)d_in[10];
    const float* ffn_w1    = (const float*)d_in[11];
    const float* ffn_b1    = (const float*)d_in[12];
    const float* ffn_w2    = (const float*)d_in[13];
    const float* ffn_b2    = (const float*)d_in[14];
    const float* router_w  = (const float*)d_in[15];
    const float* router_b  = (const float*)d_in[16];
    const float* exp_w1    = (const float*)d_in[17];
    const float* exp_b1    = (const float*)d_in[18];
    const float* exp_w2    = (const float*)d_in[19];
    const float* exp_b2    = (const float*)d_in[20];
    const float* head_ln_w = (const float*)d_in[21];
    const float* head_ln_b = (const float*)d_in[22];
    const float* head_w    = (const float*)d_in[23];
    const float* head_b    = (const float*)d_in[24];

    char* ws = (char*)d_ws;
    unsigned short* xbf   = (unsigned short*)(ws + 0);            //  4,194,304
    unsigned short* ebf   = (unsigned short*)(ws + 4194304);      //    131,072
    unsigned short* wobf  = (unsigned short*)(ws + 4325376);      //  1,572,864 outproj bf16
    unsigned short* wvtbf = (unsigned short*)(ws + 5898240);      //  1,572,864 Wv^T bf16
    unsigned short* wfold = (unsigned short*)(ws + 7471104);      //  1,572,864 (Wo@Wv) (N,K) bf16
    unsigned short* w1t   = (unsigned short*)(ws + 9043968);      //  6,291,456
    unsigned short* w2t   = (unsigned short*)(ws + 15335424);     //  6,291,456
    unsigned short* e1t   = (unsigned short*)(ws + 21626880);     //  2,097,152
    unsigned short* e2t   = (unsigned short*)(ws + 23724032);     //  2,097,152
    float*          h     = (float*)(ws + 25821184);              // 33,554,432
    unsigned short* gbf   = (unsigned short*)(ws + 59375616);     // 16,777,216 (ln out; later zbf)
    unsigned short* ubf   = (unsigned short*)(ws + 76152832);     // 67,108,864 (ffn1 out)
    unsigned short* hmidg = ubf;                                  // 17,301,504 (after ffn use)
    unsigned short* eog   = (unsigned short*)(ws + 93454336);     // 34,603,008
    char* MISC = ws + 143261696;
    int*    counts   = (int*)(MISC + 0);
    int*    cursor   = (int*)(MISC + 64);
    int*    offs     = (int*)(MISC + 128);
    float*  zbias    = (float*)(MISC + 256);       // 2048 B, zeroed
    float*  bfold    = (float*)(MISC + 2304);      // 6144 B
    int2*   idx2     = (int2*)(MISC + 8448);       // 131072
    float2* wts2     = (float2*)(MISC + 139520);   // 131072
    int2*   slot_map = (int2*)(MISC + 270592);     // 131072
    float*  gslot    = (float*)(MISC + 401664);    // 135168
    int*    tok      = (int*)(MISC + 536832);      // 135168
    float*  bsums    = (float*)(MISC + 672000);    // 131072
    unsigned short* zbf = gbf;
    float* out = (float*)d_out;

    // ---- reset control state (counts/cursor/offs/zbias + tok) ----
    zero_kernel<<<(MAXSLOT + 255)/256, 256, 0, stream>>>((int*)(MISC + 0), 576, tok, MAXSLOT);

    // ---- weight prep ----
    ConvArgs ca;
    ca.seg[0] = { x, xbf, B_TOK*IN_DIM/4 };
    ca.seg[1] = { outproj_w, wobf, DEPTH*D_DIM*D_DIM/4 };
    convert_kernel<<<1024, 256, 0, stream>>>(ca);

    TArgs ta;
    int tcur = 0, ti = 0;
    ta.seg[ti] = { embed_w, ebf, IN_DIM, D_DIM, tcur };
    tcur += (IN_DIM/32)*(D_DIM/32); ++ti;
    for (int l = 0; l < DEPTH; ++l){
        ta.seg[ti] = { ffn_w1 + (size_t)l*D_DIM*FF_DIM, w1t + (size_t)l*FF_DIM*D_DIM, D_DIM, FF_DIM, tcur };
        tcur += (D_DIM/32)*(FF_DIM/32); ++ti;
    }
    for (int l = 0; l < DEPTH; ++l){
        ta.seg[ti] = { ffn_w2 + (size_t)l*FF_DIM*D_DIM, w2t + (size_t)l*D_DIM*FF_DIM, FF_DIM, D_DIM, tcur };
        tcur += (FF_DIM/32)*(D_DIM/32); ++ti;
    }
    for (int e = 0; e < NEXP; ++e){
        ta.seg[ti] = { exp_w1 + (size_t)e*D_DIM*EH_DIM, e1t + (size_t)e*EH_DIM*D_DIM, D_DIM, EH_DIM, tcur };
        tcur += (D_DIM/32)*(EH_DIM/32); ++ti;
    }
    for (int e = 0; e < NEXP; ++e){
        ta.seg[ti] = { exp_w2 + (size_t)e*EH_DIM*D_DIM, e2t + (size_t)e*D_DIM*EH_DIM, EH_DIM, D_DIM, tcur };
        tcur += (EH_DIM/32)*(D_DIM/32); ++ti;
    }
    for (int l = 0; l < DEPTH; ++l){  // V-slice of inproj, transposed: (k, j) = Wv^T
        ta.seg[ti] = { inproj_w + (size_t)l*3*D_DIM*D_DIM + 2*D_DIM*D_DIM,
                       wvtbf + (size_t)l*D_DIM*D_DIM, D_DIM, D_DIM, tcur };
        tcur += (D_DIM/32)*(D_DIM/32); ++ti;
    }
    transpose_kernel<<<tcur, 256, 0, stream>>>(ta);

    foldb_kernel<<<DEPTH, D_DIM, 0, stream>>>(outproj_w, outproj_b, inproj_b, bfold);

    const dim3 blk(256);
    // Wfold_l = Wo_l @ Wv_l  (bf16, (N,K) layout), via GEMM: A=Wo, Bt=Wv^T
    for (int l = 0; l < DEPTH; ++l){
        gemm_bt<EPI_BF16><<<dim3(4, 4), blk, 0, stream>>>(
            wobf + (size_t)l*D_DIM*D_DIM, wvtbf + (size_t)l*D_DIM*D_DIM,
            zbias, nullptr, wfold + (size_t)l*D_DIM*D_DIM, D_DIM, D_DIM, D_DIM);
    }

    // embed
    gemm_bt<EPI_F32_BIAS><<<dim3(D_DIM/128, B_TOK/128), blk, 0, stream>>>(
        xbf, ebf, embed_b, nullptr, h, B_TOK, D_DIM, IN_DIM);

    for (int l = 0; l < DEPTH; ++l){
        ln_kernel<<<B_TOK/4, 256, 0, stream>>>(h, ln1_w + l*D_DIM, ln1_b + l*D_DIM, gbf);
        gemm_bt<EPI_F32_RESID><<<dim3(D_DIM/128, B_TOK/128), blk, 0, stream>>>(
            gbf, wfold + (size_t)l*D_DIM*D_DIM, bfold + l*D_DIM, h, h, B_TOK, D_DIM, D_DIM);
        ln_kernel<<<B_TOK/4, 256, 0, stream>>>(h, ln2_w + l*D_DIM, ln2_b + l*D_DIM, gbf);
        gemm_bt<EPI_BF16_GELU><<<dim3(FF_DIM/128, B_TOK/128), blk, 0, stream>>>(
            gbf, w1t + (size_t)l*FF_DIM*D_DIM, ffn_b1 + l*FF_DIM, nullptr, ubf, B_TOK, FF_DIM, D_DIM);
        gemm_bt<EPI_F32_RESID><<<dim3(D_DIM/128, B_TOK/128), blk, 0, stream>>>(
            ubf, w2t + (size_t)l*D_DIM*FF_DIM, ffn_b2 + l*D_DIM, h, h, B_TOK, D_DIM, FF_DIM);
    }

    router_kernel<<<B_TOK/4, 256, 0, stream>>>(h, router_w, router_b, zbf, idx2, wts2, counts, bsums);
    aux_kernel<<<1, 256, 0, stream>>>(bsums, out + B_TOK);
    offsets_kernel<<<1, 64, 0, stream>>>(counts, offs);
    gather_kernel<<<B_TOK/256, 256, 0, stream>>>(idx2, wts2, offs, cursor, slot_map, gslot, tok);

    // expert GEMMs over compacted slots
    gemm_moe<MEPI_GELU, 1><<<dim3(EH_DIM/128, MAXTILE), blk, 0, stream>>>(
        zbf, tok, offs, e1t, EH_DIM*D_DIM, exp_b1, EH_DIM, nullptr, hmidg, EH_DIM, D_DIM);
    gemm_moe<MEPI_GATED, 0><<<dim3(D_DIM/128, MAXTILE), blk, 0, stream>>>(
        hmidg, nullptr, offs, e2t, D_DIM*EH_DIM, exp_b2, D_DIM, gslot, eog, D_DIM, EH_DIM);

    head_kernel<<<B_TOK/4, 256, 0, stream>>>(h, eog, slot_map, head_ln_w, head_ln_b, head_w, head_b, out);
}

// Round 3
// 705.538 us; speedup vs baseline: 1.6576x; 1.6576x over previous
//
#include <hip/hip_runtime.h>
#include <hip/hip_bf16.h>

#define B_TOK 16384
#define IN_DIM 128
#define D_DIM 512
#define DEPTH 3
#define NEXP 8
#define FF_DIM 2048
#define EH_DIM 256
#define MAXSLOT 33792   // 32768 + 8*127 rounded to 128
#define MAXTILE 264     // MAXSLOT/128
#define NHBLK 64        // B_TOK/256 histogram blocks

typedef __attribute__((ext_vector_type(8))) __bf16 bf16x8;
typedef __attribute__((ext_vector_type(4))) float f32x4;
typedef __attribute__((ext_vector_type(4))) unsigned short u16x4;
typedef __attribute__((ext_vector_type(8))) unsigned short u16x8;

__device__ __forceinline__ unsigned short f2bf(float f){
    unsigned int u = __float_as_uint(f);
    u += 0x7fffu + ((u >> 16) & 1u);
    return (unsigned short)(u >> 16);
}
__device__ __forceinline__ float bf2f(unsigned short u){
    return __uint_as_float(((unsigned int)u) << 16);
}
__device__ __forceinline__ float geluf(float x){
    return 0.5f * x * (1.0f + erff(x * 0.70710678118654752f));
}
__device__ __forceinline__ void gload_lds16(const void* g, void* l){
    __builtin_amdgcn_global_load_lds((const __attribute__((address_space(1))) unsigned int*)g,
                                     (__attribute__((address_space(3))) unsigned int*)l,
                                     16, 0, 0);
}

// ---------------- zero scratch control state ------------------------------
__global__ void zero_kernel(int* a, int na, int* b, int nb){
    const int i = blockIdx.x * blockDim.x + threadIdx.x;
    if (i < na) a[i] = 0;
    if (i < nb) b[i] = 0;
}

// ---------------- fp32 -> bf16 convert ------------------------------------
struct ConvSeg { const float* src; unsigned short* dst; int n4; };
struct ConvArgs { ConvSeg seg[2]; };

__global__ void convert_kernel(ConvArgs a){
    const int stride = gridDim.x * blockDim.x;
    const int tid = blockIdx.x * blockDim.x + threadIdx.x;
    for (int s = 0; s < 2; ++s){
        const f32x4* src = (const f32x4*)a.seg[s].src;
        u16x4* dst = (u16x4*)a.seg[s].dst;
        const int n4 = a.seg[s].n4;
        for (int i = tid; i < n4; i += stride){
            f32x4 v = src[i];
            u16x4 o;
            o[0] = f2bf(v[0]); o[1] = f2bf(v[1]); o[2] = f2bf(v[2]); o[3] = f2bf(v[3]);
            dst[i] = o;
        }
    }
}

// ------------- weight transpose-convert: (K,N) fp32 -> (N,K) bf16 ---------
struct TSeg { const float* src; unsigned short* dst; int K; int N; int tileStart; };
struct TArgs { TSeg seg[26]; };

__global__ void transpose_kernel(TArgs a){
    __shared__ float t[32][33];
    const int tile = blockIdx.x;
    int s = 0;
    #pragma unroll 1
    while (s < 25 && tile >= a.seg[s+1].tileStart) ++s;
    const TSeg sg = a.seg[s];
    const int local = tile - sg.tileStart;
    const int tilesN = sg.N >> 5;
    const int k0 = (local / tilesN) << 5;
    const int n0 = (local % tilesN) << 5;
    const int tx = threadIdx.x & 31;
    const int ty = threadIdx.x >> 5;
    #pragma unroll
    for (int j = 0; j < 4; ++j)
        t[ty + j*8][tx] = sg.src[(size_t)(k0 + ty + j*8) * sg.N + n0 + tx];
    __syncthreads();
    #pragma unroll
    for (int j = 0; j < 4; ++j){
        const int n = ty + j*8;
        sg.dst[(size_t)(n0 + n) * sg.K + k0 + tx] = f2bf(t[tx][n]);
    }
}

// ---------------- folded attention bias: bfold = Wo@bv + bo ---------------
__global__ void foldb_kernel(const float* __restrict__ outproj_w, const float* __restrict__ outproj_b,
                             const float* __restrict__ inproj_b, float* __restrict__ bfold){
    const int l = blockIdx.x, n = threadIdx.x;
    const float* Wo = outproj_w + ((size_t)l*D_DIM + n)*D_DIM;
    const float* bv = inproj_b + l*3*D_DIM + 2*D_DIM;
    float acc = outproj_b[l*D_DIM + n];
    for (int j = 0; j < D_DIM; ++j) acc += Wo[j]*bv[j];
    bfold[l*D_DIM + n] = acc;
}

// ---------------- GEMM: C(M,N) = A(M,K) @ Bt(N,K)^T -----------------------
#define EPI_BF16 0
#define EPI_BF16_GELU 1
#define EPI_F32_BIAS 2
#define EPI_F32_RESID 3

template<int EPI>
__global__ void __launch_bounds__(256, 2)
gemm_bt(const unsigned short* __restrict__ A, const unsigned short* __restrict__ Bt,
        const float* __restrict__ bias, const float* __restrict__ resid,
        void* __restrict__ out, int M, int N, int K)
{
    __shared__ unsigned short sh[16384];
    unsigned short* Al = sh;
    unsigned short* Bl = sh + 8192;
    const int tid  = threadIdx.x;
    const int lane = tid & 63;
    const int wave = tid >> 6;
    const int wm = (wave >> 1) << 6;
    const int wn = (wave & 1) << 6;
    const int bm = blockIdx.y, bn = blockIdx.x;

    f32x4 acc[4][4] = {};

    const unsigned short* Abase = A + (size_t)bm * 128 * K;
    const unsigned short* Bbase = Bt + (size_t)bn * 128 * K;
    const int soff = tid * 16;

    for (int kt = 0; kt < K; kt += 64){
        #pragma unroll
        for (int s = 0; s < 4; ++s){
            const int off = s*4096 + soff;
            const int row = off >> 7, colb = off & 127;
            gload_lds16((const char*)(Abase + (size_t)row*K + kt) + colb, (char*)Al + off);
        }
        #pragma unroll
        for (int s = 0; s < 4; ++s){
            const int off = s*4096 + soff;
            const int row = off >> 7, colb = off & 127;
            gload_lds16((const char*)(Bbase + (size_t)row*K + kt) + colb, (char*)Bl + off);
        }
        __syncthreads();
        #pragma unroll
        for (int ks = 0; ks < 2; ++ks){
            const int k0 = ks*32 + ((lane>>4)<<3);
            bf16x8 af[4], bfr[4];
            #pragma unroll
            for (int i=0;i<4;i++) af[i]  = *(const bf16x8*)&Al[(wm + i*16 + (lane&15))*64 + k0];
            #pragma unroll
            for (int j=0;j<4;j++) bfr[j] = *(const bf16x8*)&Bl[(wn + j*16 + (lane&15))*64 + k0];
            #pragma unroll
            for (int i=0;i<4;i++)
                #pragma unroll
                for (int j=0;j<4;j++)
                    acc[i][j] = __builtin_amdgcn_mfma_f32_16x16x32_bf16(af[i], bfr[j], acc[i][j], 0, 0, 0);
        }
        __syncthreads();
    }

    const int r0 = ((lane>>4)<<2);
    const int cc = lane & 15;

    if (EPI == EPI_F32_BIAS || EPI == EPI_F32_RESID){
        #pragma unroll
        for (int j=0;j<4;j++){
            const int col = bn*128 + wn + j*16 + cc;
            const float bv = bias[col];
            #pragma unroll
            for (int i=0;i<4;i++){
                #pragma unroll
                for (int r=0;r<4;r++){
                    const int row = bm*128 + wm + i*16 + r0 + r;
                    const size_t idx = (size_t)row * N + col;
                    float v = acc[i][j][r] + bv;
                    if (EPI == EPI_F32_BIAS) ((float*)out)[idx] = v;
                    else                     ((float*)out)[idx] = resid[idx] + v;
                }
            }
        }
    } else {
        // LDS-assembled coalesced bf16 store
        unsigned short* Ct = sh;
        float bcol[4];
        #pragma unroll
        for (int j=0;j<4;j++) bcol[j] = bias[bn*128 + wn + j*16 + cc];
        #pragma unroll
        for (int i=0;i<4;i++){
            #pragma unroll
            for (int r=0;r<4;r++){
                const int rl = wm + i*16 + r0 + r;
                #pragma unroll
                for (int j=0;j<4;j++){
                    float v = acc[i][j][r] + bcol[j];
                    if (EPI == EPI_BF16_GELU) v = geluf(v);
                    Ct[rl*128 + wn + j*16 + cc] = f2bf(v);
                }
            }
        }
        __syncthreads();
        const int orow = tid >> 4;
        const int ocol = (tid & 15) * 8;
        unsigned short* op = (unsigned short*)out;
        #pragma unroll
        for (int p = 0; p < 8; ++p){
            const int row = p*16 + orow;
            *(u16x4*)(&op[(size_t)(bm*128 + row)*N + bn*128 + ocol])     = *(u16x4*)&Ct[row*128 + ocol];
            *(u16x4*)(&op[(size_t)(bm*128 + row)*N + bn*128 + ocol + 4]) = *(u16x4*)&Ct[row*128 + ocol + 4];
        }
    }
}

// ---------------- MoE GEMM over compacted slot space ----------------------
#define MEPI_GELU 0
#define MEPI_GATED 1

template<int MEPI, int INDIRECT>
__global__ void __launch_bounds__(256, 2)
gemm_moe(const unsigned short* __restrict__ A, const int* __restrict__ tok,
         const int* __restrict__ offs, const unsigned short* __restrict__ wbase,
         int wstride, const float* __restrict__ bbase, int bstride,
         const float* __restrict__ gslot, unsigned short* __restrict__ out,
         int N, int K)
{
    __shared__ unsigned short sh[16384];
    unsigned short* Al = sh;
    unsigned short* Bl = sh + 8192;
    const int tid  = threadIdx.x;
    const int lane = tid & 63;
    const int wave = tid >> 6;
    const int wm = (wave >> 1) << 6;
    const int wn = (wave & 1) << 6;
    const int bm = blockIdx.y, bn = blockIdx.x;
    const int m0 = bm * 128;
    if (m0 >= offs[8]) return;
    int e = 0;
    #pragma unroll 1
    while (offs[e+1] <= m0) ++e;

    const unsigned short* Bt = wbase + (size_t)e*wstride;
    const float* bias = bbase + (size_t)e*bstride;

    f32x4 acc[4][4] = {};
    const int soff = tid * 16;

    const unsigned short* Arow[4];
    int colb_[4];
    #pragma unroll
    for (int s = 0; s < 4; ++s){
        const int off = s*4096 + soff;
        const int row = off >> 7;
        colb_[s] = off & 127;
        if (INDIRECT){
            const int t = tok[m0 + row];
            Arow[s] = A + (size_t)t*K;
        } else {
            Arow[s] = A + (size_t)(m0 + row)*K;
        }
    }
    const unsigned short* Bbase = Bt + (size_t)bn * 128 * K;

    for (int kt = 0; kt < K; kt += 64){
        #pragma unroll
        for (int s = 0; s < 4; ++s){
            const int off = s*4096 + soff;
            gload_lds16((const char*)(Arow[s] + kt) + colb_[s], (char*)Al + off);
        }
        #pragma unroll
        for (int s = 0; s < 4; ++s){
            const int off = s*4096 + soff;
            const int row = off >> 7, colb = off & 127;
            gload_lds16((const char*)(Bbase + (size_t)row*K + kt) + colb, (char*)Bl + off);
        }
        __syncthreads();
        #pragma unroll
        for (int ks = 0; ks < 2; ++ks){
            const int k0 = ks*32 + ((lane>>4)<<3);
            bf16x8 af[4], bfr[4];
            #pragma unroll
            for (int i=0;i<4;i++) af[i]  = *(const bf16x8*)&Al[(wm + i*16 + (lane&15))*64 + k0];
            #pragma unroll
            for (int j=0;j<4;j++) bfr[j] = *(const bf16x8*)&Bl[(wn + j*16 + (lane&15))*64 + k0];
            #pragma unroll
            for (int i=0;i<4;i++)
                #pragma unroll
                for (int j=0;j<4;j++)
                    acc[i][j] = __builtin_amdgcn_mfma_f32_16x16x32_bf16(af[i], bfr[j], acc[i][j], 0, 0, 0);
        }
        __syncthreads();
    }

    const int r0 = ((lane>>4)<<2);
    const int cc = lane & 15;
    unsigned short* Ct = sh;
    float bcol[4];
    #pragma unroll
    for (int j=0;j<4;j++) bcol[j] = bias[bn*128 + wn + j*16 + cc];
    #pragma unroll
    for (int i=0;i<4;i++){
        #pragma unroll
        for (int r=0;r<4;r++){
            const int rl = wm + i*16 + r0 + r;
            float g = 1.0f;
            if (MEPI == MEPI_GATED) g = gslot[m0 + rl];
            #pragma unroll
            for (int j=0;j<4;j++){
                float v = acc[i][j][r] + bcol[j];
                if (MEPI == MEPI_GELU) v = geluf(v);
                else                   v = v * g;
                Ct[rl*128 + wn + j*16 + cc] = f2bf(v);
            }
        }
    }
    __syncthreads();
    const int orow = tid >> 4;
    const int ocol = (tid & 15) * 8;
    #pragma unroll
    for (int p = 0; p < 8; ++p){
        const int row = p*16 + orow;
        *(u16x4*)(&out[(size_t)(m0 + row)*N + bn*128 + ocol])     = *(u16x4*)&Ct[row*128 + ocol];
        *(u16x4*)(&out[(size_t)(m0 + row)*N + bn*128 + ocol + 4]) = *(u16x4*)&Ct[row*128 + ocol + 4];
    }
}

// ---------------- LayerNorm (fp32 in, bf16 out), one wave per row ---------
__global__ void ln_kernel(const float* __restrict__ x, const float* __restrict__ w,
                          const float* __restrict__ b, unsigned short* __restrict__ out)
{
    const int lane = threadIdx.x & 63;
    const int wave = threadIdx.x >> 6;
    const int row  = blockIdx.x * 4 + wave;
    const float* xr = x + (size_t)row * D_DIM;
    f32x4 v0 = *(const f32x4*)(xr + lane*8);
    f32x4 v1 = *(const f32x4*)(xr + lane*8 + 4);
    float s  = v0[0]+v0[1]+v0[2]+v0[3] + v1[0]+v1[1]+v1[2]+v1[3];
    float s2 = v0[0]*v0[0]+v0[1]*v0[1]+v0[2]*v0[2]+v0[3]*v0[3]
             + v1[0]*v1[0]+v1[1]*v1[1]+v1[2]*v1[2]+v1[3]*v1[3];
    #pragma unroll
    for (int o = 32; o > 0; o >>= 1){ s += __shfl_xor(s, o); s2 += __shfl_xor(s2, o); }
    const float mean = s * (1.0f/512.0f);
    const float var  = s2 * (1.0f/512.0f) - mean*mean;
    const float inv  = 1.0f / sqrtf(var + 1e-5f);
    const int k = lane*8;
    u16x4 o0, o1;
    #pragma unroll
    for (int j=0;j<4;j++) o0[j] = f2bf((v0[j]-mean)*inv*w[k+j]   + b[k+j]);
    #pragma unroll
    for (int j=0;j<4;j++) o1[j] = f2bf((v1[j]-mean)*inv*w[k+4+j] + b[k+4+j]);
    *(u16x4*)(out + (size_t)row*D_DIM + k)     = o0;
    *(u16x4*)(out + (size_t)row*D_DIM + k + 4) = o1;
}

// ------- Router: softmax+eps-mix+top2 (NO global atomics), zbf, bsums -----
__global__ void router_kernel(const float* __restrict__ z, const float* __restrict__ rw,
                              const float* __restrict__ rb, unsigned short* __restrict__ zbf,
                              int2* __restrict__ idx2, float2* __restrict__ wts2,
                              float* __restrict__ bsums)
{
    __shared__ float ps[4][8];
    const int lane = threadIdx.x & 63;
    const int wave = threadIdx.x >> 6;
    const int row  = blockIdx.x * 4 + wave;
    const float* zr = z + (size_t)row * D_DIM;
    f32x4 z0 = *(const f32x4*)(zr + lane*8);
    f32x4 z1 = *(const f32x4*)(zr + lane*8 + 4);
    {
        u16x4 o0, o1;
        #pragma unroll
        for (int j=0;j<4;j++){ o0[j] = f2bf(z0[j]); o1[j] = f2bf(z1[j]); }
        *(u16x4*)(zbf + (size_t)row*D_DIM + lane*8)     = o0;
        *(u16x4*)(zbf + (size_t)row*D_DIM + lane*8 + 4) = o1;
    }
    float acc[8] = {0,0,0,0,0,0,0,0};
    #pragma unroll
    for (int j = 0; j < 8; ++j){
        const float zv = (j < 4) ? z0[j] : z1[j-4];
        const float* wr = rw + (size_t)(lane*8 + j) * 8;
        f32x4 w0 = *(const f32x4*)wr;
        f32x4 w1 = *(const f32x4*)(wr + 4);
        acc[0] += zv*w0[0]; acc[1] += zv*w0[1]; acc[2] += zv*w0[2]; acc[3] += zv*w0[3];
        acc[4] += zv*w1[0]; acc[5] += zv*w1[1]; acc[6] += zv*w1[2]; acc[7] += zv*w1[3];
    }
    #pragma unroll
    for (int o = 32; o > 0; o >>= 1){
        #pragma unroll
        for (int e = 0; e < 8; ++e) acc[e] += __shfl_xor(acc[e], o);
    }
    if (lane == 0){
        float p[8]; float mx = -1e30f;
        #pragma unroll
        for (int e=0;e<8;e++){ p[e] = acc[e] + rb[e]; mx = fmaxf(mx, p[e]); }
        float se = 0.f;
        #pragma unroll
        for (int e=0;e<8;e++){ p[e] = expf(p[e]-mx); se += p[e]; }
        const float sc = 0.9f / se;
        #pragma unroll
        for (int e=0;e<8;e++) p[e] = p[e]*sc + 0.0125f;
        int i1 = 0;
        #pragma unroll
        for (int e=1;e<8;e++) if (p[e] > p[i1]) i1 = e;
        int i2 = (i1 == 0) ? 1 : 0;
        for (int e=i2+1;e<8;e++) if (e != i1 && p[e] > p[i2]) i2 = e;
        idx2[row] = make_int2(i1, i2);
        wts2[row] = make_float2(p[i1], p[i2]);
        #pragma unroll
        for (int e=0;e<8;e++) ps[wave][e] = p[e];
    }
    __syncthreads();
    if (threadIdx.x < 8){
        bsums[blockIdx.x*8 + threadIdx.x] =
            ps[0][threadIdx.x] + ps[1][threadIdx.x] + ps[2][threadIdx.x] + ps[3][threadIdx.x];
    }
}

// ------- histogram: per-block expert counts via LDS (no global atomics) ---
__global__ void hist_kernel(const int2* __restrict__ idx2, int* __restrict__ blockHist){
    __shared__ int hc[8];
    if (threadIdx.x < 8) hc[threadIdx.x] = 0;
    __syncthreads();
    const int t = blockIdx.x * 256 + threadIdx.x;
    const int2 ii = idx2[t];
    atomicAdd(&hc[ii.x], 1);
    atomicAdd(&hc[ii.y], 1);
    __syncthreads();
    if (threadIdx.x < 8) blockHist[blockIdx.x*8 + threadIdx.x] = hc[threadIdx.x];
}

// ------- scan: padded expert offsets + per-block bases (1 thread) ---------
__global__ void scan_kernel(const int* __restrict__ blockHist, int* __restrict__ offs,
                            int* __restrict__ baseArr){
    if (threadIdx.x == 0){
        int counts[8];
        #pragma unroll
        for (int e=0;e<8;e++) counts[e] = 0;
        for (int b=0;b<NHBLK;b++)
            #pragma unroll
            for (int e=0;e<8;e++) counts[e] += blockHist[b*8+e];
        int o = 0; offs[0] = 0;
        int start[8];
        #pragma unroll
        for (int e=0;e<8;e++){ start[e] = o; o += (counts[e]+127)&~127; offs[e+1] = o; }
        for (int e=0;e<8;e++){
            int cur = start[e];
            for (int b=0;b<NHBLK;b++){ baseArr[b*8+e] = cur; cur += blockHist[b*8+e]; }
        }
    }
}

// ------- assign: block-local LDS cursors -> slots (no global atomics) -----
__global__ void assign_kernel(const int2* __restrict__ idx2, const float2* __restrict__ wts2,
                              const int* __restrict__ baseArr, int2* __restrict__ slot_map,
                              float* __restrict__ gslot, int* __restrict__ tok)
{
    __shared__ int cur[8];
    if (threadIdx.x < 8) cur[threadIdx.x] = 0;
    __syncthreads();
    const int t = blockIdx.x * 256 + threadIdx.x;
    const int2 ii = idx2[t];
    const float2 ww = wts2[t];
    const int r1 = atomicAdd(&cur[ii.x], 1);
    const int r2 = atomicAdd(&cur[ii.y], 1);
    const int s1 = baseArr[blockIdx.x*8 + ii.x] + r1;
    const int s2 = baseArr[blockIdx.x*8 + ii.y] + r2;
    slot_map[t] = make_int2(s1, s2);
    gslot[s1] = ww.x; gslot[s2] = ww.y;
    tok[s1] = t; tok[s2] = t;
}

// ---------------- aux loss ------------------------------------------------
__global__ void aux_kernel(const float* __restrict__ bsums, float* __restrict__ out_aux)
{
    __shared__ float part[256];
    const int t = threadIdx.x;
    const int e = t & 7, chunk = t >> 3;
    float s = 0.f;
    for (int blk = chunk*128; blk < chunk*128 + 128; ++blk) s += bsums[blk*8 + e];
    part[t] = s;
    __syncthreads();
    if (t < 8){
        float tot = 0.f;
        for (int c = 0; c < 32; ++c) tot += part[c*8 + t];
        part[t] = tot;
    }
    __syncthreads();
    if (t == 0){
        float aux = 0.f;
        for (int e2 = 0; e2 < 8; ++e2){
            float load = part[e2] * (1.0f/16384.0f);
            aux += load * logf(load * 8.0f + 1e-9f);
        }
        out_aux[0] = aux / 2.0794415416798357f;
    }
}

// -------- head: z = h + eo[s1] + eo[s2]; LN; dot; one wave per row --------
__global__ void head_kernel(const float* __restrict__ h, const unsigned short* __restrict__ eog,
                            const int2* __restrict__ slot_map,
                            const float* __restrict__ w, const float* __restrict__ b,
                            const float* __restrict__ hw, const float* __restrict__ hb,
                            float* __restrict__ out)
{
    const int lane = threadIdx.x & 63;
    const int wave = threadIdx.x >> 6;
    const int row  = blockIdx.x * 4 + wave;
    const int2 sm = slot_map[row];
    const float* zr = h + (size_t)row * D_DIM;
    f32x4 v0 = *(const f32x4*)(zr + lane*8);
    f32x4 v1 = *(const f32x4*)(zr + lane*8 + 4);
    u16x8 e1 = *(const u16x8*)(eog + (size_t)sm.x * D_DIM + lane*8);
    u16x8 e2 = *(const u16x8*)(eog + (size_t)sm.y * D_DIM + lane*8);
    #pragma unroll
    for (int j=0;j<4;j++){ v0[j] += bf2f(e1[j]) + bf2f(e2[j]); }
    #pragma unroll
    for (int j=0;j<4;j++){ v1[j] += bf2f(e1[4+j]) + bf2f(e2[4+j]); }
    float s  = v0[0]+v0[1]+v0[2]+v0[3] + v1[0]+v1[1]+v1[2]+v1[3];
    float s2 = v0[0]*v0[0]+v0[1]*v0[1]+v0[2]*v0[2]+v0[3]*v0[3]
             + v1[0]*v1[0]+v1[1]*v1[1]+v1[2]*v1[2]+v1[3]*v1[3];
    #pragma unroll
    for (int o = 32; o > 0; o >>= 1){ s += __shfl_xor(s, o); s2 += __shfl_xor(s2, o); }
    const float mean = s * (1.0f/512.0f);
    const float var  = s2 * (1.0f/512.0f) - mean*mean;
    const float inv  = 1.0f / sqrtf(var + 1e-5f);
    const int k = lane*8;
    float dot = 0.f;
    #pragma unroll
    for (int j=0;j<4;j++) dot += ((v0[j]-mean)*inv*w[k+j]   + b[k+j])   * hw[k+j];
    #pragma unroll
    for (int j=0;j<4;j++) dot += ((v1[j]-mean)*inv*w[k+4+j] + b[k+4+j]) * hw[k+4+j];
    #pragma unroll
    for (int o = 32; o > 0; o >>= 1) dot += __shfl_xor(dot, o);
    if (lane == 0) out[row] = dot + hb[0];
}

// ===========================================================================
extern "C" void kernel_launch(void* const* d_in, const int* in_sizes, int n_in,
                              void* d_out, int out_size, void* d_ws, size_t ws_size,
                              hipStream_t stream)
{
    (void)in_sizes; (void)n_in; (void)out_size; (void)ws_size;
    const float* x         = (const float*)d_in[0];
    const float* embed_w   = (const float*)d_in[1];
    const float* embed_b   = (const float*)d_in[2];
    const float* ln1_w     = (const float*)d_in[3];
    const float* ln1_b     = (const float*)d_in[4];
    const float* inproj_w  = (const float*)d_in[5];
    const float* inproj_b  = (const float*)d_in[6];
    const float* outproj_w = (const float*)d_in[7];
    const float* outproj_b = (const float*)d_in[8];
    const float* ln2_w     = (const float*)d_in[9];
    const float* ln2_b     = (const float*)d_in[10];
    const float* ffn_w1    = (const float*)d_in[11];
    const float* ffn_b1    = (const float*)d_in[12];
    const float* ffn_w2    = (const float*)d_in[13];
    const float* ffn_b2    = (const float*)d_in[14];
    const float* router_w  = (const float*)d_in[15];
    const float* router_b  = (const float*)d_in[16];
    const float* exp_w1    = (const float*)d_in[17];
    const float* exp_b1    = (const float*)d_in[18];
    const float* exp_w2    = (const float*)d_in[19];
    const float* exp_b2    = (const float*)d_in[20];
    const float* head_ln_w = (const float*)d_in[21];
    const float* head_ln_b = (const float*)d_in[22];
    const float* head_w    = (const float*)d_in[23];
    const float* head_b    = (const float*)d_in[24];

    char* ws = (char*)d_ws;
    unsigned short* xbf   = (unsigned short*)(ws + 0);            //  4,194,304
    unsigned short* ebf   = (unsigned short*)(ws + 4194304);      //    131,072
    unsigned short* wobf  = (unsigned short*)(ws + 4325376);      //  1,572,864 outproj bf16
    unsigned short* wvtbf = (unsigned short*)(ws + 5898240);      //  1,572,864 Wv^T bf16
    unsigned short* wfold = (unsigned short*)(ws + 7471104);      //  1,572,864 (Wo@Wv) (N,K) bf16
    unsigned short* w1t   = (unsigned short*)(ws + 9043968);      //  6,291,456
    unsigned short* w2t   = (unsigned short*)(ws + 15335424);     //  6,291,456
    unsigned short* e1t   = (unsigned short*)(ws + 21626880);     //  2,097,152
    unsigned short* e2t   = (unsigned short*)(ws + 23724032);     //  2,097,152
    float*          h     = (float*)(ws + 25821184);              // 33,554,432
    unsigned short* gbf   = (unsigned short*)(ws + 59375616);     // 16,777,216 (ln out; later zbf)
    unsigned short* ubf   = (unsigned short*)(ws + 76152832);     // 67,108,864 (ffn1 out)
    unsigned short* hmidg = ubf;                                  // (after ffn use)
    unsigned short* eog   = (unsigned short*)(ws + 93454336);     // 34,603,008
    char* MISC = ws + 143261696;
    int*    offs     = (int*)(MISC + 0);           // 64 B
    float*  zbias    = (float*)(MISC + 256);       // 2048 B, zeroed
    float*  bfold    = (float*)(MISC + 2304);      // 6144 B
    int2*   idx2     = (int2*)(MISC + 8448);       // 131072
    float2* wts2     = (float2*)(MISC + 139520);   // 131072
    int2*   slot_map = (int2*)(MISC + 270592);     // 131072
    float*  gslot    = (float*)(MISC + 401664);    // 135168
    int*    tok      = (int*)(MISC + 536832);      // 135168, zeroed
    float*  bsums    = (float*)(MISC + 672000);    // 131072
    int*    blockHist= (int*)(MISC + 803072);      // 2048
    int*    baseArr  = (int*)(MISC + 805120);      // 2048
    unsigned short* zbf = gbf;
    float* out = (float*)d_out;

    // ---- reset control state (zbias + tok) ----
    zero_kernel<<<(MAXSLOT + 255)/256, 256, 0, stream>>>((int*)zbias, 512, tok, MAXSLOT);

    // ---- weight prep ----
    ConvArgs ca;
    ca.seg[0] = { x, xbf, B_TOK*IN_DIM/4 };
    ca.seg[1] = { outproj_w, wobf, DEPTH*D_DIM*D_DIM/4 };
    convert_kernel<<<1024, 256, 0, stream>>>(ca);

    TArgs ta;
    int tcur = 0, ti = 0;
    ta.seg[ti] = { embed_w, ebf, IN_DIM, D_DIM, tcur };
    tcur += (IN_DIM/32)*(D_DIM/32); ++ti;
    for (int l = 0; l < DEPTH; ++l){
        ta.seg[ti] = { ffn_w1 + (size_t)l*D_DIM*FF_DIM, w1t + (size_t)l*FF_DIM*D_DIM, D_DIM, FF_DIM, tcur };
        tcur += (D_DIM/32)*(FF_DIM/32); ++ti;
    }
    for (int l = 0; l < DEPTH; ++l){
        ta.seg[ti] = { ffn_w2 + (size_t)l*FF_DIM*D_DIM, w2t + (size_t)l*D_DIM*FF_DIM, FF_DIM, D_DIM, tcur };
        tcur += (FF_DIM/32)*(D_DIM/32); ++ti;
    }
    for (int e = 0; e < NEXP; ++e){
        ta.seg[ti] = { exp_w1 + (size_t)e*D_DIM*EH_DIM, e1t + (size_t)e*EH_DIM*D_DIM, D_DIM, EH_DIM, tcur };
        tcur += (D_DIM/32)*(EH_DIM/32); ++ti;
    }
    for (int e = 0; e < NEXP; ++e){
        ta.seg[ti] = { exp_w2 + (size_t)e*EH_DIM*D_DIM, e2t + (size_t)e*D_DIM*EH_DIM, EH_DIM, D_DIM, tcur };
        tcur += (EH_DIM/32)*(D_DIM/32); ++ti;
    }
    for (int l = 0; l < DEPTH; ++l){
        ta.seg[ti] = { inproj_w + (size_t)l*3*D_DIM*D_DIM + 2*D_DIM*D_DIM,
                       wvtbf + (size_t)l*D_DIM*D_DIM, D_DIM, D_DIM, tcur };
        tcur += (D_DIM/32)*(D_DIM/32); ++ti;
    }
    transpose_kernel<<<tcur, 256, 0, stream>>>(ta);

    foldb_kernel<<<DEPTH, D_DIM, 0, stream>>>(outproj_w, outproj_b, inproj_b, bfold);

    const dim3 blk(256);
    for (int l = 0; l < DEPTH; ++l){
        gemm_bt<EPI_BF16><<<dim3(4, 4), blk, 0, stream>>>(
            wobf + (size_t)l*D_DIM*D_DIM, wvtbf + (size_t)l*D_DIM*D_DIM,
            zbias, nullptr, wfold + (size_t)l*D_DIM*D_DIM, D_DIM, D_DIM, D_DIM);
    }

    gemm_bt<EPI_F32_BIAS><<<dim3(D_DIM/128, B_TOK/128), blk, 0, stream>>>(
        xbf, ebf, embed_b, nullptr, h, B_TOK, D_DIM, IN_DIM);

    for (int l = 0; l < DEPTH; ++l){
        ln_kernel<<<B_TOK/4, 256, 0, stream>>>(h, ln1_w + l*D_DIM, ln1_b + l*D_DIM, gbf);
        gemm_bt<EPI_F32_RESID><<<dim3(D_DIM/128, B_TOK/128), blk, 0, stream>>>(
            gbf, wfold + (size_t)l*D_DIM*D_DIM, bfold + l*D_DIM, h, h, B_TOK, D_DIM, D_DIM);
        ln_kernel<<<B_TOK/4, 256, 0, stream>>>(h, ln2_w + l*D_DIM, ln2_b + l*D_DIM, gbf);
        gemm_bt<EPI_BF16_GELU><<<dim3(FF_DIM/128, B_TOK/128), blk, 0, stream>>>(
            gbf, w1t + (size_t)l*FF_DIM*D_DIM, ffn_b1 + l*FF_DIM, nullptr, ubf, B_TOK, FF_DIM, D_DIM);
        gemm_bt<EPI_F32_RESID><<<dim3(D_DIM/128, B_TOK/128), blk, 0, stream>>>(
            ubf, w2t + (size_t)l*D_DIM*FF_DIM, ffn_b2 + l*D_DIM, h, h, B_TOK, D_DIM, FF_DIM);
    }

    router_kernel<<<B_TOK/4, 256, 0, stream>>>(h, router_w, router_b, zbf, idx2, wts2, bsums);
    aux_kernel<<<1, 256, 0, stream>>>(bsums, out + B_TOK);
    hist_kernel<<<NHBLK, 256, 0, stream>>>(idx2, blockHist);
    scan_kernel<<<1, 64, 0, stream>>>(blockHist, offs, baseArr);
    assign_kernel<<<NHBLK, 256, 0, stream>>>(idx2, wts2, baseArr, slot_map, gslot, tok);

    gemm_moe<MEPI_GELU, 1><<<dim3(EH_DIM/128, MAXTILE), blk, 0, stream>>>(
        zbf, tok, offs, e1t, EH_DIM*D_DIM, exp_b1, EH_DIM, nullptr, hmidg, EH_DIM, D_DIM);
    gemm_moe<MEPI_GATED, 0><<<dim3(D_DIM/128, MAXTILE), blk, 0, stream>>>(
        hmidg, nullptr, offs, e2t, D_DIM*EH_DIM, exp_b2, D_DIM, gslot, eog, D_DIM, EH_DIM);

    head_kernel<<<B_TOK/4, 256, 0, stream>>>(h, eog, slot_map, head_ln_w, head_ln_b, head_w, head_b, out);
}

// Round 4
// 697.492 us; speedup vs baseline: 1.6767x; 1.0115x over previous
//
#include <hip/hip_runtime.h>
#include <hip/hip_bf16.h>

#define B_TOK 16384
#define IN_DIM 128
#define D_DIM 512
#define DEPTH 3
#define NEXP 8
#define FF_DIM 2048
#define EH_DIM 256
#define MAXSLOT 33792   // 32768 + 8*127 rounded to 128
#define MAXTILE 264     // MAXSLOT/128
#define NHBLK 64        // B_TOK/256 histogram blocks

typedef __attribute__((ext_vector_type(8))) __bf16 bf16x8;
typedef __attribute__((ext_vector_type(4))) float f32x4;
typedef __attribute__((ext_vector_type(4))) unsigned short u16x4;
typedef __attribute__((ext_vector_type(8))) unsigned short u16x8;

__device__ __forceinline__ unsigned short f2bf(float f){
    unsigned int u = __float_as_uint(f);
    u += 0x7fffu + ((u >> 16) & 1u);
    return (unsigned short)(u >> 16);
}
__device__ __forceinline__ float bf2f(unsigned short u){
    return __uint_as_float(((unsigned int)u) << 16);
}
__device__ __forceinline__ float geluf(float x){
    return 0.5f * x * (1.0f + erff(x * 0.70710678118654752f));
}
__device__ __forceinline__ void gload_lds16(const void* g, void* l){
    __builtin_amdgcn_global_load_lds((const __attribute__((address_space(1))) unsigned int*)g,
                                     (__attribute__((address_space(3))) unsigned int*)l,
                                     16, 0, 0);
}
// bijective XCD-chunked remap (m204): round-robin dispatch -> contiguous chunks
__device__ __forceinline__ int xcd_swizzle(int orig, int nwg){
    const int q = nwg >> 3, r = nwg & 7;
    const int xcd = orig & 7;
    const int idx = orig >> 3;
    return (xcd < r ? xcd*(q+1) : r*(q+1) + (xcd-r)*q) + idx;
}

// ---------------- zero scratch control state ------------------------------
__global__ void zero_kernel(int* a, int na, int* b, int nb){
    const int i = blockIdx.x * blockDim.x + threadIdx.x;
    if (i < na) a[i] = 0;
    if (i < nb) b[i] = 0;
}

// ---------------- fp32 -> bf16 convert ------------------------------------
struct ConvSeg { const float* src; unsigned short* dst; int n4; };
struct ConvArgs { ConvSeg seg[2]; };

__global__ void convert_kernel(ConvArgs a){
    const int stride = gridDim.x * blockDim.x;
    const int tid = blockIdx.x * blockDim.x + threadIdx.x;
    for (int s = 0; s < 2; ++s){
        const f32x4* src = (const f32x4*)a.seg[s].src;
        u16x4* dst = (u16x4*)a.seg[s].dst;
        const int n4 = a.seg[s].n4;
        for (int i = tid; i < n4; i += stride){
            f32x4 v = src[i];
            u16x4 o;
            o[0] = f2bf(v[0]); o[1] = f2bf(v[1]); o[2] = f2bf(v[2]); o[3] = f2bf(v[3]);
            dst[i] = o;
        }
    }
}

// ------------- weight transpose-convert: (K,N) fp32 -> (N,K) bf16 ---------
struct TSeg { const float* src; unsigned short* dst; int K; int N; int tileStart; };
struct TArgs { TSeg seg[26]; };

__global__ void transpose_kernel(TArgs a){
    __shared__ float t[32][33];
    const int tile = blockIdx.x;
    int s = 0;
    #pragma unroll 1
    while (s < 25 && tile >= a.seg[s+1].tileStart) ++s;
    const TSeg sg = a.seg[s];
    const int local = tile - sg.tileStart;
    const int tilesN = sg.N >> 5;
    const int k0 = (local / tilesN) << 5;
    const int n0 = (local % tilesN) << 5;
    const int tx = threadIdx.x & 31;
    const int ty = threadIdx.x >> 5;
    #pragma unroll
    for (int j = 0; j < 4; ++j)
        t[ty + j*8][tx] = sg.src[(size_t)(k0 + ty + j*8) * sg.N + n0 + tx];
    __syncthreads();
    #pragma unroll
    for (int j = 0; j < 4; ++j){
        const int n = ty + j*8;
        sg.dst[(size_t)(n0 + n) * sg.K + k0 + tx] = f2bf(t[tx][n]);
    }
}

// ---------------- folded attention bias: bfold = Wo@bv + bo ---------------
__global__ void foldb_kernel(const float* __restrict__ outproj_w, const float* __restrict__ outproj_b,
                             const float* __restrict__ inproj_b, float* __restrict__ bfold){
    const int l = blockIdx.x, n = threadIdx.x;
    const float* Wo = outproj_w + ((size_t)l*D_DIM + n)*D_DIM;
    const float* bv = inproj_b + l*3*D_DIM + 2*D_DIM;
    float acc = outproj_b[l*D_DIM + n];
    for (int j = 0; j < D_DIM; ++j) acc += Wo[j]*bv[j];
    bfold[l*D_DIM + n] = acc;
}

// ---------------- GEMM: C(M,N) = A(M,K) @ Bt(N,K)^T -----------------------
// 128x128 tile, BK=64, dbuf LDS prefetch (T3 minimum-2-phase), XCD swizzle.
#define EPI_BF16 0
#define EPI_BF16_GELU 1
#define EPI_F32_BIAS 2
#define EPI_F32_RESID 3

template<int EPI>
__global__ void __launch_bounds__(256, 2)
gemm_bt(const unsigned short* __restrict__ A, const unsigned short* __restrict__ Bt,
        const float* __restrict__ bias, const float* __restrict__ resid,
        void* __restrict__ out, int NB, int N, int K)
{
    __shared__ unsigned short sh[32768];   // 64 KiB: 2 x (A 16KB + B 16KB)
    const int nwg = gridDim.x;
    const int wg  = xcd_swizzle(blockIdx.x, nwg);
    const int bn  = wg % NB;
    const int bm  = wg / NB;

    const int tid  = threadIdx.x;
    const int lane = tid & 63;
    const int wave = tid >> 6;
    const int wm = (wave >> 1) << 6;
    const int wn = (wave & 1) << 6;

    f32x4 acc[4][4] = {};

    const unsigned short* Abase = A + (size_t)bm * 128 * K;
    const unsigned short* Bbase = Bt + (size_t)bn * 128 * K;
    const int soff = tid * 16;   // byte offset, 0..4080

    auto STAGE = [&](int b, int kt){
        char* Ab = (char*)(sh + b*16384);
        char* Bb = (char*)(sh + b*16384 + 8192);
        #pragma unroll
        for (int s = 0; s < 4; ++s){
            const int off = s*4096 + soff;
            const int row = off >> 7, colb = off & 127;
            gload_lds16((const char*)(Abase + (size_t)row*K + kt) + colb, Ab + off);
        }
        #pragma unroll
        for (int s = 0; s < 4; ++s){
            const int off = s*4096 + soff;
            const int row = off >> 7, colb = off & 127;
            gload_lds16((const char*)(Bbase + (size_t)row*K + kt) + colb, Bb + off);
        }
    };
    auto COMPUTE = [&](int b){
        const unsigned short* Ab = sh + b*16384;
        const unsigned short* Bb = sh + b*16384 + 8192;
        #pragma unroll
        for (int ks = 0; ks < 2; ++ks){
            const int k0 = ks*32 + ((lane>>4)<<3);
            bf16x8 af[4], bfr[4];
            #pragma unroll
            for (int i=0;i<4;i++) af[i]  = *(const bf16x8*)&Ab[(wm + i*16 + (lane&15))*64 + k0];
            #pragma unroll
            for (int j=0;j<4;j++) bfr[j] = *(const bf16x8*)&Bb[(wn + j*16 + (lane&15))*64 + k0];
            #pragma unroll
            for (int i=0;i<4;i++)
                #pragma unroll
                for (int j=0;j<4;j++)
                    acc[i][j] = __builtin_amdgcn_mfma_f32_16x16x32_bf16(af[i], bfr[j], acc[i][j], 0, 0, 0);
        }
    };

    STAGE(0, 0);
    __syncthreads();
    const int nk = K >> 6;
    int cur = 0;
    for (int i = 0; i < nk; ++i){
        if (i + 1 < nk) STAGE(cur ^ 1, (i + 1) << 6);
        COMPUTE(cur);
        __syncthreads();        // drains prefetch vmcnt + protects dbuf reuse
        cur ^= 1;
    }

    const int r0 = ((lane>>4)<<2);
    const int cc = lane & 15;

    if (EPI == EPI_F32_BIAS || EPI == EPI_F32_RESID){
        #pragma unroll
        for (int j=0;j<4;j++){
            const int col = bn*128 + wn + j*16 + cc;
            const float bv = bias[col];
            #pragma unroll
            for (int i=0;i<4;i++){
                #pragma unroll
                for (int r=0;r<4;r++){
                    const int row = bm*128 + wm + i*16 + r0 + r;
                    const size_t idx = (size_t)row * N + col;
                    float v = acc[i][j][r] + bv;
                    if (EPI == EPI_F32_BIAS) ((float*)out)[idx] = v;
                    else                     ((float*)out)[idx] = resid[idx] + v;
                }
            }
        }
    } else {
        // LDS-assembled coalesced bf16 store
        unsigned short* Ct = sh;
        float bcol[4];
        #pragma unroll
        for (int j=0;j<4;j++) bcol[j] = bias[bn*128 + wn + j*16 + cc];
        #pragma unroll
        for (int i=0;i<4;i++){
            #pragma unroll
            for (int r=0;r<4;r++){
                const int rl = wm + i*16 + r0 + r;
                #pragma unroll
                for (int j=0;j<4;j++){
                    float v = acc[i][j][r] + bcol[j];
                    if (EPI == EPI_BF16_GELU) v = geluf(v);
                    Ct[rl*128 + wn + j*16 + cc] = f2bf(v);
                }
            }
        }
        __syncthreads();
        const int orow = tid >> 4;
        const int ocol = (tid & 15) * 8;
        unsigned short* op = (unsigned short*)out;
        #pragma unroll
        for (int p = 0; p < 8; ++p){
            const int row = p*16 + orow;
            *(u16x4*)(&op[(size_t)(bm*128 + row)*N + bn*128 + ocol])     = *(u16x4*)&Ct[row*128 + ocol];
            *(u16x4*)(&op[(size_t)(bm*128 + row)*N + bn*128 + ocol + 4]) = *(u16x4*)&Ct[row*128 + ocol + 4];
        }
    }
}

// ---------------- MoE GEMM over compacted slot space ----------------------
#define MEPI_GELU 0
#define MEPI_GATED 1

template<int MEPI, int INDIRECT>
__global__ void __launch_bounds__(256, 2)
gemm_moe(const unsigned short* __restrict__ A, const int* __restrict__ tok,
         const int* __restrict__ offs, const unsigned short* __restrict__ wbase,
         int wstride, const float* __restrict__ bbase, int bstride,
         const float* __restrict__ gslot, unsigned short* __restrict__ out,
         int NB, int N, int K)
{
    __shared__ unsigned short sh[32768];
    const int nwg = gridDim.x;
    const int wg  = xcd_swizzle(blockIdx.x, nwg);
    const int bn  = wg % NB;
    const int bm  = wg / NB;
    const int m0  = bm * 128;
    if (m0 >= offs[8]) return;

    const int tid  = threadIdx.x;
    const int lane = tid & 63;
    const int wave = tid >> 6;
    const int wm = (wave >> 1) << 6;
    const int wn = (wave & 1) << 6;

    int e = 0;
    #pragma unroll 1
    while (offs[e+1] <= m0) ++e;

    const unsigned short* Bt = wbase + (size_t)e*wstride;
    const float* bias = bbase + (size_t)e*bstride;

    f32x4 acc[4][4] = {};
    const int soff = tid * 16;

    const unsigned short* Arow[4];
    int colb_[4];
    #pragma unroll
    for (int s = 0; s < 4; ++s){
        const int off = s*4096 + soff;
        const int row = off >> 7;
        colb_[s] = off & 127;
        if (INDIRECT){
            const int t = tok[m0 + row];
            Arow[s] = A + (size_t)t*K;
        } else {
            Arow[s] = A + (size_t)(m0 + row)*K;
        }
    }
    const unsigned short* Bbase = Bt + (size_t)bn * 128 * K;

    auto STAGE = [&](int b, int kt){
        char* Ab = (char*)(sh + b*16384);
        char* Bb = (char*)(sh + b*16384 + 8192);
        #pragma unroll
        for (int s = 0; s < 4; ++s){
            const int off = s*4096 + soff;
            gload_lds16((const char*)(Arow[s] + kt) + colb_[s], Ab + off);
        }
        #pragma unroll
        for (int s = 0; s < 4; ++s){
            const int off = s*4096 + soff;
            const int row = off >> 7, colb = off & 127;
            gload_lds16((const char*)(Bbase + (size_t)row*K + kt) + colb, Bb + off);
        }
    };
    auto COMPUTE = [&](int b){
        const unsigned short* Ab = sh + b*16384;
        const unsigned short* Bb = sh + b*16384 + 8192;
        #pragma unroll
        for (int ks = 0; ks < 2; ++ks){
            const int k0 = ks*32 + ((lane>>4)<<3);
            bf16x8 af[4], bfr[4];
            #pragma unroll
            for (int i=0;i<4;i++) af[i]  = *(const bf16x8*)&Ab[(wm + i*16 + (lane&15))*64 + k0];
            #pragma unroll
            for (int j=0;j<4;j++) bfr[j] = *(const bf16x8*)&Bb[(wn + j*16 + (lane&15))*64 + k0];
            #pragma unroll
            for (int i=0;i<4;i++)
                #pragma unroll
                for (int j=0;j<4;j++)
                    acc[i][j] = __builtin_amdgcn_mfma_f32_16x16x32_bf16(af[i], bfr[j], acc[i][j], 0, 0, 0);
        }
    };

    STAGE(0, 0);
    __syncthreads();
    const int nk = K >> 6;
    int cur = 0;
    for (int i = 0; i < nk; ++i){
        if (i + 1 < nk) STAGE(cur ^ 1, (i + 1) << 6);
        COMPUTE(cur);
        __syncthreads();
        cur ^= 1;
    }

    const int r0 = ((lane>>4)<<2);
    const int cc = lane & 15;
    unsigned short* Ct = sh;
    float bcol[4];
    #pragma unroll
    for (int j=0;j<4;j++) bcol[j] = bias[bn*128 + wn + j*16 + cc];
    #pragma unroll
    for (int i=0;i<4;i++){
        #pragma unroll
        for (int r=0;r<4;r++){
            const int rl = wm + i*16 + r0 + r;
            float g = 1.0f;
            if (MEPI == MEPI_GATED) g = gslot[m0 + rl];
            #pragma unroll
            for (int j=0;j<4;j++){
                float v = acc[i][j][r] + bcol[j];
                if (MEPI == MEPI_GELU) v = geluf(v);
                else                   v = v * g;
                Ct[rl*128 + wn + j*16 + cc] = f2bf(v);
            }
        }
    }
    __syncthreads();
    const int orow = tid >> 4;
    const int ocol = (tid & 15) * 8;
    #pragma unroll
    for (int p = 0; p < 8; ++p){
        const int row = p*16 + orow;
        *(u16x4*)(&out[(size_t)(m0 + row)*N + bn*128 + ocol])     = *(u16x4*)&Ct[row*128 + ocol];
        *(u16x4*)(&out[(size_t)(m0 + row)*N + bn*128 + ocol + 4]) = *(u16x4*)&Ct[row*128 + ocol + 4];
    }
}

// ---------------- LayerNorm (fp32 in, bf16 out), one wave per row ---------
__global__ void ln_kernel(const float* __restrict__ x, const float* __restrict__ w,
                          const float* __restrict__ b, unsigned short* __restrict__ out)
{
    const int lane = threadIdx.x & 63;
    const int wave = threadIdx.x >> 6;
    const int row  = blockIdx.x * 4 + wave;
    const float* xr = x + (size_t)row * D_DIM;
    f32x4 v0 = *(const f32x4*)(xr + lane*8);
    f32x4 v1 = *(const f32x4*)(xr + lane*8 + 4);
    float s  = v0[0]+v0[1]+v0[2]+v0[3] + v1[0]+v1[1]+v1[2]+v1[3];
    float s2 = v0[0]*v0[0]+v0[1]*v0[1]+v0[2]*v0[2]+v0[3]*v0[3]
             + v1[0]*v1[0]+v1[1]*v1[1]+v1[2]*v1[2]+v1[3]*v1[3];
    #pragma unroll
    for (int o = 32; o > 0; o >>= 1){ s += __shfl_xor(s, o); s2 += __shfl_xor(s2, o); }
    const float mean = s * (1.0f/512.0f);
    const float var  = s2 * (1.0f/512.0f) - mean*mean;
    const float inv  = 1.0f / sqrtf(var + 1e-5f);
    const int k = lane*8;
    u16x4 o0, o1;
    #pragma unroll
    for (int j=0;j<4;j++) o0[j] = f2bf((v0[j]-mean)*inv*w[k+j]   + b[k+j]);
    #pragma unroll
    for (int j=0;j<4;j++) o1[j] = f2bf((v1[j]-mean)*inv*w[k+4+j] + b[k+4+j]);
    *(u16x4*)(out + (size_t)row*D_DIM + k)     = o0;
    *(u16x4*)(out + (size_t)row*D_DIM + k + 4) = o1;
}

// ------- Router: softmax+eps-mix+top2 (NO global atomics), zbf, bsums -----
__global__ void router_kernel(const float* __restrict__ z, const float* __restrict__ rw,
                              const float* __restrict__ rb, unsigned short* __restrict__ zbf,
                              int2* __restrict__ idx2, float2* __restrict__ wts2,
                              float* __restrict__ bsums)
{
    __shared__ float ps[4][8];
    const int lane = threadIdx.x & 63;
    const int wave = threadIdx.x >> 6;
    const int row  = blockIdx.x * 4 + wave;
    const float* zr = z + (size_t)row * D_DIM;
    f32x4 z0 = *(const f32x4*)(zr + lane*8);
    f32x4 z1 = *(const f32x4*)(zr + lane*8 + 4);
    {
        u16x4 o0, o1;
        #pragma unroll
        for (int j=0;j<4;j++){ o0[j] = f2bf(z0[j]); o1[j] = f2bf(z1[j]); }
        *(u16x4*)(zbf + (size_t)row*D_DIM + lane*8)     = o0;
        *(u16x4*)(zbf + (size_t)row*D_DIM + lane*8 + 4) = o1;
    }
    float acc[8] = {0,0,0,0,0,0,0,0};
    #pragma unroll
    for (int j = 0; j < 8; ++j){
        const float zv = (j < 4) ? z0[j] : z1[j-4];
        const float* wr = rw + (size_t)(lane*8 + j) * 8;
        f32x4 w0 = *(const f32x4*)wr;
        f32x4 w1 = *(const f32x4*)(wr + 4);
        acc[0] += zv*w0[0]; acc[1] += zv*w0[1]; acc[2] += zv*w0[2]; acc[3] += zv*w0[3];
        acc[4] += zv*w1[0]; acc[5] += zv*w1[1]; acc[6] += zv*w1[2]; acc[7] += zv*w1[3];
    }
    #pragma unroll
    for (int o = 32; o > 0; o >>= 1){
        #pragma unroll
        for (int e = 0; e < 8; ++e) acc[e] += __shfl_xor(acc[e], o);
    }
    if (lane == 0){
        float p[8]; float mx = -1e30f;
        #pragma unroll
        for (int e=0;e<8;e++){ p[e] = acc[e] + rb[e]; mx = fmaxf(mx, p[e]); }
        float se = 0.f;
        #pragma unroll
        for (int e=0;e<8;e++){ p[e] = expf(p[e]-mx); se += p[e]; }
        const float sc = 0.9f / se;
        #pragma unroll
        for (int e=0;e<8;e++) p[e] = p[e]*sc + 0.0125f;
        int i1 = 0;
        #pragma unroll
        for (int e=1;e<8;e++) if (p[e] > p[i1]) i1 = e;
        int i2 = (i1 == 0) ? 1 : 0;
        for (int e=i2+1;e<8;e++) if (e != i1 && p[e] > p[i2]) i2 = e;
        idx2[row] = make_int2(i1, i2);
        wts2[row] = make_float2(p[i1], p[i2]);
        #pragma unroll
        for (int e=0;e<8;e++) ps[wave][e] = p[e];
    }
    __syncthreads();
    if (threadIdx.x < 8){
        bsums[blockIdx.x*8 + threadIdx.x] =
            ps[0][threadIdx.x] + ps[1][threadIdx.x] + ps[2][threadIdx.x] + ps[3][threadIdx.x];
    }
}

// ------- histogram: per-block expert counts via LDS (no global atomics) ---
__global__ void hist_kernel(const int2* __restrict__ idx2, int* __restrict__ blockHist){
    __shared__ int hc[8];
    if (threadIdx.x < 8) hc[threadIdx.x] = 0;
    __syncthreads();
    const int t = blockIdx.x * 256 + threadIdx.x;
    const int2 ii = idx2[t];
    atomicAdd(&hc[ii.x], 1);
    atomicAdd(&hc[ii.y], 1);
    __syncthreads();
    if (threadIdx.x < 8) blockHist[blockIdx.x*8 + threadIdx.x] = hc[threadIdx.x];
}

// ------- scan: padded expert offsets + per-block bases (1 thread) ---------
__global__ void scan_kernel(const int* __restrict__ blockHist, int* __restrict__ offs,
                            int* __restrict__ baseArr){
    if (threadIdx.x == 0){
        int counts[8];
        #pragma unroll
        for (int e=0;e<8;e++) counts[e] = 0;
        for (int b=0;b<NHBLK;b++)
            #pragma unroll
            for (int e=0;e<8;e++) counts[e] += blockHist[b*8+e];
        int o = 0; offs[0] = 0;
        int start[8];
        #pragma unroll
        for (int e=0;e<8;e++){ start[e] = o; o += (counts[e]+127)&~127; offs[e+1] = o; }
        for (int e=0;e<8;e++){
            int cur = start[e];
            for (int b=0;b<NHBLK;b++){ baseArr[b*8+e] = cur; cur += blockHist[b*8+e]; }
        }
    }
}

// ------- assign: block-local LDS cursors -> slots (no global atomics) -----
__global__ void assign_kernel(const int2* __restrict__ idx2, const float2* __restrict__ wts2,
                              const int* __restrict__ baseArr, int2* __restrict__ slot_map,
                              float* __restrict__ gslot, int* __restrict__ tok)
{
    __shared__ int cur[8];
    if (threadIdx.x < 8) cur[threadIdx.x] = 0;
    __syncthreads();
    const int t = blockIdx.x * 256 + threadIdx.x;
    const int2 ii = idx2[t];
    const float2 ww = wts2[t];
    const int r1 = atomicAdd(&cur[ii.x], 1);
    const int r2 = atomicAdd(&cur[ii.y], 1);
    const int s1 = baseArr[blockIdx.x*8 + ii.x] + r1;
    const int s2 = baseArr[blockIdx.x*8 + ii.y] + r2;
    slot_map[t] = make_int2(s1, s2);
    gslot[s1] = ww.x; gslot[s2] = ww.y;
    tok[s1] = t; tok[s2] = t;
}

// ---------------- aux loss ------------------------------------------------
__global__ void aux_kernel(const float* __restrict__ bsums, float* __restrict__ out_aux)
{
    __shared__ float part[256];
    const int t = threadIdx.x;
    const int e = t & 7, chunk = t >> 3;
    float s = 0.f;
    for (int blk = chunk*128; blk < chunk*128 + 128; ++blk) s += bsums[blk*8 + e];
    part[t] = s;
    __syncthreads();
    if (t < 8){
        float tot = 0.f;
        for (int c = 0; c < 32; ++c) tot += part[c*8 + t];
        part[t] = tot;
    }
    __syncthreads();
    if (t == 0){
        float aux = 0.f;
        for (int e2 = 0; e2 < 8; ++e2){
            float load = part[e2] * (1.0f/16384.0f);
            aux += load * logf(load * 8.0f + 1e-9f);
        }
        out_aux[0] = aux / 2.0794415416798357f;
    }
}

// -------- head: z = h + eo[s1] + eo[s2]; LN; dot; one wave per row --------
__global__ void head_kernel(const float* __restrict__ h, const unsigned short* __restrict__ eog,
                            const int2* __restrict__ slot_map,
                            const float* __restrict__ w, const float* __restrict__ b,
                            const float* __restrict__ hw, const float* __restrict__ hb,
                            float* __restrict__ out)
{
    const int lane = threadIdx.x & 63;
    const int wave = threadIdx.x >> 6;
    const int row  = blockIdx.x * 4 + wave;
    const int2 sm = slot_map[row];
    const float* zr = h + (size_t)row * D_DIM;
    f32x4 v0 = *(const f32x4*)(zr + lane*8);
    f32x4 v1 = *(const f32x4*)(zr + lane*8 + 4);
    u16x8 e1 = *(const u16x8*)(eog + (size_t)sm.x * D_DIM + lane*8);
    u16x8 e2 = *(const u16x8*)(eog + (size_t)sm.y * D_DIM + lane*8);
    #pragma unroll
    for (int j=0;j<4;j++){ v0[j] += bf2f(e1[j]) + bf2f(e2[j]); }
    #pragma unroll
    for (int j=0;j<4;j++){ v1[j] += bf2f(e1[4+j]) + bf2f(e2[4+j]); }
    float s  = v0[0]+v0[1]+v0[2]+v0[3] + v1[0]+v1[1]+v1[2]+v1[3];
    float s2 = v0[0]*v0[0]+v0[1]*v0[1]+v0[2]*v0[2]+v0[3]*v0[3]
             + v1[0]*v1[0]+v1[1]*v1[1]+v1[2]*v1[2]+v1[3]*v1[3];
    #pragma unroll
    for (int o = 32; o > 0; o >>= 1){ s += __shfl_xor(s, o); s2 += __shfl_xor(s2, o); }
    const float mean = s * (1.0f/512.0f);
    const float var  = s2 * (1.0f/512.0f) - mean*mean;
    const float inv  = 1.0f / sqrtf(var + 1e-5f);
    const int k = lane*8;
    float dot = 0.f;
    #pragma unroll
    for (int j=0;j<4;j++) dot += ((v0[j]-mean)*inv*w[k+j]   + b[k+j])   * hw[k+j];
    #pragma unroll
    for (int j=0;j<4;j++) dot += ((v1[j]-mean)*inv*w[k+4+j] + b[k+4+j]) * hw[k+4+j];
    #pragma unroll
    for (int o = 32; o > 0; o >>= 1) dot += __shfl_xor(dot, o);
    if (lane == 0) out[row] = dot + hb[0];
}

// ===========================================================================
extern "C" void kernel_launch(void* const* d_in, const int* in_sizes, int n_in,
                              void* d_out, int out_size, void* d_ws, size_t ws_size,
                              hipStream_t stream)
{
    (void)in_sizes; (void)n_in; (void)out_size; (void)ws_size;
    const float* x         = (const float*)d_in[0];
    const float* embed_w   = (const float*)d_in[1];
    const float* embed_b   = (const float*)d_in[2];
    const float* ln1_w     = (const float*)d_in[3];
    const float* ln1_b     = (const float*)d_in[4];
    const float* inproj_w  = (const float*)d_in[5];
    const float* inproj_b  = (const float*)d_in[6];
    const float* outproj_w = (const float*)d_in[7];
    const float* outproj_b = (const float*)d_in[8];
    const float* ln2_w     = (const float*)d_in[9];
    const float* ln2_b     = (const float*)d_in[10];
    const float* ffn_w1    = (const float*)d_in[11];
    const float* ffn_b1    = (const float*)d_in[12];
    const float* ffn_w2    = (const float*)d_in[13];
    const float* ffn_b2    = (const float*)d_in[14];
    const float* router_w  = (const float*)d_in[15];
    const float* router_b  = (const float*)d_in[16];
    const float* exp_w1    = (const float*)d_in[17];
    const float* exp_b1    = (const float*)d_in[18];
    const float* exp_w2    = (const float*)d_in[19];
    const float* exp_b2    = (const float*)d_in[20];
    const float* head_ln_w = (const float*)d_in[21];
    const float* head_ln_b = (const float*)d_in[22];
    const float* head_w    = (const float*)d_in[23];
    const float* head_b    = (const float*)d_in[24];

    char* ws = (char*)d_ws;
    unsigned short* xbf   = (unsigned short*)(ws + 0);            //  4,194,304
    unsigned short* ebf   = (unsigned short*)(ws + 4194304);      //    131,072
    unsigned short* wobf  = (unsigned short*)(ws + 4325376);      //  1,572,864 outproj bf16
    unsigned short* wvtbf = (unsigned short*)(ws + 5898240);      //  1,572,864 Wv^T bf16
    unsigned short* wfold = (unsigned short*)(ws + 7471104);      //  1,572,864 (Wo@Wv) (N,K) bf16
    unsigned short* w1t   = (unsigned short*)(ws + 9043968);      //  6,291,456
    unsigned short* w2t   = (unsigned short*)(ws + 15335424);     //  6,291,456
    unsigned short* e1t   = (unsigned short*)(ws + 21626880);     //  2,097,152
    unsigned short* e2t   = (unsigned short*)(ws + 23724032);     //  2,097,152
    float*          h     = (float*)(ws + 25821184);              // 33,554,432
    unsigned short* gbf   = (unsigned short*)(ws + 59375616);     // 16,777,216 (ln out; later zbf)
    unsigned short* ubf   = (unsigned short*)(ws + 76152832);     // 67,108,864 (ffn1 out)
    unsigned short* hmidg = ubf;                                  // (after ffn use)
    unsigned short* eog   = (unsigned short*)(ws + 93454336);     // 34,603,008
    char* MISC = ws + 143261696;
    int*    offs     = (int*)(MISC + 0);           // 64 B
    float*  zbias    = (float*)(MISC + 256);       // 2048 B, zeroed
    float*  bfold    = (float*)(MISC + 2304);      // 6144 B
    int2*   idx2     = (int2*)(MISC + 8448);       // 131072
    float2* wts2     = (float2*)(MISC + 139520);   // 131072
    int2*   slot_map = (int2*)(MISC + 270592);     // 131072
    float*  gslot    = (float*)(MISC + 401664);    // 135168
    int*    tok      = (int*)(MISC + 536832);      // 135168, zeroed
    float*  bsums    = (float*)(MISC + 672000);    // 131072
    int*    blockHist= (int*)(MISC + 803072);      // 2048
    int*    baseArr  = (int*)(MISC + 805120);      // 2048
    unsigned short* zbf = gbf;
    float* out = (float*)d_out;

    // ---- reset control state (zbias + tok) ----
    zero_kernel<<<(MAXSLOT + 255)/256, 256, 0, stream>>>((int*)zbias, 512, tok, MAXSLOT);

    // ---- weight prep ----
    ConvArgs ca;
    ca.seg[0] = { x, xbf, B_TOK*IN_DIM/4 };
    ca.seg[1] = { outproj_w, wobf, DEPTH*D_DIM*D_DIM/4 };
    convert_kernel<<<1024, 256, 0, stream>>>(ca);

    TArgs ta;
    int tcur = 0, ti = 0;
    ta.seg[ti] = { embed_w, ebf, IN_DIM, D_DIM, tcur };
    tcur += (IN_DIM/32)*(D_DIM/32); ++ti;
    for (int l = 0; l < DEPTH; ++l){
        ta.seg[ti] = { ffn_w1 + (size_t)l*D_DIM*FF_DIM, w1t + (size_t)l*FF_DIM*D_DIM, D_DIM, FF_DIM, tcur };
        tcur += (D_DIM/32)*(FF_DIM/32); ++ti;
    }
    for (int l = 0; l < DEPTH; ++l){
        ta.seg[ti] = { ffn_w2 + (size_t)l*FF_DIM*D_DIM, w2t + (size_t)l*D_DIM*FF_DIM, FF_DIM, D_DIM, tcur };
        tcur += (FF_DIM/32)*(D_DIM/32); ++ti;
    }
    for (int e = 0; e < NEXP; ++e){
        ta.seg[ti] = { exp_w1 + (size_t)e*D_DIM*EH_DIM, e1t + (size_t)e*EH_DIM*D_DIM, D_DIM, EH_DIM, tcur };
        tcur += (D_DIM/32)*(EH_DIM/32); ++ti;
    }
    for (int e = 0; e < NEXP; ++e){
        ta.seg[ti] = { exp_w2 + (size_t)e*EH_DIM*D_DIM, e2t + (size_t)e*D_DIM*EH_DIM, EH_DIM, D_DIM, tcur };
        tcur += (EH_DIM/32)*(D_DIM/32); ++ti;
    }
    for (int l = 0; l < DEPTH; ++l){
        ta.seg[ti] = { inproj_w + (size_t)l*3*D_DIM*D_DIM + 2*D_DIM*D_DIM,
                       wvtbf + (size_t)l*D_DIM*D_DIM, D_DIM, D_DIM, tcur };
        tcur += (D_DIM/32)*(D_DIM/32); ++ti;
    }
    transpose_kernel<<<tcur, 256, 0, stream>>>(ta);

    foldb_kernel<<<DEPTH, D_DIM, 0, stream>>>(outproj_w, outproj_b, inproj_b, bfold);

    const dim3 blk(256);
    for (int l = 0; l < DEPTH; ++l){
        gemm_bt<EPI_BF16><<<16, blk, 0, stream>>>(
            wobf + (size_t)l*D_DIM*D_DIM, wvtbf + (size_t)l*D_DIM*D_DIM,
            zbias, nullptr, wfold + (size_t)l*D_DIM*D_DIM, 4, D_DIM, D_DIM);
    }

    gemm_bt<EPI_F32_BIAS><<<(D_DIM/128)*(B_TOK/128), blk, 0, stream>>>(
        xbf, ebf, embed_b, nullptr, h, D_DIM/128, D_DIM, IN_DIM);

    for (int l = 0; l < DEPTH; ++l){
        ln_kernel<<<B_TOK/4, 256, 0, stream>>>(h, ln1_w + l*D_DIM, ln1_b + l*D_DIM, gbf);
        gemm_bt<EPI_F32_RESID><<<(D_DIM/128)*(B_TOK/128), blk, 0, stream>>>(
            gbf, wfold + (size_t)l*D_DIM*D_DIM, bfold + l*D_DIM, h, h, D_DIM/128, D_DIM, D_DIM);
        ln_kernel<<<B_TOK/4, 256, 0, stream>>>(h, ln2_w + l*D_DIM, ln2_b + l*D_DIM, gbf);
        gemm_bt<EPI_BF16_GELU><<<(FF_DIM/128)*(B_TOK/128), blk, 0, stream>>>(
            gbf, w1t + (size_t)l*FF_DIM*D_DIM, ffn_b1 + l*FF_DIM, nullptr, ubf, FF_DIM/128, FF_DIM, D_DIM);
        gemm_bt<EPI_F32_RESID><<<(D_DIM/128)*(B_TOK/128), blk, 0, stream>>>(
            ubf, w2t + (size_t)l*D_DIM*FF_DIM, ffn_b2 + l*D_DIM, h, h, D_DIM/128, D_DIM, FF_DIM);
    }

    router_kernel<<<B_TOK/4, 256, 0, stream>>>(h, router_w, router_b, zbf, idx2, wts2, bsums);
    aux_kernel<<<1, 256, 0, stream>>>(bsums, out + B_TOK);
    hist_kernel<<<NHBLK, 256, 0, stream>>>(idx2, blockHist);
    scan_kernel<<<1, 64, 0, stream>>>(blockHist, offs, baseArr);
    assign_kernel<<<NHBLK, 256, 0, stream>>>(idx2, wts2, baseArr, slot_map, gslot, tok);

    gemm_moe<MEPI_GELU, 1><<<(EH_DIM/128)*MAXTILE, blk, 0, stream>>>(
        zbf, tok, offs, e1t, EH_DIM*D_DIM, exp_b1, EH_DIM, nullptr, hmidg, EH_DIM/128, EH_DIM, D_DIM);
    gemm_moe<MEPI_GATED, 0><<<(D_DIM/128)*MAXTILE, blk, 0, stream>>>(
        hmidg, nullptr, offs, e2t, D_DIM*EH_DIM, exp_b2, D_DIM, gslot, eog, D_DIM/128, D_DIM, EH_DIM);

    head_kernel<<<B_TOK/4, 256, 0, stream>>>(h, eog, slot_map, head_ln_w, head_ln_b, head_w, head_b, out);
}

// Round 5
// 679.200 us; speedup vs baseline: 1.7219x; 1.0269x over previous
//
#include <hip/hip_runtime.h>
#include <hip/hip_bf16.h>

#define B_TOK 16384
#define IN_DIM 128
#define D_DIM 512
#define DEPTH 3
#define NEXP 8
#define FF_DIM 2048
#define EH_DIM 256
#define MAXSLOT 34816   // 32768 + 8*256, 256-padded expert segments
#define MAXT256 136     // MAXSLOT/256
#define NHBLK 64

typedef __attribute__((ext_vector_type(8))) __bf16 bf16x8;
typedef __attribute__((ext_vector_type(4))) float f32x4;
typedef __attribute__((ext_vector_type(4))) unsigned short u16x4;
typedef __attribute__((ext_vector_type(8))) unsigned short u16x8;

__device__ __forceinline__ unsigned short f2bf(float f){
    unsigned int u = __float_as_uint(f);
    u += 0x7fffu + ((u >> 16) & 1u);
    return (unsigned short)(u >> 16);
}
__device__ __forceinline__ float bf2f(unsigned short u){
    return __uint_as_float(((unsigned int)u) << 16);
}
__device__ __forceinline__ float geluf(float x){
    return 0.5f * x * (1.0f + erff(x * 0.70710678118654752f));
}
__device__ __forceinline__ void gload_lds16(const void* g, void* l){
    __builtin_amdgcn_global_load_lds((const __attribute__((address_space(1))) unsigned int*)g,
                                     (__attribute__((address_space(3))) unsigned int*)l,
                                     16, 0, 0);
}
__device__ __forceinline__ int xcd_swizzle(int orig, int nwg){
    const int q = nwg >> 3, r = nwg & 7;
    const int xcd = orig & 7;
    const int idx = orig >> 3;
    return (xcd < r ? xcd*(q+1) : r*(q+1) + (xcd-r)*q) + idx;
}
__device__ __forceinline__ void wgbar(){
    asm volatile("" ::: "memory");
    __builtin_amdgcn_s_barrier();
    asm volatile("" ::: "memory");
}

// ---------------- zero scratch control state ------------------------------
__global__ void zero_kernel(int* a, int na, int* b, int nb){
    const int i = blockIdx.x * blockDim.x + threadIdx.x;
    if (i < na) a[i] = 0;
    if (i < nb) b[i] = 0;
}

// ---------------- fp32 -> bf16 convert ------------------------------------
struct ConvSeg { const float* src; unsigned short* dst; int n4; };
struct ConvArgs { ConvSeg seg[2]; };

__global__ void convert_kernel(ConvArgs a){
    const int stride = gridDim.x * blockDim.x;
    const int tid = blockIdx.x * blockDim.x + threadIdx.x;
    for (int s = 0; s < 2; ++s){
        const f32x4* src = (const f32x4*)a.seg[s].src;
        u16x4* dst = (u16x4*)a.seg[s].dst;
        const int n4 = a.seg[s].n4;
        for (int i = tid; i < n4; i += stride){
            f32x4 v = src[i];
            u16x4 o;
            o[0] = f2bf(v[0]); o[1] = f2bf(v[1]); o[2] = f2bf(v[2]); o[3] = f2bf(v[3]);
            dst[i] = o;
        }
    }
}

// ------------- weight transpose-convert: (K,N) fp32 -> (N,K) bf16 ---------
struct TSeg { const float* src; unsigned short* dst; int K; int N; int tileStart; };
struct TArgs { TSeg seg[26]; };

__global__ void transpose_kernel(TArgs a){
    __shared__ float t[32][33];
    const int tile = blockIdx.x;
    int s = 0;
    #pragma unroll 1
    while (s < 25 && tile >= a.seg[s+1].tileStart) ++s;
    const TSeg sg = a.seg[s];
    const int local = tile - sg.tileStart;
    const int tilesN = sg.N >> 5;
    const int k0 = (local / tilesN) << 5;
    const int n0 = (local % tilesN) << 5;
    const int tx = threadIdx.x & 31;
    const int ty = threadIdx.x >> 5;
    #pragma unroll
    for (int j = 0; j < 4; ++j)
        t[ty + j*8][tx] = sg.src[(size_t)(k0 + ty + j*8) * sg.N + n0 + tx];
    __syncthreads();
    #pragma unroll
    for (int j = 0; j < 4; ++j){
        const int n = ty + j*8;
        sg.dst[(size_t)(n0 + n) * sg.K + k0 + tx] = f2bf(t[tx][n]);
    }
}

// ---------------- folded attention bias: bfold = Wo@bv + bo ---------------
__global__ void foldb_kernel(const float* __restrict__ outproj_w, const float* __restrict__ outproj_b,
                             const float* __restrict__ inproj_b, float* __restrict__ bfold){
    const int l = blockIdx.x, n = threadIdx.x;
    const float* Wo = outproj_w + ((size_t)l*D_DIM + n)*D_DIM;
    const float* bv = inproj_b + l*3*D_DIM + 2*D_DIM;
    float acc = outproj_b[l*D_DIM + n];
    for (int j = 0; j < D_DIM; ++j) acc += Wo[j]*bv[j];
    bfold[l*D_DIM + n] = acc;
}

// ---------------- small GEMM (embed/fold): 128x128, dbuf ------------------
#define EPI_BF16 0
#define EPI_F32_BIAS 2

template<int EPI>
__global__ void __launch_bounds__(256, 2)
gemm_bt(const unsigned short* __restrict__ A, const unsigned short* __restrict__ Bt,
        const float* __restrict__ bias, void* __restrict__ out, int NB, int N, int K)
{
    __shared__ unsigned short sh[32768];
    const int nwg = gridDim.x;
    const int wg  = xcd_swizzle(blockIdx.x, nwg);
    const int bn  = wg % NB;
    const int bm  = wg / NB;

    const int tid  = threadIdx.x;
    const int lane = tid & 63;
    const int wave = tid >> 6;
    const int wm = (wave >> 1) << 6;
    const int wn = (wave & 1) << 6;

    f32x4 acc[4][4] = {};

    const unsigned short* Abase = A + (size_t)bm * 128 * K;
    const unsigned short* Bbase = Bt + (size_t)bn * 128 * K;
    const int soff = tid * 16;

    auto STAGE = [&](int b, int kt){
        char* Ab = (char*)(sh + b*16384);
        char* Bb = (char*)(sh + b*16384 + 8192);
        #pragma unroll
        for (int s = 0; s < 4; ++s){
            const int off = s*4096 + soff;
            const int row = off >> 7, colb = off & 127;
            gload_lds16((const char*)(Abase + (size_t)row*K + kt) + colb, Ab + off);
        }
        #pragma unroll
        for (int s = 0; s < 4; ++s){
            const int off = s*4096 + soff;
            const int row = off >> 7, colb = off & 127;
            gload_lds16((const char*)(Bbase + (size_t)row*K + kt) + colb, Bb + off);
        }
    };
    auto COMPUTE = [&](int b){
        const unsigned short* Ab = sh + b*16384;
        const unsigned short* Bb = sh + b*16384 + 8192;
        #pragma unroll
        for (int ks = 0; ks < 2; ++ks){
            const int k0 = ks*32 + ((lane>>4)<<3);
            bf16x8 af[4], bfr[4];
            #pragma unroll
            for (int i=0;i<4;i++) af[i]  = *(const bf16x8*)&Ab[(wm + i*16 + (lane&15))*64 + k0];
            #pragma unroll
            for (int j=0;j<4;j++) bfr[j] = *(const bf16x8*)&Bb[(wn + j*16 + (lane&15))*64 + k0];
            #pragma unroll
            for (int i=0;i<4;i++)
                #pragma unroll
                for (int j=0;j<4;j++)
                    acc[i][j] = __builtin_amdgcn_mfma_f32_16x16x32_bf16(af[i], bfr[j], acc[i][j], 0, 0, 0);
        }
    };

    STAGE(0, 0);
    __syncthreads();
    const int nk = K >> 6;
    int cur = 0;
    for (int i = 0; i < nk; ++i){
        if (i + 1 < nk) STAGE(cur ^ 1, (i + 1) << 6);
        COMPUTE(cur);
        __syncthreads();
        cur ^= 1;
    }

    const int r0 = ((lane>>4)<<2);
    const int cc = lane & 15;

    if (EPI == EPI_F32_BIAS){
        #pragma unroll
        for (int j=0;j<4;j++){
            const int col = bn*128 + wn + j*16 + cc;
            const float bv = bias[col];
            #pragma unroll
            for (int i=0;i<4;i++)
                #pragma unroll
                for (int r=0;r<4;r++){
                    const int row = bm*128 + wm + i*16 + r0 + r;
                    ((float*)out)[(size_t)row * N + col] = acc[i][j][r] + bv;
                }
        }
    } else {
        unsigned short* Ct = sh;
        float bcol[4];
        #pragma unroll
        for (int j=0;j<4;j++) bcol[j] = bias[bn*128 + wn + j*16 + cc];
        #pragma unroll
        for (int i=0;i<4;i++)
            #pragma unroll
            for (int r=0;r<4;r++){
                const int rl = wm + i*16 + r0 + r;
                #pragma unroll
                for (int j=0;j<4;j++)
                    Ct[rl*128 + wn + j*16 + cc] = f2bf(acc[i][j][r] + bcol[j]);
            }
        __syncthreads();
        const int orow = tid >> 4;
        const int ocol = (tid & 15) * 8;
        unsigned short* op = (unsigned short*)out;
        #pragma unroll
        for (int p = 0; p < 8; ++p){
            const int row = p*16 + orow;
            *(u16x4*)(&op[(size_t)(bm*128 + row)*N + bn*128 + ocol])     = *(u16x4*)&Ct[row*128 + ocol];
            *(u16x4*)(&op[(size_t)(bm*128 + row)*N + bn*128 + ocol + 4]) = *(u16x4*)&Ct[row*128 + ocol + 4];
        }
    }
}

// =================== 256x128 4-phase pipelined GEMM =======================
// BM=256 BN=128 BK=64, 512 thr (8 waves 4Mx2N), LDS 96KB dbuf, T2 swizzle,
// counted vmcnt (T4), setprio (T5). C = A(M,K) @ Bt(N,K)^T.
#define G_GELU_BF16 0
#define G_F32_RESID 1
#define G_GATED_BF16 2
#define ASZ 32768
#define BSZ 16384

template<int EPI, int MOE, int INDIRECT>
__global__ void __launch_bounds__(512, 2)
gemm256(const unsigned short* __restrict__ A, const unsigned short* __restrict__ BtG,
        const float* __restrict__ biasG, const float* __restrict__ resid,
        const int* __restrict__ tok, const int* __restrict__ offs,
        int wstride, int bstride, const float* __restrict__ gslot,
        void* __restrict__ out, int NB, int N, int K)
{
    __shared__ __align__(16) char sh[98304];  // A0,A1 @0/32K; B0,B1 @64K/80K
    const int nwg = gridDim.x;
    const int wg  = xcd_swizzle(blockIdx.x, nwg);
    const int bn  = wg % NB;
    const int bm  = wg / NB;
    const int m0  = bm * 256;

    const unsigned short* Bt = BtG;
    const float* bias = biasG;
    if (MOE){
        if (m0 >= offs[8]) return;
        int e = 0;
        #pragma unroll 1
        while (offs[e+1] <= m0) ++e;
        Bt   += (size_t)e * wstride;
        bias += (size_t)e * bstride;
    }

    const int tid = threadIdx.x, lane = tid & 63, wave = tid >> 6;
    const int wm = (wave >> 1) * 64;   // 0,64,128,192
    const int wn = (wave & 1) * 64;    // 0,64

    // ---- staging: linear LDS dest, inverse-swizzled global source --------
    const int srow = wave*16 + (lane >> 3);                  // + l*8 (+ u*128)
    const int scol = ((lane & 7) ^ (lane >> 3)) * 8;         // element offset
    const unsigned short* aptr[2][2];
    #pragma unroll
    for (int u = 0; u < 2; ++u)
        #pragma unroll
        for (int l = 0; l < 2; ++l){
            const int r = u*128 + srow + l*8;
            const int gr = INDIRECT ? tok[m0 + r] : (m0 + r);
            aptr[u][l] = A + (size_t)gr * K + scol;
        }
    const unsigned short* bptr[2];
    #pragma unroll
    for (int l = 0; l < 2; ++l)
        bptr[l] = Bt + (size_t)(bn*128 + srow + l*8) * K + scol;
    const int sdst = wave*2048 + lane*16;

    // ---- swizzled read offsets (bytes) -----------------------------------
    int aoff[2], boff[2];
    #pragma unroll
    for (int ks = 0; ks < 2; ++ks){
        const int ch = (((ks<<2) + (lane>>4)) ^ (lane & 7)) << 4;
        aoff[ks] = (wm + (lane & 15))*128 + ch;
        boff[ks] = (wn + (lane & 15))*128 + ch;
    }

    f32x4 acc[4][4] = {};
    bf16x8 bfr[4][2];

    auto STA = [&](int buf, int kt){
        #pragma unroll
        for (int u = 0; u < 2; ++u)
            #pragma unroll
            for (int l = 0; l < 2; ++l)
                gload_lds16(aptr[u][l] + kt, sh + buf*ASZ + u*16384 + l*1024 + sdst);
    };
    auto STB = [&](int buf, int kt){
        #pragma unroll
        for (int l = 0; l < 2; ++l)
            gload_lds16(bptr[l] + kt, sh + 65536 + buf*BSZ + l*1024 + sdst);
    };
    auto RDB = [&](int buf){
        #pragma unroll
        for (int nf = 0; nf < 4; ++nf)
            #pragma unroll
            for (int ks = 0; ks < 2; ++ks)
                bfr[nf][ks] = *(const bf16x8*)(sh + 65536 + buf*BSZ + nf*2048 + boff[ks]);
    };

    // ---- prologue: tile0 (A,B) + tile1 (B); leave B1 in flight -----------
    STA(0, 0);
    STB(0, 0);
    STB(1, 64);
    asm volatile("s_waitcnt vmcnt(2)" ::: "memory");
    wgbar();

    const int NT = K >> 7;   // 2 K-tiles per iteration
    for (int u = 0; u < NT; ++u){
        const int kb = u << 7;
        const bool more = (u + 1 < NT);
        bf16x8 af[2][2];

        // P1: buf0 m{0,1} + B; stage A->buf1 (tile kb+64)
        RDB(0);
        #pragma unroll
        for (int m2 = 0; m2 < 2; ++m2)
            #pragma unroll
            for (int ks = 0; ks < 2; ++ks)
                af[m2][ks] = *(const bf16x8*)(sh + 0*ASZ + (0+m2)*2048 + aoff[ks]);
        STA(1, kb + 64);
        wgbar();
        __builtin_amdgcn_s_setprio(1);
        #pragma unroll
        for (int m2 = 0; m2 < 2; ++m2)
            #pragma unroll
            for (int nf = 0; nf < 4; ++nf)
                #pragma unroll
                for (int ks = 0; ks < 2; ++ks)
                    acc[0+m2][nf] = __builtin_amdgcn_mfma_f32_16x16x32_bf16(af[m2][ks], bfr[nf][ks], acc[0+m2][nf], 0,0,0);
        __builtin_amdgcn_s_setprio(0);
        wgbar();

        // P2: buf0 m{2,3}; stage B->buf0 (tile kb+128); counted vmcnt
        #pragma unroll
        for (int m2 = 0; m2 < 2; ++m2)
            #pragma unroll
            for (int ks = 0; ks < 2; ++ks)
                af[m2][ks] = *(const bf16x8*)(sh + 0*ASZ + (2+m2)*2048 + aoff[ks]);
        if (more){
            STB(0, kb + 128);
            asm volatile("s_waitcnt vmcnt(2)" ::: "memory");
        } else {
            asm volatile("s_waitcnt vmcnt(0)" ::: "memory");
        }
        wgbar();
        __builtin_amdgcn_s_setprio(1);
        #pragma unroll
        for (int m2 = 0; m2 < 2; ++m2)
            #pragma unroll
            for (int nf = 0; nf < 4; ++nf)
                #pragma unroll
                for (int ks = 0; ks < 2; ++ks)
                    acc[2+m2][nf] = __builtin_amdgcn_mfma_f32_16x16x32_bf16(af[m2][ks], bfr[nf][ks], acc[2+m2][nf], 0,0,0);
        __builtin_amdgcn_s_setprio(0);
        wgbar();

        // P3: buf1 m{0,1} + B; stage A->buf0 (tile kb+128)
        RDB(1);
        #pragma unroll
        for (int m2 = 0; m2 < 2; ++m2)
            #pragma unroll
            for (int ks = 0; ks < 2; ++ks)
                af[m2][ks] = *(const bf16x8*)(sh + 1*ASZ + (0+m2)*2048 + aoff[ks]);
        if (more) STA(0, kb + 128);
        wgbar();
        __builtin_amdgcn_s_setprio(1);
        #pragma unroll
        for (int m2 = 0; m2 < 2; ++m2)
            #pragma unroll
            for (int nf = 0; nf < 4; ++nf)
                #pragma unroll
                for (int ks = 0; ks < 2; ++ks)
                    acc[0+m2][nf] = __builtin_amdgcn_mfma_f32_16x16x32_bf16(af[m2][ks], bfr[nf][ks], acc[0+m2][nf], 0,0,0);
        __builtin_amdgcn_s_setprio(0);
        wgbar();

        // P4: buf1 m{2,3}; stage B->buf1 (tile kb+192); counted vmcnt
        #pragma unroll
        for (int m2 = 0; m2 < 2; ++m2)
            #pragma unroll
            for (int ks = 0; ks < 2; ++ks)
                af[m2][ks] = *(const bf16x8*)(sh + 1*ASZ + (2+m2)*2048 + aoff[ks]);
        if (more) STB(1, kb + 192);
        asm volatile("s_waitcnt vmcnt(2)" ::: "memory");
        wgbar();
        __builtin_amdgcn_s_setprio(1);
        #pragma unroll
        for (int m2 = 0; m2 < 2; ++m2)
            #pragma unroll
            for (int nf = 0; nf < 4; ++nf)
                #pragma unroll
                for (int ks = 0; ks < 2; ++ks)
                    acc[2+m2][nf] = __builtin_amdgcn_mfma_f32_16x16x32_bf16(af[m2][ks], bfr[nf][ks], acc[2+m2][nf], 0,0,0);
        __builtin_amdgcn_s_setprio(0);
        wgbar();
    }

    // ---- epilogue --------------------------------------------------------
    const int r4 = (lane >> 4) * 4;
    const int cc = lane & 15;
    if (EPI == G_F32_RESID){
        #pragma unroll
        for (int nf = 0; nf < 4; ++nf){
            const int col = bn*128 + wn + nf*16 + cc;
            const float bv = bias[col];
            #pragma unroll
            for (int mf = 0; mf < 4; ++mf)
                #pragma unroll
                for (int r = 0; r < 4; ++r){
                    const int row = m0 + wm + mf*16 + r4 + r;
                    const size_t idx = (size_t)row * N + col;
                    ((float*)out)[idx] = resid[idx] + acc[mf][nf][r] + bv;
                }
        }
    } else {
        unsigned short* ct = (unsigned short*)sh;  // 256x128 bf16 = 64KB
        #pragma unroll
        for (int nf = 0; nf < 4; ++nf){
            const float bv = bias[bn*128 + wn + nf*16 + cc];
            #pragma unroll
            for (int mf = 0; mf < 4; ++mf)
                #pragma unroll
                for (int r = 0; r < 4; ++r){
                    const int row = wm + mf*16 + r4 + r;
                    float v = acc[mf][nf][r] + bv;
                    if (EPI == G_GELU_BF16) v = geluf(v);
                    else                    v *= gslot[m0 + row];
                    ct[row*128 + wn + nf*16 + cc] = f2bf(v);
                }
        }
        __syncthreads();
        unsigned short* op = (unsigned short*)out;
        #pragma unroll
        for (int p = 0; p < 8; ++p){
            const int uidx = p*512 + tid;
            const int row = uidx >> 4;
            const int cu  = uidx & 15;
            *(u16x8*)(op + (size_t)(m0 + row)*N + bn*128 + cu*8) =
                *(const u16x8*)(ct + row*128 + cu*8);
        }
    }
}

// ---------------- LayerNorm (fp32 in, bf16 out), one wave per row ---------
__global__ void ln_kernel(const float* __restrict__ x, const float* __restrict__ w,
                          const float* __restrict__ b, unsigned short* __restrict__ out)
{
    const int lane = threadIdx.x & 63;
    const int wave = threadIdx.x >> 6;
    const int row  = blockIdx.x * 4 + wave;
    const float* xr = x + (size_t)row * D_DIM;
    f32x4 v0 = *(const f32x4*)(xr + lane*8);
    f32x4 v1 = *(const f32x4*)(xr + lane*8 + 4);
    float s  = v0[0]+v0[1]+v0[2]+v0[3] + v1[0]+v1[1]+v1[2]+v1[3];
    float s2 = v0[0]*v0[0]+v0[1]*v0[1]+v0[2]*v0[2]+v0[3]*v0[3]
             + v1[0]*v1[0]+v1[1]*v1[1]+v1[2]*v1[2]+v1[3]*v1[3];
    #pragma unroll
    for (int o = 32; o > 0; o >>= 1){ s += __shfl_xor(s, o); s2 += __shfl_xor(s2, o); }
    const float mean = s * (1.0f/512.0f);
    const float var  = s2 * (1.0f/512.0f) - mean*mean;
    const float inv  = 1.0f / sqrtf(var + 1e-5f);
    const int k = lane*8;
    u16x4 o0, o1;
    #pragma unroll
    for (int j=0;j<4;j++) o0[j] = f2bf((v0[j]-mean)*inv*w[k+j]   + b[k+j]);
    #pragma unroll
    for (int j=0;j<4;j++) o1[j] = f2bf((v1[j]-mean)*inv*w[k+4+j] + b[k+4+j]);
    *(u16x4*)(out + (size_t)row*D_DIM + k)     = o0;
    *(u16x4*)(out + (size_t)row*D_DIM + k + 4) = o1;
}

// ------- Router: softmax+eps-mix+top2 (no global atomics) -----------------
__global__ void router_kernel(const float* __restrict__ z, const float* __restrict__ rw,
                              const float* __restrict__ rb, unsigned short* __restrict__ zbf,
                              int2* __restrict__ idx2, float2* __restrict__ wts2,
                              float* __restrict__ bsums)
{
    __shared__ float ps[4][8];
    const int lane = threadIdx.x & 63;
    const int wave = threadIdx.x >> 6;
    const int row  = blockIdx.x * 4 + wave;
    const float* zr = z + (size_t)row * D_DIM;
    f32x4 z0 = *(const f32x4*)(zr + lane*8);
    f32x4 z1 = *(const f32x4*)(zr + lane*8 + 4);
    {
        u16x4 o0, o1;
        #pragma unroll
        for (int j=0;j<4;j++){ o0[j] = f2bf(z0[j]); o1[j] = f2bf(z1[j]); }
        *(u16x4*)(zbf + (size_t)row*D_DIM + lane*8)     = o0;
        *(u16x4*)(zbf + (size_t)row*D_DIM + lane*8 + 4) = o1;
    }
    float acc[8] = {0,0,0,0,0,0,0,0};
    #pragma unroll
    for (int j = 0; j < 8; ++j){
        const float zv = (j < 4) ? z0[j] : z1[j-4];
        const float* wr = rw + (size_t)(lane*8 + j) * 8;
        f32x4 w0 = *(const f32x4*)wr;
        f32x4 w1 = *(const f32x4*)(wr + 4);
        acc[0] += zv*w0[0]; acc[1] += zv*w0[1]; acc[2] += zv*w0[2]; acc[3] += zv*w0[3];
        acc[4] += zv*w1[0]; acc[5] += zv*w1[1]; acc[6] += zv*w1[2]; acc[7] += zv*w1[3];
    }
    #pragma unroll
    for (int o = 32; o > 0; o >>= 1){
        #pragma unroll
        for (int e = 0; e < 8; ++e) acc[e] += __shfl_xor(acc[e], o);
    }
    if (lane == 0){
        float p[8]; float mx = -1e30f;
        #pragma unroll
        for (int e=0;e<8;e++){ p[e] = acc[e] + rb[e]; mx = fmaxf(mx, p[e]); }
        float se = 0.f;
        #pragma unroll
        for (int e=0;e<8;e++){ p[e] = expf(p[e]-mx); se += p[e]; }
        const float sc = 0.9f / se;
        #pragma unroll
        for (int e=0;e<8;e++) p[e] = p[e]*sc + 0.0125f;
        int i1 = 0;
        #pragma unroll
        for (int e=1;e<8;e++) if (p[e] > p[i1]) i1 = e;
        int i2 = (i1 == 0) ? 1 : 0;
        for (int e=i2+1;e<8;e++) if (e != i1 && p[e] > p[i2]) i2 = e;
        idx2[row] = make_int2(i1, i2);
        wts2[row] = make_float2(p[i1], p[i2]);
        #pragma unroll
        for (int e=0;e<8;e++) ps[wave][e] = p[e];
    }
    __syncthreads();
    if (threadIdx.x < 8){
        bsums[blockIdx.x*8 + threadIdx.x] =
            ps[0][threadIdx.x] + ps[1][threadIdx.x] + ps[2][threadIdx.x] + ps[3][threadIdx.x];
    }
}

// ------- histogram / scan / assign (block-local, no global atomics) -------
__global__ void hist_kernel(const int2* __restrict__ idx2, int* __restrict__ blockHist){
    __shared__ int hc[8];
    if (threadIdx.x < 8) hc[threadIdx.x] = 0;
    __syncthreads();
    const int t = blockIdx.x * 256 + threadIdx.x;
    const int2 ii = idx2[t];
    atomicAdd(&hc[ii.x], 1);
    atomicAdd(&hc[ii.y], 1);
    __syncthreads();
    if (threadIdx.x < 8) blockHist[blockIdx.x*8 + threadIdx.x] = hc[threadIdx.x];
}

__global__ void scan_kernel(const int* __restrict__ blockHist, int* __restrict__ offs,
                            int* __restrict__ baseArr){
    if (threadIdx.x == 0){
        int counts[8];
        #pragma unroll
        for (int e=0;e<8;e++) counts[e] = 0;
        for (int b=0;b<NHBLK;b++)
            #pragma unroll
            for (int e=0;e<8;e++) counts[e] += blockHist[b*8+e];
        int o = 0; offs[0] = 0;
        int start[8];
        #pragma unroll
        for (int e=0;e<8;e++){ start[e] = o; o += (counts[e]+255)&~255; offs[e+1] = o; }
        for (int e=0;e<8;e++){
            int cur = start[e];
            for (int b=0;b<NHBLK;b++){ baseArr[b*8+e] = cur; cur += blockHist[b*8+e]; }
        }
    }
}

__global__ void assign_kernel(const int2* __restrict__ idx2, const float2* __restrict__ wts2,
                              const int* __restrict__ baseArr, int2* __restrict__ slot_map,
                              float* __restrict__ gslot, int* __restrict__ tok)
{
    __shared__ int cur[8];
    if (threadIdx.x < 8) cur[threadIdx.x] = 0;
    __syncthreads();
    const int t = blockIdx.x * 256 + threadIdx.x;
    const int2 ii = idx2[t];
    const float2 ww = wts2[t];
    const int r1 = atomicAdd(&cur[ii.x], 1);
    const int r2 = atomicAdd(&cur[ii.y], 1);
    const int s1 = baseArr[blockIdx.x*8 + ii.x] + r1;
    const int s2 = baseArr[blockIdx.x*8 + ii.y] + r2;
    slot_map[t] = make_int2(s1, s2);
    gslot[s1] = ww.x; gslot[s2] = ww.y;
    tok[s1] = t; tok[s2] = t;
}

// ---------------- aux loss ------------------------------------------------
__global__ void aux_kernel(const float* __restrict__ bsums, float* __restrict__ out_aux)
{
    __shared__ float part[256];
    const int t = threadIdx.x;
    const int e = t & 7, chunk = t >> 3;
    float s = 0.f;
    for (int blk = chunk*128; blk < chunk*128 + 128; ++blk) s += bsums[blk*8 + e];
    part[t] = s;
    __syncthreads();
    if (t < 8){
        float tot = 0.f;
        for (int c = 0; c < 32; ++c) tot += part[c*8 + t];
        part[t] = tot;
    }
    __syncthreads();
    if (t == 0){
        float aux = 0.f;
        for (int e2 = 0; e2 < 8; ++e2){
            float load = part[e2] * (1.0f/16384.0f);
            aux += load * logf(load * 8.0f + 1e-9f);
        }
        out_aux[0] = aux / 2.0794415416798357f;
    }
}

// -------- head: z = h + eo[s1] + eo[s2]; LN; dot --------------------------
__global__ void head_kernel(const float* __restrict__ h, const unsigned short* __restrict__ eog,
                            const int2* __restrict__ slot_map,
                            const float* __restrict__ w, const float* __restrict__ b,
                            const float* __restrict__ hw, const float* __restrict__ hb,
                            float* __restrict__ out)
{
    const int lane = threadIdx.x & 63;
    const int wave = threadIdx.x >> 6;
    const int row  = blockIdx.x * 4 + wave;
    const int2 sm = slot_map[row];
    const float* zr = h + (size_t)row * D_DIM;
    f32x4 v0 = *(const f32x4*)(zr + lane*8);
    f32x4 v1 = *(const f32x4*)(zr + lane*8 + 4);
    u16x8 e1 = *(const u16x8*)(eog + (size_t)sm.x * D_DIM + lane*8);
    u16x8 e2 = *(const u16x8*)(eog + (size_t)sm.y * D_DIM + lane*8);
    #pragma unroll
    for (int j=0;j<4;j++){ v0[j] += bf2f(e1[j]) + bf2f(e2[j]); }
    #pragma unroll
    for (int j=0;j<4;j++){ v1[j] += bf2f(e1[4+j]) + bf2f(e2[4+j]); }
    float s  = v0[0]+v0[1]+v0[2]+v0[3] + v1[0]+v1[1]+v1[2]+v1[3];
    float s2 = v0[0]*v0[0]+v0[1]*v0[1]+v0[2]*v0[2]+v0[3]*v0[3]
             + v1[0]*v1[0]+v1[1]*v1[1]+v1[2]*v1[2]+v1[3]*v1[3];
    #pragma unroll
    for (int o = 32; o > 0; o >>= 1){ s += __shfl_xor(s, o); s2 += __shfl_xor(s2, o); }
    const float mean = s * (1.0f/512.0f);
    const float var  = s2 * (1.0f/512.0f) - mean*mean;
    const float inv  = 1.0f / sqrtf(var + 1e-5f);
    const int k = lane*8;
    float dot = 0.f;
    #pragma unroll
    for (int j=0;j<4;j++) dot += ((v0[j]-mean)*inv*w[k+j]   + b[k+j])   * hw[k+j];
    #pragma unroll
    for (int j=0;j<4;j++) dot += ((v1[j]-mean)*inv*w[k+4+j] + b[k+4+j]) * hw[k+4+j];
    #pragma unroll
    for (int o = 32; o > 0; o >>= 1) dot += __shfl_xor(dot, o);
    if (lane == 0) out[row] = dot + hb[0];
}

// ===========================================================================
extern "C" void kernel_launch(void* const* d_in, const int* in_sizes, int n_in,
                              void* d_out, int out_size, void* d_ws, size_t ws_size,
                              hipStream_t stream)
{
    (void)in_sizes; (void)n_in; (void)out_size; (void)ws_size;
    const float* x         = (const float*)d_in[0];
    const float* embed_w   = (const float*)d_in[1];
    const float* embed_b   = (const float*)d_in[2];
    const float* ln1_w     = (const float*)d_in[3];
    const float* ln1_b     = (const float*)d_in[4];
    const float* inproj_w  = (const float*)d_in[5];
    const float* inproj_b  = (const float*)d_in[6];
    const float* outproj_w = (const float*)d_in[7];
    const float* outproj_b = (const float*)d_in[8];
    const float* ln2_w     = (const float*)d_in[9];
    const float* ln2_b     = (const float*)d_in[10];
    const float* ffn_w1    = (const float*)d_in[11];
    const float* ffn_b1    = (const float*)d_in[12];
    const float* ffn_w2    = (const float*)d_in[13];
    const float* ffn_b2    = (const float*)d_in[14];
    const float* router_w  = (const float*)d_in[15];
    const float* router_b  = (const float*)d_in[16];
    const float* exp_w1    = (const float*)d_in[17];
    const float* exp_b1    = (const float*)d_in[18];
    const float* exp_w2    = (const float*)d_in[19];
    const float* exp_b2    = (const float*)d_in[20];
    const float* head_ln_w = (const float*)d_in[21];
    const float* head_ln_b = (const float*)d_in[22];
    const float* head_w    = (const float*)d_in[23];
    const float* head_b    = (const float*)d_in[24];

    char* ws = (char*)d_ws;
    unsigned short* xbf   = (unsigned short*)(ws + 0);
    unsigned short* ebf   = (unsigned short*)(ws + 4194304);
    unsigned short* wobf  = (unsigned short*)(ws + 4325376);
    unsigned short* wvtbf = (unsigned short*)(ws + 5898240);
    unsigned short* wfold = (unsigned short*)(ws + 7471104);
    unsigned short* w1t   = (unsigned short*)(ws + 9043968);
    unsigned short* w2t   = (unsigned short*)(ws + 15335424);
    unsigned short* e1t   = (unsigned short*)(ws + 21626880);
    unsigned short* e2t   = (unsigned short*)(ws + 23724032);
    float*          h     = (float*)(ws + 25821184);          // 33,554,432
    unsigned short* gbf   = (unsigned short*)(ws + 59375616); // 16,777,216 (ln out; later zbf)
    unsigned short* ubf   = (unsigned short*)(ws + 76152832); // 67,108,864 (ffn1 out)
    unsigned short* hmidg = ubf;                              // 17,825,792 (MoE phase)
    unsigned short* eog   = (unsigned short*)(ws + 93978624); // 35,651,584 (within ubf region)
    char* MISC = ws + 143261696;
    int*    offs     = (int*)(MISC + 0);
    float*  zbias    = (float*)(MISC + 256);
    float*  bfold    = (float*)(MISC + 2304);
    int2*   idx2     = (int2*)(MISC + 8448);
    float2* wts2     = (float2*)(MISC + 139520);
    int2*   slot_map = (int2*)(MISC + 270592);
    float*  gslot    = (float*)(MISC + 401664);    // 139,264
    int*    tok      = (int*)(MISC + 544768);      // 139,264
    float*  bsums    = (float*)(MISC + 684032);    // 131,072
    int*    blockHist= (int*)(MISC + 815104);
    int*    baseArr  = (int*)(MISC + 817152);
    unsigned short* zbf = gbf;
    float* out = (float*)d_out;

    zero_kernel<<<(MAXSLOT + 255)/256, 256, 0, stream>>>((int*)zbias, 512, tok, MAXSLOT);

    ConvArgs ca;
    ca.seg[0] = { x, xbf, B_TOK*IN_DIM/4 };
    ca.seg[1] = { outproj_w, wobf, DEPTH*D_DIM*D_DIM/4 };
    convert_kernel<<<1024, 256, 0, stream>>>(ca);

    TArgs ta;
    int tcur = 0, ti = 0;
    ta.seg[ti] = { embed_w, ebf, IN_DIM, D_DIM, tcur };
    tcur += (IN_DIM/32)*(D_DIM/32); ++ti;
    for (int l = 0; l < DEPTH; ++l){
        ta.seg[ti] = { ffn_w1 + (size_t)l*D_DIM*FF_DIM, w1t + (size_t)l*FF_DIM*D_DIM, D_DIM, FF_DIM, tcur };
        tcur += (D_DIM/32)*(FF_DIM/32); ++ti;
    }
    for (int l = 0; l < DEPTH; ++l){
        ta.seg[ti] = { ffn_w2 + (size_t)l*FF_DIM*D_DIM, w2t + (size_t)l*D_DIM*FF_DIM, FF_DIM, D_DIM, tcur };
        tcur += (FF_DIM/32)*(D_DIM/32); ++ti;
    }
    for (int e = 0; e < NEXP; ++e){
        ta.seg[ti] = { exp_w1 + (size_t)e*D_DIM*EH_DIM, e1t + (size_t)e*EH_DIM*D_DIM, D_DIM, EH_DIM, tcur };
        tcur += (D_DIM/32)*(EH_DIM/32); ++ti;
    }
    for (int e = 0; e < NEXP; ++e){
        ta.seg[ti] = { exp_w2 + (size_t)e*EH_DIM*D_DIM, e2t + (size_t)e*D_DIM*EH_DIM, EH_DIM, D_DIM, tcur };
        tcur += (EH_DIM/32)*(D_DIM/32); ++ti;
    }
    for (int l = 0; l < DEPTH; ++l){
        ta.seg[ti] = { inproj_w + (size_t)l*3*D_DIM*D_DIM + 2*D_DIM*D_DIM,
                       wvtbf + (size_t)l*D_DIM*D_DIM, D_DIM, D_DIM, tcur };
        tcur += (D_DIM/32)*(D_DIM/32); ++ti;
    }
    transpose_kernel<<<tcur, 256, 0, stream>>>(ta);

    foldb_kernel<<<DEPTH, D_DIM, 0, stream>>>(outproj_w, outproj_b, inproj_b, bfold);

    for (int l = 0; l < DEPTH; ++l){
        gemm_bt<EPI_BF16><<<16, 256, 0, stream>>>(
            wobf + (size_t)l*D_DIM*D_DIM, wvtbf + (size_t)l*D_DIM*D_DIM,
            zbias, wfold + (size_t)l*D_DIM*D_DIM, 4, D_DIM, D_DIM);
    }

    gemm_bt<EPI_F32_BIAS><<<(D_DIM/128)*(B_TOK/128), 256, 0, stream>>>(
        xbf, ebf, embed_b, h, D_DIM/128, D_DIM, IN_DIM);

    for (int l = 0; l < DEPTH; ++l){
        ln_kernel<<<B_TOK/4, 256, 0, stream>>>(h, ln1_w + l*D_DIM, ln1_b + l*D_DIM, gbf);
        gemm256<G_F32_RESID,0,0><<<(B_TOK/256)*(D_DIM/128), 512, 0, stream>>>(
            gbf, wfold + (size_t)l*D_DIM*D_DIM, bfold + l*D_DIM, h,
            nullptr, nullptr, 0, 0, nullptr, h, D_DIM/128, D_DIM, D_DIM);
        ln_kernel<<<B_TOK/4, 256, 0, stream>>>(h, ln2_w + l*D_DIM, ln2_b + l*D_DIM, gbf);
        gemm256<G_GELU_BF16,0,0><<<(B_TOK/256)*(FF_DIM/128), 512, 0, stream>>>(
            gbf, w1t + (size_t)l*FF_DIM*D_DIM, ffn_b1 + l*FF_DIM, nullptr,
            nullptr, nullptr, 0, 0, nullptr, ubf, FF_DIM/128, FF_DIM, D_DIM);
        gemm256<G_F32_RESID,0,0><<<(B_TOK/256)*(D_DIM/128), 512, 0, stream>>>(
            ubf, w2t + (size_t)l*D_DIM*FF_DIM, ffn_b2 + l*D_DIM, h,
            nullptr, nullptr, 0, 0, nullptr, h, D_DIM/128, D_DIM, FF_DIM);
    }

    router_kernel<<<B_TOK/4, 256, 0, stream>>>(h, router_w, router_b, zbf, idx2, wts2, bsums);
    aux_kernel<<<1, 256, 0, stream>>>(bsums, out + B_TOK);
    hist_kernel<<<NHBLK, 256, 0, stream>>>(idx2, blockHist);
    scan_kernel<<<1, 64, 0, stream>>>(blockHist, offs, baseArr);
    assign_kernel<<<B_TOK/256, 256, 0, stream>>>(idx2, wts2, baseArr, slot_map, gslot, tok);

    gemm256<G_GELU_BF16,1,1><<<MAXT256*(EH_DIM/128), 512, 0, stream>>>(
        zbf, e1t, exp_b1, nullptr, tok, offs, EH_DIM*D_DIM, EH_DIM, nullptr,
        hmidg, EH_DIM/128, EH_DIM, D_DIM);
    gemm256<G_GATED_BF16,1,0><<<MAXT256*(D_DIM/128), 512, 0, stream>>>(
        hmidg, e2t, exp_b2, nullptr, nullptr, offs, D_DIM*EH_DIM, D_DIM, gslot,
        eog, D_DIM/128, D_DIM, EH_DIM);

    head_kernel<<<B_TOK/4, 256, 0, stream>>>(h, eog, slot_map, head_ln_w, head_ln_b, head_w, head_b, out);
}

// Round 6
// 673.914 us; speedup vs baseline: 1.7354x; 1.0078x over previous
//
#include <hip/hip_runtime.h>
#include <hip/hip_bf16.h>

#define B_TOK 16384
#define IN_DIM 128
#define D_DIM 512
#define DEPTH 3
#define NEXP 8
#define FF_DIM 2048
#define EH_DIM 256
#define MAXSLOT 34816   // 32768 + 8*256, 256-padded expert segments
#define MAXT256 136     // MAXSLOT/256
#define NHBLK 64

typedef __attribute__((ext_vector_type(8))) __bf16 bf16x8;
typedef __attribute__((ext_vector_type(4))) float f32x4;
typedef __attribute__((ext_vector_type(4))) unsigned short u16x4;
typedef __attribute__((ext_vector_type(8))) unsigned short u16x8;

__device__ __forceinline__ unsigned short f2bf(float f){
    unsigned int u = __float_as_uint(f);
    u += 0x7fffu + ((u >> 16) & 1u);
    return (unsigned short)(u >> 16);
}
__device__ __forceinline__ float bf2f(unsigned short u){
    return __uint_as_float(((unsigned int)u) << 16);
}
__device__ __forceinline__ float geluf(float x){
    return 0.5f * x * (1.0f + erff(x * 0.70710678118654752f));
}
__device__ __forceinline__ void gload_lds16(const void* g, void* l){
    __builtin_amdgcn_global_load_lds((const __attribute__((address_space(1))) unsigned int*)g,
                                     (__attribute__((address_space(3))) unsigned int*)l,
                                     16, 0, 0);
}
__device__ __forceinline__ int xcd_swizzle(int orig, int nwg){
    const int q = nwg >> 3, r = nwg & 7;
    const int xcd = orig & 7;
    const int idx = orig >> 3;
    return (xcd < r ? xcd*(q+1) : r*(q+1) + (xcd-r)*q) + idx;
}
__device__ __forceinline__ void wgbar(){
    asm volatile("" ::: "memory");
    __builtin_amdgcn_s_barrier();
    asm volatile("" ::: "memory");
}

// ---------------- zero scratch control state ------------------------------
__global__ void zero_kernel(int* a, int na, int* b, int nb){
    const int i = blockIdx.x * blockDim.x + threadIdx.x;
    if (i < na) a[i] = 0;
    if (i < nb) b[i] = 0;
}

// ---------------- fp32 -> bf16 convert ------------------------------------
struct ConvSeg { const float* src; unsigned short* dst; int n4; };
struct ConvArgs { ConvSeg seg[2]; };

__global__ void convert_kernel(ConvArgs a){
    const int stride = gridDim.x * blockDim.x;
    const int tid = blockIdx.x * blockDim.x + threadIdx.x;
    for (int s = 0; s < 2; ++s){
        const f32x4* src = (const f32x4*)a.seg[s].src;
        u16x4* dst = (u16x4*)a.seg[s].dst;
        const int n4 = a.seg[s].n4;
        for (int i = tid; i < n4; i += stride){
            f32x4 v = src[i];
            u16x4 o;
            o[0] = f2bf(v[0]); o[1] = f2bf(v[1]); o[2] = f2bf(v[2]); o[3] = f2bf(v[3]);
            dst[i] = o;
        }
    }
}

// ------------- weight transpose-convert: (K,N) fp32 -> (N,K) bf16 ---------
struct TSeg { const float* src; unsigned short* dst; int K; int N; int tileStart; };
struct TArgs { TSeg seg[26]; };

__global__ void transpose_kernel(TArgs a){
    __shared__ float t[32][33];
    const int tile = blockIdx.x;
    int s = 0;
    #pragma unroll 1
    while (s < 25 && tile >= a.seg[s+1].tileStart) ++s;
    const TSeg sg = a.seg[s];
    const int local = tile - sg.tileStart;
    const int tilesN = sg.N >> 5;
    const int k0 = (local / tilesN) << 5;
    const int n0 = (local % tilesN) << 5;
    const int tx = threadIdx.x & 31;
    const int ty = threadIdx.x >> 5;
    #pragma unroll
    for (int j = 0; j < 4; ++j)
        t[ty + j*8][tx] = sg.src[(size_t)(k0 + ty + j*8) * sg.N + n0 + tx];
    __syncthreads();
    #pragma unroll
    for (int j = 0; j < 4; ++j){
        const int n = ty + j*8;
        sg.dst[(size_t)(n0 + n) * sg.K + k0 + tx] = f2bf(t[tx][n]);
    }
}

// ---------------- folded attention bias: bfold = Wo@bv + bo ---------------
__global__ void foldb_kernel(const float* __restrict__ outproj_w, const float* __restrict__ outproj_b,
                             const float* __restrict__ inproj_b, float* __restrict__ bfold){
    const int l = blockIdx.x, n = threadIdx.x;
    const float* Wo = outproj_w + ((size_t)l*D_DIM + n)*D_DIM;
    const float* bv = inproj_b + l*3*D_DIM + 2*D_DIM;
    float acc = outproj_b[l*D_DIM + n];
    for (int j = 0; j < D_DIM; ++j) acc += Wo[j]*bv[j];
    bfold[l*D_DIM + n] = acc;
}

// ---------------- small GEMM (embed/fold): 128x128, dbuf ------------------
#define EPI_BF16 0
#define EPI_F32_BIAS 2

template<int EPI>
__global__ void __launch_bounds__(256, 2)
gemm_bt(const unsigned short* __restrict__ A, const unsigned short* __restrict__ Bt,
        const float* __restrict__ bias, void* __restrict__ out, int NB, int N, int K)
{
    __shared__ unsigned short sh[32768];
    const int nwg = gridDim.x;
    const int wg  = xcd_swizzle(blockIdx.x, nwg);
    const int bn  = wg % NB;
    const int bm  = wg / NB;

    const int tid  = threadIdx.x;
    const int lane = tid & 63;
    const int wave = tid >> 6;
    const int wm = (wave >> 1) << 6;
    const int wn = (wave & 1) << 6;

    f32x4 acc[4][4] = {};

    const unsigned short* Abase = A + (size_t)bm * 128 * K;
    const unsigned short* Bbase = Bt + (size_t)bn * 128 * K;
    const int soff = tid * 16;

    auto STAGE = [&](int b, int kt){
        char* Ab = (char*)(sh + b*16384);
        char* Bb = (char*)(sh + b*16384 + 8192);
        #pragma unroll
        for (int s = 0; s < 4; ++s){
            const int off = s*4096 + soff;
            const int row = off >> 7, colb = off & 127;
            gload_lds16((const char*)(Abase + (size_t)row*K + kt) + colb, Ab + off);
        }
        #pragma unroll
        for (int s = 0; s < 4; ++s){
            const int off = s*4096 + soff;
            const int row = off >> 7, colb = off & 127;
            gload_lds16((const char*)(Bbase + (size_t)row*K + kt) + colb, Bb + off);
        }
    };
    auto COMPUTE = [&](int b){
        const unsigned short* Ab = sh + b*16384;
        const unsigned short* Bb = sh + b*16384 + 8192;
        #pragma unroll
        for (int ks = 0; ks < 2; ++ks){
            const int k0 = ks*32 + ((lane>>4)<<3);
            bf16x8 af[4], bfr[4];
            #pragma unroll
            for (int i=0;i<4;i++) af[i]  = *(const bf16x8*)&Ab[(wm + i*16 + (lane&15))*64 + k0];
            #pragma unroll
            for (int j=0;j<4;j++) bfr[j] = *(const bf16x8*)&Bb[(wn + j*16 + (lane&15))*64 + k0];
            #pragma unroll
            for (int i=0;i<4;i++)
                #pragma unroll
                for (int j=0;j<4;j++)
                    acc[i][j] = __builtin_amdgcn_mfma_f32_16x16x32_bf16(af[i], bfr[j], acc[i][j], 0, 0, 0);
        }
    };

    STAGE(0, 0);
    __syncthreads();
    const int nk = K >> 6;
    int cur = 0;
    for (int i = 0; i < nk; ++i){
        if (i + 1 < nk) STAGE(cur ^ 1, (i + 1) << 6);
        COMPUTE(cur);
        __syncthreads();
        cur ^= 1;
    }

    const int r0 = ((lane>>4)<<2);
    const int cc = lane & 15;

    if (EPI == EPI_F32_BIAS){
        #pragma unroll
        for (int j=0;j<4;j++){
            const int col = bn*128 + wn + j*16 + cc;
            const float bv = bias[col];
            #pragma unroll
            for (int i=0;i<4;i++)
                #pragma unroll
                for (int r=0;r<4;r++){
                    const int row = bm*128 + wm + i*16 + r0 + r;
                    ((float*)out)[(size_t)row * N + col] = acc[i][j][r] + bv;
                }
        }
    } else {
        unsigned short* Ct = sh;
        float bcol[4];
        #pragma unroll
        for (int j=0;j<4;j++) bcol[j] = bias[bn*128 + wn + j*16 + cc];
        #pragma unroll
        for (int i=0;i<4;i++)
            #pragma unroll
            for (int r=0;r<4;r++){
                const int rl = wm + i*16 + r0 + r;
                #pragma unroll
                for (int j=0;j<4;j++)
                    Ct[rl*128 + wn + j*16 + cc] = f2bf(acc[i][j][r] + bcol[j]);
            }
        __syncthreads();
        const int orow = tid >> 4;
        const int ocol = (tid & 15) * 8;
        unsigned short* op = (unsigned short*)out;
        #pragma unroll
        for (int p = 0; p < 8; ++p){
            const int row = p*16 + orow;
            *(u16x4*)(&op[(size_t)(bm*128 + row)*N + bn*128 + ocol])     = *(u16x4*)&Ct[row*128 + ocol];
            *(u16x4*)(&op[(size_t)(bm*128 + row)*N + bn*128 + ocol + 4]) = *(u16x4*)&Ct[row*128 + ocol + 4];
        }
    }
}

// =================== 256x128 pipelined GEMM, triple-buffered ==============
// BM=256 BN=128 BK=64, 512 thr (8 waves 4Mx2N), LDS 144KB (A x3, B x3),
// T2 swizzle, counted vmcnt(6) (T4, 3-tile ledger), setprio (T5).
#define G_GELU_BF16 0
#define G_F32_RESID 1
#define G_GATED_BF16 2

template<int EPI, int MOE, int INDIRECT>
__global__ void __launch_bounds__(512, 2)
gemm256(const unsigned short* __restrict__ A, const unsigned short* __restrict__ BtG,
        const float* __restrict__ biasG, const float* __restrict__ resid,
        const int* __restrict__ tok, const int* __restrict__ offs,
        int wstride, int bstride, const float* __restrict__ gslot,
        void* __restrict__ out, int NB, int N, int K)
{
    // A bufs: 0/32K/64K (32KB each). B bufs: 96K + 0/16K/32K (16KB each).
    __shared__ __align__(16) char sh[147456];
    const int nwg = gridDim.x;
    const int wg  = xcd_swizzle(blockIdx.x, nwg);
    const int bn  = wg % NB;
    const int bm  = wg / NB;
    const int m0  = bm * 256;

    const unsigned short* Bt = BtG;
    const float* bias = biasG;
    if (MOE){
        if (m0 >= offs[8]) return;
        int e = 0;
        #pragma unroll 1
        while (offs[e+1] <= m0) ++e;
        Bt   += (size_t)e * wstride;
        bias += (size_t)e * bstride;
    }

    const int tid = threadIdx.x, lane = tid & 63, wave = tid >> 6;
    const int wm = (wave >> 1) * 64;   // 0,64,128,192
    const int wn = (wave & 1) * 64;    // 0,64

    // ---- staging: linear LDS dest, inverse-swizzled global source --------
    const int srow = wave*16 + (lane >> 3);
    const int scol = ((lane & 7) ^ (lane >> 3)) * 8;
    const unsigned short* aptr[2][2];
    #pragma unroll
    for (int u = 0; u < 2; ++u)
        #pragma unroll
        for (int l = 0; l < 2; ++l){
            const int r = u*128 + srow + l*8;
            const int gr = INDIRECT ? tok[m0 + r] : (m0 + r);
            aptr[u][l] = A + (size_t)gr * K + scol;
        }
    const unsigned short* bptr[2];
    #pragma unroll
    for (int l = 0; l < 2; ++l)
        bptr[l] = Bt + (size_t)(bn*128 + srow + l*8) * K + scol;
    const int sdst = wave*2048 + lane*16;

    // ---- swizzled read offsets (bytes) -----------------------------------
    int aoff[2], boff[2];
    #pragma unroll
    for (int ks = 0; ks < 2; ++ks){
        const int ch = (((ks<<2) + (lane>>4)) ^ (lane & 7)) << 4;
        aoff[ks] = (wm + (lane & 15))*128 + ch;
        boff[ks] = (wn + (lane & 15))*128 + ch;
    }

    f32x4 acc[4][4] = {};
    bf16x8 bfr[4][2];

    auto STA = [&](int buf, int kt){
        #pragma unroll
        for (int u = 0; u < 2; ++u)
            #pragma unroll
            for (int l = 0; l < 2; ++l)
                gload_lds16(aptr[u][l] + kt, sh + buf*32768 + u*16384 + l*1024 + sdst);
    };
    auto STB = [&](int buf, int kt){
        #pragma unroll
        for (int l = 0; l < 2; ++l)
            gload_lds16(bptr[l] + kt, sh + 98304 + buf*16384 + l*1024 + sdst);
    };
    auto RDB = [&](int buf){
        #pragma unroll
        for (int nf = 0; nf < 4; ++nf)
            #pragma unroll
            for (int ks = 0; ks < 2; ++ks)
                bfr[nf][ks] = *(const bf16x8*)(sh + 98304 + buf*16384 + nf*2048 + boff[ks]);
    };

    // ---- prologue: stage T0, T1 (12 loads); wait until T0 resident -------
    STA(0, 0);  STB(0, 0);
    STA(1, 64); STB(1, 64);
    asm volatile("s_waitcnt vmcnt(6)" ::: "memory");
    wgbar();

    const int nk = K >> 6;
    int c0 = 0;
    for (int t = 0; t < nk; ++t){
        const bool f = (t + 2 < nk);
        int c2 = c0 + 2; if (c2 >= 3) c2 -= 3;
        bf16x8 af[2][2];

        // ---- phase alpha: B frags + A m0,m1 from buf c0; issue T_{t+2} ---
        RDB(c0);
        #pragma unroll
        for (int m2 = 0; m2 < 2; ++m2)
            #pragma unroll
            for (int ks = 0; ks < 2; ++ks)
                af[m2][ks] = *(const bf16x8*)(sh + c0*32768 + (0+m2)*2048 + aoff[ks]);
        if (f){
            const int kt2 = (t + 2) << 6;
            STA(c2, kt2);          // buf c2's occupant (T_{t-1}) dead since beta(t-1)+barrier
            STB(c2, kt2);
        }
        __builtin_amdgcn_s_setprio(1);
        #pragma unroll
        for (int m2 = 0; m2 < 2; ++m2)
            #pragma unroll
            for (int nf = 0; nf < 4; ++nf)
                #pragma unroll
                for (int ks = 0; ks < 2; ++ks)
                    acc[0+m2][nf] = __builtin_amdgcn_mfma_f32_16x16x32_bf16(af[m2][ks], bfr[nf][ks], acc[0+m2][nf], 0,0,0);
        __builtin_amdgcn_s_setprio(0);
        wgbar();

        // ---- phase beta: A m2,m3 from buf c0; drain T_{t+1} --------------
        #pragma unroll
        for (int m2 = 0; m2 < 2; ++m2)
            #pragma unroll
            for (int ks = 0; ks < 2; ++ks)
                af[m2][ks] = *(const bf16x8*)(sh + c0*32768 + (2+m2)*2048 + aoff[ks]);
        __builtin_amdgcn_s_setprio(1);
        #pragma unroll
        for (int m2 = 0; m2 < 2; ++m2)
            #pragma unroll
            for (int nf = 0; nf < 4; ++nf)
                #pragma unroll
                for (int ks = 0; ks < 2; ++ks)
                    acc[2+m2][nf] = __builtin_amdgcn_mfma_f32_16x16x32_bf16(af[m2][ks], bfr[nf][ks], acc[2+m2][nf], 0,0,0);
        __builtin_amdgcn_s_setprio(0);
        if (f) asm volatile("s_waitcnt vmcnt(6)" ::: "memory");  // T_{t+1} resident, T_{t+2} in flight
        else   asm volatile("s_waitcnt vmcnt(0)" ::: "memory");
        wgbar();

        ++c0; if (c0 >= 3) c0 -= 3;
    }

    // ---- epilogue --------------------------------------------------------
    const int r4 = (lane >> 4) * 4;
    const int cc = lane & 15;
    if (EPI == G_F32_RESID){
        #pragma unroll
        for (int nf = 0; nf < 4; ++nf){
            const int col = bn*128 + wn + nf*16 + cc;
            const float bv = bias[col];
            #pragma unroll
            for (int mf = 0; mf < 4; ++mf)
                #pragma unroll
                for (int r = 0; r < 4; ++r){
                    const int row = m0 + wm + mf*16 + r4 + r;
                    const size_t idx = (size_t)row * N + col;
                    ((float*)out)[idx] = resid[idx] + acc[mf][nf][r] + bv;
                }
        }
    } else {
        unsigned short* ct = (unsigned short*)sh;  // 256x128 bf16 = 64KB
        #pragma unroll
        for (int nf = 0; nf < 4; ++nf){
            const float bv = bias[bn*128 + wn + nf*16 + cc];
            #pragma unroll
            for (int mf = 0; mf < 4; ++mf)
                #pragma unroll
                for (int r = 0; r < 4; ++r){
                    const int row = wm + mf*16 + r4 + r;
                    float v = acc[mf][nf][r] + bv;
                    if (EPI == G_GELU_BF16) v = geluf(v);
                    else                    v *= gslot[m0 + row];
                    ct[row*128 + wn + nf*16 + cc] = f2bf(v);
                }
        }
        __syncthreads();
        unsigned short* op = (unsigned short*)out;
        #pragma unroll
        for (int p = 0; p < 8; ++p){
            const int uidx = p*512 + tid;
            const int row = uidx >> 4;
            const int cu  = uidx & 15;
            *(u16x8*)(op + (size_t)(m0 + row)*N + bn*128 + cu*8) =
                *(const u16x8*)(ct + row*128 + cu*8);
        }
    }
}

// ---------------- LayerNorm (fp32 in, bf16 out), one wave per row ---------
__global__ void ln_kernel(const float* __restrict__ x, const float* __restrict__ w,
                          const float* __restrict__ b, unsigned short* __restrict__ out)
{
    const int lane = threadIdx.x & 63;
    const int wave = threadIdx.x >> 6;
    const int row  = blockIdx.x * 4 + wave;
    const float* xr = x + (size_t)row * D_DIM;
    f32x4 v0 = *(const f32x4*)(xr + lane*8);
    f32x4 v1 = *(const f32x4*)(xr + lane*8 + 4);
    float s  = v0[0]+v0[1]+v0[2]+v0[3] + v1[0]+v1[1]+v1[2]+v1[3];
    float s2 = v0[0]*v0[0]+v0[1]*v0[1]+v0[2]*v0[2]+v0[3]*v0[3]
             + v1[0]*v1[0]+v1[1]*v1[1]+v1[2]*v1[2]+v1[3]*v1[3];
    #pragma unroll
    for (int o = 32; o > 0; o >>= 1){ s += __shfl_xor(s, o); s2 += __shfl_xor(s2, o); }
    const float mean = s * (1.0f/512.0f);
    const float var  = s2 * (1.0f/512.0f) - mean*mean;
    const float inv  = 1.0f / sqrtf(var + 1e-5f);
    const int k = lane*8;
    u16x4 o0, o1;
    #pragma unroll
    for (int j=0;j<4;j++) o0[j] = f2bf((v0[j]-mean)*inv*w[k+j]   + b[k+j]);
    #pragma unroll
    for (int j=0;j<4;j++) o1[j] = f2bf((v1[j]-mean)*inv*w[k+4+j] + b[k+4+j]);
    *(u16x4*)(out + (size_t)row*D_DIM + k)     = o0;
    *(u16x4*)(out + (size_t)row*D_DIM + k + 4) = o1;
}

// ------- Router: softmax+eps-mix+top2 (no global atomics) -----------------
__global__ void router_kernel(const float* __restrict__ z, const float* __restrict__ rw,
                              const float* __restrict__ rb, unsigned short* __restrict__ zbf,
                              int2* __restrict__ idx2, float2* __restrict__ wts2,
                              float* __restrict__ bsums)
{
    __shared__ float ps[4][8];
    const int lane = threadIdx.x & 63;
    const int wave = threadIdx.x >> 6;
    const int row  = blockIdx.x * 4 + wave;
    const float* zr = z + (size_t)row * D_DIM;
    f32x4 z0 = *(const f32x4*)(zr + lane*8);
    f32x4 z1 = *(const f32x4*)(zr + lane*8 + 4);
    {
        u16x4 o0, o1;
        #pragma unroll
        for (int j=0;j<4;j++){ o0[j] = f2bf(z0[j]); o1[j] = f2bf(z1[j]); }
        *(u16x4*)(zbf + (size_t)row*D_DIM + lane*8)     = o0;
        *(u16x4*)(zbf + (size_t)row*D_DIM + lane*8 + 4) = o1;
    }
    float acc[8] = {0,0,0,0,0,0,0,0};
    #pragma unroll
    for (int j = 0; j < 8; ++j){
        const float zv = (j < 4) ? z0[j] : z1[j-4];
        const float* wr = rw + (size_t)(lane*8 + j) * 8;
        f32x4 w0 = *(const f32x4*)wr;
        f32x4 w1 = *(const f32x4*)(wr + 4);
        acc[0] += zv*w0[0]; acc[1] += zv*w0[1]; acc[2] += zv*w0[2]; acc[3] += zv*w0[3];
        acc[4] += zv*w1[0]; acc[5] += zv*w1[1]; acc[6] += zv*w1[2]; acc[7] += zv*w1[3];
    }
    #pragma unroll
    for (int o = 32; o > 0; o >>= 1){
        #pragma unroll
        for (int e = 0; e < 8; ++e) acc[e] += __shfl_xor(acc[e], o);
    }
    if (lane == 0){
        float p[8]; float mx = -1e30f;
        #pragma unroll
        for (int e=0;e<8;e++){ p[e] = acc[e] + rb[e]; mx = fmaxf(mx, p[e]); }
        float se = 0.f;
        #pragma unroll
        for (int e=0;e<8;e++){ p[e] = expf(p[e]-mx); se += p[e]; }
        const float sc = 0.9f / se;
        #pragma unroll
        for (int e=0;e<8;e++) p[e] = p[e]*sc + 0.0125f;
        int i1 = 0;
        #pragma unroll
        for (int e=1;e<8;e++) if (p[e] > p[i1]) i1 = e;
        int i2 = (i1 == 0) ? 1 : 0;
        for (int e=i2+1;e<8;e++) if (e != i1 && p[e] > p[i2]) i2 = e;
        idx2[row] = make_int2(i1, i2);
        wts2[row] = make_float2(p[i1], p[i2]);
        #pragma unroll
        for (int e=0;e<8;e++) ps[wave][e] = p[e];
    }
    __syncthreads();
    if (threadIdx.x < 8){
        bsums[blockIdx.x*8 + threadIdx.x] =
            ps[0][threadIdx.x] + ps[1][threadIdx.x] + ps[2][threadIdx.x] + ps[3][threadIdx.x];
    }
}

// ------- histogram / scan / assign (block-local, no global atomics) -------
__global__ void hist_kernel(const int2* __restrict__ idx2, int* __restrict__ blockHist){
    __shared__ int hc[8];
    if (threadIdx.x < 8) hc[threadIdx.x] = 0;
    __syncthreads();
    const int t = blockIdx.x * 256 + threadIdx.x;
    const int2 ii = idx2[t];
    atomicAdd(&hc[ii.x], 1);
    atomicAdd(&hc[ii.y], 1);
    __syncthreads();
    if (threadIdx.x < 8) blockHist[blockIdx.x*8 + threadIdx.x] = hc[threadIdx.x];
}

__global__ void scan_kernel(const int* __restrict__ blockHist, int* __restrict__ offs,
                            int* __restrict__ baseArr){
    if (threadIdx.x == 0){
        int counts[8];
        #pragma unroll
        for (int e=0;e<8;e++) counts[e] = 0;
        for (int b=0;b<NHBLK;b++)
            #pragma unroll
            for (int e=0;e<8;e++) counts[e] += blockHist[b*8+e];
        int o = 0; offs[0] = 0;
        int start[8];
        #pragma unroll
        for (int e=0;e<8;e++){ start[e] = o; o += (counts[e]+255)&~255; offs[e+1] = o; }
        for (int e=0;e<8;e++){
            int cur = start[e];
            for (int b=0;b<NHBLK;b++){ baseArr[b*8+e] = cur; cur += blockHist[b*8+e]; }
        }
    }
}

__global__ void assign_kernel(const int2* __restrict__ idx2, const float2* __restrict__ wts2,
                              const int* __restrict__ baseArr, int2* __restrict__ slot_map,
                              float* __restrict__ gslot, int* __restrict__ tok)
{
    __shared__ int cur[8];
    if (threadIdx.x < 8) cur[threadIdx.x] = 0;
    __syncthreads();
    const int t = blockIdx.x * 256 + threadIdx.x;
    const int2 ii = idx2[t];
    const float2 ww = wts2[t];
    const int r1 = atomicAdd(&cur[ii.x], 1);
    const int r2 = atomicAdd(&cur[ii.y], 1);
    const int s1 = baseArr[blockIdx.x*8 + ii.x] + r1;
    const int s2 = baseArr[blockIdx.x*8 + ii.y] + r2;
    slot_map[t] = make_int2(s1, s2);
    gslot[s1] = ww.x; gslot[s2] = ww.y;
    tok[s1] = t; tok[s2] = t;
}

// ---------------- aux loss ------------------------------------------------
__global__ void aux_kernel(const float* __restrict__ bsums, float* __restrict__ out_aux)
{
    __shared__ float part[256];
    const int t = threadIdx.x;
    const int e = t & 7, chunk = t >> 3;
    float s = 0.f;
    for (int blk = chunk*128; blk < chunk*128 + 128; ++blk) s += bsums[blk*8 + e];
    part[t] = s;
    __syncthreads();
    if (t < 8){
        float tot = 0.f;
        for (int c = 0; c < 32; ++c) tot += part[c*8 + t];
        part[t] = tot;
    }
    __syncthreads();
    if (t == 0){
        float aux = 0.f;
        for (int e2 = 0; e2 < 8; ++e2){
            float load = part[e2] * (1.0f/16384.0f);
            aux += load * logf(load * 8.0f + 1e-9f);
        }
        out_aux[0] = aux / 2.0794415416798357f;
    }
}

// -------- head: z = h + eo[s1] + eo[s2]; LN; dot --------------------------
__global__ void head_kernel(const float* __restrict__ h, const unsigned short* __restrict__ eog,
                            const int2* __restrict__ slot_map,
                            const float* __restrict__ w, const float* __restrict__ b,
                            const float* __restrict__ hw, const float* __restrict__ hb,
                            float* __restrict__ out)
{
    const int lane = threadIdx.x & 63;
    const int wave = threadIdx.x >> 6;
    const int row  = blockIdx.x * 4 + wave;
    const int2 sm = slot_map[row];
    const float* zr = h + (size_t)row * D_DIM;
    f32x4 v0 = *(const f32x4*)(zr + lane*8);
    f32x4 v1 = *(const f32x4*)(zr + lane*8 + 4);
    u16x8 e1 = *(const u16x8*)(eog + (size_t)sm.x * D_DIM + lane*8);
    u16x8 e2 = *(const u16x8*)(eog + (size_t)sm.y * D_DIM + lane*8);
    #pragma unroll
    for (int j=0;j<4;j++){ v0[j] += bf2f(e1[j]) + bf2f(e2[j]); }
    #pragma unroll
    for (int j=0;j<4;j++){ v1[j] += bf2f(e1[4+j]) + bf2f(e2[4+j]); }
    float s  = v0[0]+v0[1]+v0[2]+v0[3] + v1[0]+v1[1]+v1[2]+v1[3];
    float s2 = v0[0]*v0[0]+v0[1]*v0[1]+v0[2]*v0[2]+v0[3]*v0[3]
             + v1[0]*v1[0]+v1[1]*v1[1]+v1[2]*v1[2]+v1[3]*v1[3];
    #pragma unroll
    for (int o = 32; o > 0; o >>= 1){ s += __shfl_xor(s, o); s2 += __shfl_xor(s2, o); }
    const float mean = s * (1.0f/512.0f);
    const float var  = s2 * (1.0f/512.0f) - mean*mean;
    const float inv  = 1.0f / sqrtf(var + 1e-5f);
    const int k = lane*8;
    float dot = 0.f;
    #pragma unroll
    for (int j=0;j<4;j++) dot += ((v0[j]-mean)*inv*w[k+j]   + b[k+j])   * hw[k+j];
    #pragma unroll
    for (int j=0;j<4;j++) dot += ((v1[j]-mean)*inv*w[k+4+j] + b[k+4+j]) * hw[k+4+j];
    #pragma unroll
    for (int o = 32; o > 0; o >>= 1) dot += __shfl_xor(dot, o);
    if (lane == 0) out[row] = dot + hb[0];
}

// ===========================================================================
extern "C" void kernel_launch(void* const* d_in, const int* in_sizes, int n_in,
                              void* d_out, int out_size, void* d_ws, size_t ws_size,
                              hipStream_t stream)
{
    (void)in_sizes; (void)n_in; (void)out_size; (void)ws_size;
    const float* x         = (const float*)d_in[0];
    const float* embed_w   = (const float*)d_in[1];
    const float* embed_b   = (const float*)d_in[2];
    const float* ln1_w     = (const float*)d_in[3];
    const float* ln1_b     = (const float*)d_in[4];
    const float* inproj_w  = (const float*)d_in[5];
    const float* inproj_b  = (const float*)d_in[6];
    const float* outproj_w = (const float*)d_in[7];
    const float* outproj_b = (const float*)d_in[8];
    const float* ln2_w     = (const float*)d_in[9];
    const float* ln2_b     = (const float*)d_in[10];
    const float* ffn_w1    = (const float*)d_in[11];
    const float* ffn_b1    = (const float*)d_in[12];
    const float* ffn_w2    = (const float*)d_in[13];
    const float* ffn_b2    = (const float*)d_in[14];
    const float* router_w  = (const float*)d_in[15];
    const float* router_b  = (const float*)d_in[16];
    const float* exp_w1    = (const float*)d_in[17];
    const float* exp_b1    = (const float*)d_in[18];
    const float* exp_w2    = (const float*)d_in[19];
    const float* exp_b2    = (const float*)d_in[20];
    const float* head_ln_w = (const float*)d_in[21];
    const float* head_ln_b = (const float*)d_in[22];
    const float* head_w    = (const float*)d_in[23];
    const float* head_b    = (const float*)d_in[24];

    char* ws = (char*)d_ws;
    unsigned short* xbf   = (unsigned short*)(ws + 0);
    unsigned short* ebf   = (unsigned short*)(ws + 4194304);
    unsigned short* wobf  = (unsigned short*)(ws + 4325376);
    unsigned short* wvtbf = (unsigned short*)(ws + 5898240);
    unsigned short* wfold = (unsigned short*)(ws + 7471104);
    unsigned short* w1t   = (unsigned short*)(ws + 9043968);
    unsigned short* w2t   = (unsigned short*)(ws + 15335424);
    unsigned short* e1t   = (unsigned short*)(ws + 21626880);
    unsigned short* e2t   = (unsigned short*)(ws + 23724032);
    float*          h     = (float*)(ws + 25821184);          // 33,554,432
    unsigned short* gbf   = (unsigned short*)(ws + 59375616); // 16,777,216 (ln out; later zbf)
    unsigned short* ubf   = (unsigned short*)(ws + 76152832); // 67,108,864 (ffn1 out)
    unsigned short* hmidg = ubf;                              // (MoE phase)
    unsigned short* eog   = (unsigned short*)(ws + 93978624); // 35,651,584
    char* MISC = ws + 143261696;
    int*    offs     = (int*)(MISC + 0);
    float*  zbias    = (float*)(MISC + 256);
    float*  bfold    = (float*)(MISC + 2304);
    int2*   idx2     = (int2*)(MISC + 8448);
    float2* wts2     = (float2*)(MISC + 139520);
    int2*   slot_map = (int2*)(MISC + 270592);
    float*  gslot    = (float*)(MISC + 401664);
    int*    tok      = (int*)(MISC + 544768);
    float*  bsums    = (float*)(MISC + 684032);
    int*    blockHist= (int*)(MISC + 815104);
    int*    baseArr  = (int*)(MISC + 817152);
    unsigned short* zbf = gbf;
    float* out = (float*)d_out;

    zero_kernel<<<(MAXSLOT + 255)/256, 256, 0, stream>>>((int*)zbias, 512, tok, MAXSLOT);

    ConvArgs ca;
    ca.seg[0] = { x, xbf, B_TOK*IN_DIM/4 };
    ca.seg[1] = { outproj_w, wobf, DEPTH*D_DIM*D_DIM/4 };
    convert_kernel<<<1024, 256, 0, stream>>>(ca);

    TArgs ta;
    int tcur = 0, ti = 0;
    ta.seg[ti] = { embed_w, ebf, IN_DIM, D_DIM, tcur };
    tcur += (IN_DIM/32)*(D_DIM/32); ++ti;
    for (int l = 0; l < DEPTH; ++l){
        ta.seg[ti] = { ffn_w1 + (size_t)l*D_DIM*FF_DIM, w1t + (size_t)l*FF_DIM*D_DIM, D_DIM, FF_DIM, tcur };
        tcur += (D_DIM/32)*(FF_DIM/32); ++ti;
    }
    for (int l = 0; l < DEPTH; ++l){
        ta.seg[ti] = { ffn_w2 + (size_t)l*FF_DIM*D_DIM, w2t + (size_t)l*D_DIM*FF_DIM, FF_DIM, D_DIM, tcur };
        tcur += (FF_DIM/32)*(D_DIM/32); ++ti;
    }
    for (int e = 0; e < NEXP; ++e){
        ta.seg[ti] = { exp_w1 + (size_t)e*D_DIM*EH_DIM, e1t + (size_t)e*EH_DIM*D_DIM, D_DIM, EH_DIM, tcur };
        tcur += (D_DIM/32)*(EH_DIM/32); ++ti;
    }
    for (int e = 0; e < NEXP; ++e){
        ta.seg[ti] = { exp_w2 + (size_t)e*EH_DIM*D_DIM, e2t + (size_t)e*D_DIM*EH_DIM, EH_DIM, D_DIM, tcur };
        tcur += (EH_DIM/32)*(D_DIM/32); ++ti;
    }
    for (int l = 0; l < DEPTH; ++l){
        ta.seg[ti] = { inproj_w + (size_t)l*3*D_DIM*D_DIM + 2*D_DIM*D_DIM,
                       wvtbf + (size_t)l*D_DIM*D_DIM, D_DIM, D_DIM, tcur };
        tcur += (D_DIM/32)*(D_DIM/32); ++ti;
    }
    transpose_kernel<<<tcur, 256, 0, stream>>>(ta);

    foldb_kernel<<<DEPTH, D_DIM, 0, stream>>>(outproj_w, outproj_b, inproj_b, bfold);

    for (int l = 0; l < DEPTH; ++l){
        gemm_bt<EPI_BF16><<<16, 256, 0, stream>>>(
            wobf + (size_t)l*D_DIM*D_DIM, wvtbf + (size_t)l*D_DIM*D_DIM,
            zbias, wfold + (size_t)l*D_DIM*D_DIM, 4, D_DIM, D_DIM);
    }

    gemm_bt<EPI_F32_BIAS><<<(D_DIM/128)*(B_TOK/128), 256, 0, stream>>>(
        xbf, ebf, embed_b, h, D_DIM/128, D_DIM, IN_DIM);

    for (int l = 0; l < DEPTH; ++l){
        ln_kernel<<<B_TOK/4, 256, 0, stream>>>(h, ln1_w + l*D_DIM, ln1_b + l*D_DIM, gbf);
        gemm256<G_F32_RESID,0,0><<<(B_TOK/256)*(D_DIM/128), 512, 0, stream>>>(
            gbf, wfold + (size_t)l*D_DIM*D_DIM, bfold + l*D_DIM, h,
            nullptr, nullptr, 0, 0, nullptr, h, D_DIM/128, D_DIM, D_DIM);
        ln_kernel<<<B_TOK/4, 256, 0, stream>>>(h, ln2_w + l*D_DIM, ln2_b + l*D_DIM, gbf);
        gemm256<G_GELU_BF16,0,0><<<(B_TOK/256)*(FF_DIM/128), 512, 0, stream>>>(
            gbf, w1t + (size_t)l*FF_DIM*D_DIM, ffn_b1 + l*FF_DIM, nullptr,
            nullptr, nullptr, 0, 0, nullptr, ubf, FF_DIM/128, FF_DIM, D_DIM);
        gemm256<G_F32_RESID,0,0><<<(B_TOK/256)*(D_DIM/128), 512, 0, stream>>>(
            ubf, w2t + (size_t)l*D_DIM*FF_DIM, ffn_b2 + l*D_DIM, h,
            nullptr, nullptr, 0, 0, nullptr, h, D_DIM/128, D_DIM, FF_DIM);
    }

    router_kernel<<<B_TOK/4, 256, 0, stream>>>(h, router_w, router_b, zbf, idx2, wts2, bsums);
    aux_kernel<<<1, 256, 0, stream>>>(bsums, out + B_TOK);
    hist_kernel<<<NHBLK, 256, 0, stream>>>(idx2, blockHist);
    scan_kernel<<<1, 64, 0, stream>>>(blockHist, offs, baseArr);
    assign_kernel<<<B_TOK/256, 256, 0, stream>>>(idx2, wts2, baseArr, slot_map, gslot, tok);

    gemm256<G_GELU_BF16,1,1><<<MAXT256*(EH_DIM/128), 512, 0, stream>>>(
        zbf, e1t, exp_b1, nullptr, tok, offs, EH_DIM*D_DIM, EH_DIM, nullptr,
        hmidg, EH_DIM/128, EH_DIM, D_DIM);
    gemm256<G_GATED_BF16,1,0><<<MAXT256*(D_DIM/128), 512, 0, stream>>>(
        hmidg, e2t, exp_b2, nullptr, nullptr, offs, D_DIM*EH_DIM, D_DIM, gslot,
        eog, D_DIM/128, D_DIM, EH_DIM);

    head_kernel<<<B_TOK/4, 256, 0, stream>>>(h, eog, slot_map, head_ln_w, head_ln_b, head_w, head_b, out);
}

// Round 7
// 628.397 us; speedup vs baseline: 1.8611x; 1.0724x over previous
//
#include <hip/hip_runtime.h>
#include <hip/hip_bf16.h>

#define B_TOK 16384
#define IN_DIM 128
#define D_DIM 512
#define DEPTH 3
#define NEXP 8
#define FF_DIM 2048
#define EH_DIM 256
#define MAXSLOT 34816   // 32768 + 8*256, 256-padded expert segments
#define MAXT256 136     // MAXSLOT/256
#define NHBLK 64

typedef __attribute__((ext_vector_type(8))) __bf16 bf16x8;
typedef __attribute__((ext_vector_type(4))) float f32x4;
typedef __attribute__((ext_vector_type(4))) unsigned short u16x4;
typedef __attribute__((ext_vector_type(8))) unsigned short u16x8;

__device__ __forceinline__ unsigned short f2bf(float f){
    unsigned int u = __float_as_uint(f);
    u += 0x7fffu + ((u >> 16) & 1u);
    return (unsigned short)(u >> 16);
}
__device__ __forceinline__ float bf2f(unsigned short u){
    return __uint_as_float(((unsigned int)u) << 16);
}
// tanh-form GELU via fast exp; |err| vs exact erf-GELU <= ~3e-4
__device__ __forceinline__ float geluf(float x){
    float x2 = x * x;
    float y  = x * (0.79788456080287f + 0.03567740814183f * x2);
    y = fminf(fmaxf(y, -15.0f), 15.0f);
    float e = __expf(2.0f * y);
    float th = 1.0f - 2.0f / (e + 1.0f);
    return 0.5f * x * (1.0f + th);
}
__device__ __forceinline__ void gload_lds16(const void* g, void* l){
    __builtin_amdgcn_global_load_lds((const __attribute__((address_space(1))) unsigned int*)g,
                                     (__attribute__((address_space(3))) unsigned int*)l,
                                     16, 0, 0);
}
__device__ __forceinline__ int xcd_swizzle(int orig, int nwg){
    const int q = nwg >> 3, r = nwg & 7;
    const int xcd = orig & 7;
    const int idx = orig >> 3;
    return (xcd < r ? xcd*(q+1) : r*(q+1) + (xcd-r)*q) + idx;
}

// ---------------- zero scratch control state ------------------------------
__global__ void zero_kernel(int* a, int na, int* b, int nb){
    const int i = blockIdx.x * blockDim.x + threadIdx.x;
    if (i < na) a[i] = 0;
    if (i < nb) b[i] = 0;
}

// ---------------- fp32 -> bf16 convert ------------------------------------
struct ConvSeg { const float* src; unsigned short* dst; int n4; };
struct ConvArgs { ConvSeg seg[2]; };

__global__ void convert_kernel(ConvArgs a){
    const int stride = gridDim.x * blockDim.x;
    const int tid = blockIdx.x * blockDim.x + threadIdx.x;
    for (int s = 0; s < 2; ++s){
        const f32x4* src = (const f32x4*)a.seg[s].src;
        u16x4* dst = (u16x4*)a.seg[s].dst;
        const int n4 = a.seg[s].n4;
        for (int i = tid; i < n4; i += stride){
            f32x4 v = src[i];
            u16x4 o;
            o[0] = f2bf(v[0]); o[1] = f2bf(v[1]); o[2] = f2bf(v[2]); o[3] = f2bf(v[3]);
            dst[i] = o;
        }
    }
}

// ------------- weight transpose-convert: (K,N) fp32 -> (N,K) bf16 ---------
struct TSeg { const float* src; unsigned short* dst; int K; int N; int tileStart; };
struct TArgs { TSeg seg[26]; };

__global__ void transpose_kernel(TArgs a){
    __shared__ float t[32][33];
    const int tile = blockIdx.x;
    int s = 0;
    #pragma unroll 1
    while (s < 25 && tile >= a.seg[s+1].tileStart) ++s;
    const TSeg sg = a.seg[s];
    const int local = tile - sg.tileStart;
    const int tilesN = sg.N >> 5;
    const int k0 = (local / tilesN) << 5;
    const int n0 = (local % tilesN) << 5;
    const int tx = threadIdx.x & 31;
    const int ty = threadIdx.x >> 5;
    #pragma unroll
    for (int j = 0; j < 4; ++j)
        t[ty + j*8][tx] = sg.src[(size_t)(k0 + ty + j*8) * sg.N + n0 + tx];
    __syncthreads();
    #pragma unroll
    for (int j = 0; j < 4; ++j){
        const int n = ty + j*8;
        sg.dst[(size_t)(n0 + n) * sg.K + k0 + tx] = f2bf(t[tx][n]);
    }
}

// ---------------- folded attention bias: bfold = Wo@bv + bo ---------------
__global__ void foldb_kernel(const float* __restrict__ outproj_w, const float* __restrict__ outproj_b,
                             const float* __restrict__ inproj_b, float* __restrict__ bfold){
    const int l = blockIdx.x, n = threadIdx.x;
    const float* Wo = outproj_w + ((size_t)l*D_DIM + n)*D_DIM;
    const float* bv = inproj_b + l*3*D_DIM + 2*D_DIM;
    float acc = outproj_b[l*D_DIM + n];
    for (int j = 0; j < D_DIM; ++j) acc += Wo[j]*bv[j];
    bfold[l*D_DIM + n] = acc;
}

// ---------------- small GEMM (embed/fold): 128x128, dbuf, bf16 out --------
__global__ void __launch_bounds__(256, 2)
gemm_bt(const unsigned short* __restrict__ A, const unsigned short* __restrict__ Bt,
        const float* __restrict__ bias, unsigned short* __restrict__ out, int NB, int N, int K)
{
    __shared__ unsigned short sh[32768];
    const int nwg = gridDim.x;
    const int wg  = xcd_swizzle(blockIdx.x, nwg);
    const int bn  = wg % NB;
    const int bm  = wg / NB;

    const int tid  = threadIdx.x;
    const int lane = tid & 63;
    const int wave = tid >> 6;
    const int wm = (wave >> 1) << 6;
    const int wn = (wave & 1) << 6;

    f32x4 acc[4][4] = {};

    const unsigned short* Abase = A + (size_t)bm * 128 * K;
    const unsigned short* Bbase = Bt + (size_t)bn * 128 * K;
    const int soff = tid * 16;

    auto STAGE = [&](int b, int kt){
        char* Ab = (char*)(sh + b*16384);
        char* Bb = (char*)(sh + b*16384 + 8192);
        #pragma unroll
        for (int s = 0; s < 4; ++s){
            const int off = s*4096 + soff;
            const int row = off >> 7, colb = off & 127;
            gload_lds16((const char*)(Abase + (size_t)row*K + kt) + colb, Ab + off);
        }
        #pragma unroll
        for (int s = 0; s < 4; ++s){
            const int off = s*4096 + soff;
            const int row = off >> 7, colb = off & 127;
            gload_lds16((const char*)(Bbase + (size_t)row*K + kt) + colb, Bb + off);
        }
    };
    auto COMPUTE = [&](int b){
        const unsigned short* Ab = sh + b*16384;
        const unsigned short* Bb = sh + b*16384 + 8192;
        #pragma unroll
        for (int ks = 0; ks < 2; ++ks){
            const int k0 = ks*32 + ((lane>>4)<<3);
            bf16x8 af[4], bfr[4];
            #pragma unroll
            for (int i=0;i<4;i++) af[i]  = *(const bf16x8*)&Ab[(wm + i*16 + (lane&15))*64 + k0];
            #pragma unroll
            for (int j=0;j<4;j++) bfr[j] = *(const bf16x8*)&Bb[(wn + j*16 + (lane&15))*64 + k0];
            #pragma unroll
            for (int i=0;i<4;i++)
                #pragma unroll
                for (int j=0;j<4;j++)
                    acc[i][j] = __builtin_amdgcn_mfma_f32_16x16x32_bf16(af[i], bfr[j], acc[i][j], 0, 0, 0);
        }
    };

    STAGE(0, 0);
    __syncthreads();
    const int nk = K >> 6;
    int cur = 0;
    for (int i = 0; i < nk; ++i){
        if (i + 1 < nk) STAGE(cur ^ 1, (i + 1) << 6);
        COMPUTE(cur);
        __syncthreads();
        cur ^= 1;
    }

    const int r0 = ((lane>>4)<<2);
    const int cc = lane & 15;
    unsigned short* Ct = sh;
    float bcol[4];
    #pragma unroll
    for (int j=0;j<4;j++) bcol[j] = bias[bn*128 + wn + j*16 + cc];
    #pragma unroll
    for (int i=0;i<4;i++)
        #pragma unroll
        for (int r=0;r<4;r++){
            const int rl = wm + i*16 + r0 + r;
            #pragma unroll
            for (int j=0;j<4;j++)
                Ct[rl*128 + wn + j*16 + cc] = f2bf(acc[i][j][r] + bcol[j]);
        }
    __syncthreads();
    const int orow = tid >> 4;
    const int ocol = (tid & 15) * 8;
    #pragma unroll
    for (int p = 0; p < 8; ++p){
        const int row = p*16 + orow;
        *(u16x8*)(&out[(size_t)(bm*128 + row)*N + bn*128 + ocol]) = *(u16x8*)&Ct[row*128 + ocol];
    }
}

// =============== 256x256 GEMM, per-wave 128x64, 2-phase dbuf ==============
// 512 thr = 8 waves (2M x 4N). LDS 128KB: A 2x32KB @0, B 2x32KB @64K.
// T2 swizzle (linear LDS dest + inv-swizzled global src + swizzled read).
// Epilogue: bias + GELU + bf16 coalesced store. C = A(M,K) @ Bt(N,K)^T.
__global__ void __launch_bounds__(512, 2)
gemm256sq(const unsigned short* __restrict__ A, const unsigned short* __restrict__ Bt,
          const float* __restrict__ bias, unsigned short* __restrict__ out,
          int NB, int N, int K)
{
    __shared__ __align__(16) char sh[131072];
    const int nwg = gridDim.x;
    const int wg  = xcd_swizzle(blockIdx.x, nwg);
    const int bn  = wg % NB;
    const int bm  = wg / NB;
    const int m0  = bm * 256;
    const int n0  = bn * 256;

    const int tid = threadIdx.x, lane = tid & 63, wave = tid >> 6;
    const int wr = wave >> 2;      // 0..1, rows wr*128..+127
    const int wc = wave & 3;       // 0..3, cols wc*64..+63

    // staging: linear LDS dest, inverse-swizzled global source
    const int srow = wave*16 + (lane >> 3);              // 0..127
    const int scol = ((lane & 7) ^ (lane >> 3)) * 8;     // element offset
    const unsigned short* aptr[2][2];
    const unsigned short* bptr[2][2];
    #pragma unroll
    for (int u = 0; u < 2; ++u)
        #pragma unroll
        for (int l = 0; l < 2; ++l){
            aptr[u][l] = A  + (size_t)(m0 + u*128 + srow + l*8) * K + scol;
            bptr[u][l] = Bt + (size_t)(n0 + u*128 + srow + l*8) * K + scol;
        }
    const int sdst = wave*2048 + lane*16;

    int ch[2];
    #pragma unroll
    for (int ks = 0; ks < 2; ++ks)
        ch[ks] = ((((ks<<2) + (lane>>4)) ^ (lane & 7)) << 4);
    const int arow = wr*128 + (lane & 15);
    const int brow = wc*64  + (lane & 15);

    f32x4 acc[8][4] = {};

    auto STAGE = [&](int buf, int kt){
        #pragma unroll
        for (int u = 0; u < 2; ++u)
            #pragma unroll
            for (int l = 0; l < 2; ++l)
                gload_lds16(aptr[u][l] + kt, sh + buf*32768 + u*16384 + l*1024 + sdst);
        #pragma unroll
        for (int u = 0; u < 2; ++u)
            #pragma unroll
            for (int l = 0; l < 2; ++l)
                gload_lds16(bptr[u][l] + kt, sh + 65536 + buf*32768 + u*16384 + l*1024 + sdst);
    };
    auto COMPUTE = [&](int buf){
        bf16x8 bfr[4][2];
        #pragma unroll
        for (int nf = 0; nf < 4; ++nf)
            #pragma unroll
            for (int ks = 0; ks < 2; ++ks)
                bfr[nf][ks] = *(const bf16x8*)(sh + 65536 + buf*32768 + (brow + nf*16)*128 + ch[ks]);
        #pragma unroll
        for (int mf = 0; mf < 8; ++mf){
            bf16x8 af[2];
            #pragma unroll
            for (int ks = 0; ks < 2; ++ks)
                af[ks] = *(const bf16x8*)(sh + buf*32768 + (arow + mf*16)*128 + ch[ks]);
            #pragma unroll
            for (int nf = 0; nf < 4; ++nf)
                #pragma unroll
                for (int ks = 0; ks < 2; ++ks)
                    acc[mf][nf] = __builtin_amdgcn_mfma_f32_16x16x32_bf16(af[ks], bfr[nf][ks], acc[mf][nf], 0,0,0);
        }
    };

    STAGE(0, 0);
    __syncthreads();
    const int nk = K >> 6;
    int cur = 0;
    for (int i = 0; i < nk; ++i){
        if (i + 1 < nk) STAGE(cur ^ 1, (i + 1) << 6);
        COMPUTE(cur);
        __syncthreads();
        cur ^= 1;
    }

    // epilogue: bias + GELU -> Ct(256x256 bf16, 128KB) -> coalesced store
    unsigned short* Ct = (unsigned short*)sh;
    const int r4 = (lane >> 4) * 4;
    const int cc = lane & 15;
    #pragma unroll
    for (int nf = 0; nf < 4; ++nf){
        const int col = wc*64 + nf*16 + cc;
        const float bv = bias[n0 + col];
        #pragma unroll
        for (int mf = 0; mf < 8; ++mf)
            #pragma unroll
            for (int r = 0; r < 4; ++r){
                const int row = wr*128 + mf*16 + r4 + r;
                Ct[row*256 + col] = f2bf(geluf(acc[mf][nf][r] + bv));
            }
    }
    __syncthreads();
    #pragma unroll
    for (int p = 0; p < 16; ++p){
        const int uidx = p*512 + tid;
        const int row = uidx >> 5;
        const int cu  = uidx & 31;
        *(u16x8*)(out + (size_t)(m0 + row)*N + n0 + cu*8) = *(const u16x8*)(Ct + row*256 + cu*8);
    }
}

// =================== 256x128 pipelined GEMM (from r6) =====================
#define G_GELU_BF16 0
#define G_BF16_RESID 1
#define G_GATED_BF16 2

template<int EPI, int MOE, int INDIRECT>
__global__ void __launch_bounds__(512, 2)
gemm256(const unsigned short* __restrict__ A, const unsigned short* __restrict__ BtG,
        const float* __restrict__ biasG, const unsigned short* __restrict__ resid,
        const int* __restrict__ tok, const int* __restrict__ offs,
        int wstride, int bstride, const float* __restrict__ gslot,
        unsigned short* __restrict__ out, int NB, int N, int K)
{
    __shared__ __align__(16) char sh[147456];
    const int nwg = gridDim.x;
    const int wg  = xcd_swizzle(blockIdx.x, nwg);
    const int bn  = wg % NB;
    const int bm  = wg / NB;
    const int m0  = bm * 256;

    const unsigned short* Bt = BtG;
    const float* bias = biasG;
    if (MOE){
        if (m0 >= offs[8]) return;
        int e = 0;
        #pragma unroll 1
        while (offs[e+1] <= m0) ++e;
        Bt   += (size_t)e * wstride;
        bias += (size_t)e * bstride;
    }

    const int tid = threadIdx.x, lane = tid & 63, wave = tid >> 6;
    const int wm = (wave >> 1) * 64;
    const int wn = (wave & 1) * 64;

    const int srow = wave*16 + (lane >> 3);
    const int scol = ((lane & 7) ^ (lane >> 3)) * 8;
    const unsigned short* aptr[2][2];
    #pragma unroll
    for (int u = 0; u < 2; ++u)
        #pragma unroll
        for (int l = 0; l < 2; ++l){
            const int r = u*128 + srow + l*8;
            const int gr = INDIRECT ? tok[m0 + r] : (m0 + r);
            aptr[u][l] = A + (size_t)gr * K + scol;
        }
    const unsigned short* bptr[2];
    #pragma unroll
    for (int l = 0; l < 2; ++l)
        bptr[l] = Bt + (size_t)(bn*128 + srow + l*8) * K + scol;
    const int sdst = wave*2048 + lane*16;

    int aoff[2], boff[2];
    #pragma unroll
    for (int ks = 0; ks < 2; ++ks){
        const int ch = (((ks<<2) + (lane>>4)) ^ (lane & 7)) << 4;
        aoff[ks] = (wm + (lane & 15))*128 + ch;
        boff[ks] = (wn + (lane & 15))*128 + ch;
    }

    f32x4 acc[4][4] = {};

    auto STAGE = [&](int buf, int kt){
        #pragma unroll
        for (int u = 0; u < 2; ++u)
            #pragma unroll
            for (int l = 0; l < 2; ++l)
                gload_lds16(aptr[u][l] + kt, sh + buf*32768 + u*16384 + l*1024 + sdst);
        #pragma unroll
        for (int l = 0; l < 2; ++l)
            gload_lds16(bptr[l] + kt, sh + 98304 + buf*16384 + l*1024 + sdst);
    };
    auto COMPUTE = [&](int buf){
        bf16x8 bfr[4][2];
        #pragma unroll
        for (int nf = 0; nf < 4; ++nf)
            #pragma unroll
            for (int ks = 0; ks < 2; ++ks)
                bfr[nf][ks] = *(const bf16x8*)(sh + 98304 + buf*16384 + nf*2048 + boff[ks]);
        #pragma unroll
        for (int mf = 0; mf < 4; ++mf){
            bf16x8 af[2];
            #pragma unroll
            for (int ks = 0; ks < 2; ++ks)
                af[ks] = *(const bf16x8*)(sh + buf*32768 + mf*2048 + aoff[ks]);
            #pragma unroll
            for (int nf = 0; nf < 4; ++nf)
                #pragma unroll
                for (int ks = 0; ks < 2; ++ks)
                    acc[mf][nf] = __builtin_amdgcn_mfma_f32_16x16x32_bf16(af[ks], bfr[nf][ks], acc[mf][nf], 0,0,0);
        }
    };

    STAGE(0, 0);
    __syncthreads();
    const int nk = K >> 6;
    int cur = 0;
    for (int i = 0; i < nk; ++i){
        if (i + 1 < nk) STAGE(cur ^ 1, (i + 1) << 6);
        COMPUTE(cur);
        __syncthreads();
        cur ^= 1;
    }

    const int r4 = (lane >> 4) * 4;
    const int cc = lane & 15;
    if (EPI == G_BF16_RESID){
        // stage acc+bias as f32 in LDS, then coalesced bf16 read-add-write
        float* ctf = (float*)sh;   // 256x128 f32 = 128KB
        #pragma unroll
        for (int nf = 0; nf < 4; ++nf){
            const float bv = bias[bn*128 + wn + nf*16 + cc];
            #pragma unroll
            for (int mf = 0; mf < 4; ++mf)
                #pragma unroll
                for (int r = 0; r < 4; ++r){
                    const int row = wm + mf*16 + r4 + r;
                    ctf[row*128 + wn + nf*16 + cc] = acc[mf][nf][r] + bv;
                }
        }
        __syncthreads();
        #pragma unroll
        for (int p = 0; p < 8; ++p){
            const int uidx = p*512 + tid;
            const int row = uidx >> 4;
            const int cu  = uidx & 15;
            const size_t gidx = (size_t)(m0 + row)*N + bn*128 + cu*8;
            u16x8 hv = *(const u16x8*)(resid + gidx);
            u16x8 o;
            #pragma unroll
            for (int j = 0; j < 8; ++j)
                o[j] = f2bf(bf2f(hv[j]) + ctf[row*128 + cu*8 + j]);
            *(u16x8*)(out + gidx) = o;
        }
    } else {
        unsigned short* ct = (unsigned short*)sh;
        #pragma unroll
        for (int nf = 0; nf < 4; ++nf){
            const float bv = bias[bn*128 + wn + nf*16 + cc];
            #pragma unroll
            for (int mf = 0; mf < 4; ++mf)
                #pragma unroll
                for (int r = 0; r < 4; ++r){
                    const int row = wm + mf*16 + r4 + r;
                    float v = acc[mf][nf][r] + bv;
                    if (EPI == G_GELU_BF16) v = geluf(v);
                    else                    v *= gslot[m0 + row];
                    ct[row*128 + wn + nf*16 + cc] = f2bf(v);
                }
        }
        __syncthreads();
        #pragma unroll
        for (int p = 0; p < 8; ++p){
            const int uidx = p*512 + tid;
            const int row = uidx >> 4;
            const int cu  = uidx & 15;
            *(u16x8*)(out + (size_t)(m0 + row)*N + bn*128 + cu*8) =
                *(const u16x8*)(ct + row*128 + cu*8);
        }
    }
}

// ---------------- LayerNorm (bf16 in, bf16 out), one wave per row ---------
__global__ void ln_kernel(const unsigned short* __restrict__ x, const float* __restrict__ w,
                          const float* __restrict__ b, unsigned short* __restrict__ out)
{
    const int lane = threadIdx.x & 63;
    const int wave = threadIdx.x >> 6;
    const int row  = blockIdx.x * 4 + wave;
    u16x8 hv = *(const u16x8*)(x + (size_t)row * D_DIM + lane*8);
    float v[8];
    #pragma unroll
    for (int j = 0; j < 8; ++j) v[j] = bf2f(hv[j]);
    float s = 0.f, s2 = 0.f;
    #pragma unroll
    for (int j = 0; j < 8; ++j){ s += v[j]; s2 += v[j]*v[j]; }
    #pragma unroll
    for (int o = 32; o > 0; o >>= 1){ s += __shfl_xor(s, o); s2 += __shfl_xor(s2, o); }
    const float mean = s * (1.0f/512.0f);
    const float var  = s2 * (1.0f/512.0f) - mean*mean;
    const float inv  = 1.0f / sqrtf(var + 1e-5f);
    const int k = lane*8;
    u16x8 o;
    #pragma unroll
    for (int j = 0; j < 8; ++j) o[j] = f2bf((v[j]-mean)*inv*w[k+j] + b[k+j]);
    *(u16x8*)(out + (size_t)row*D_DIM + k) = o;
}

// ------- Router: softmax+eps-mix+top2 (bf16 z in, no global atomics) ------
__global__ void router_kernel(const unsigned short* __restrict__ z, const float* __restrict__ rw,
                              const float* __restrict__ rb,
                              int2* __restrict__ idx2, float2* __restrict__ wts2,
                              float* __restrict__ bsums)
{
    __shared__ float ps[4][8];
    const int lane = threadIdx.x & 63;
    const int wave = threadIdx.x >> 6;
    const int row  = blockIdx.x * 4 + wave;
    u16x8 hv = *(const u16x8*)(z + (size_t)row * D_DIM + lane*8);
    float acc[8] = {0,0,0,0,0,0,0,0};
    #pragma unroll
    for (int j = 0; j < 8; ++j){
        const float zv = bf2f(hv[j]);
        const float* wr = rw + (size_t)(lane*8 + j) * 8;
        f32x4 w0 = *(const f32x4*)wr;
        f32x4 w1 = *(const f32x4*)(wr + 4);
        acc[0] += zv*w0[0]; acc[1] += zv*w0[1]; acc[2] += zv*w0[2]; acc[3] += zv*w0[3];
        acc[4] += zv*w1[0]; acc[5] += zv*w1[1]; acc[6] += zv*w1[2]; acc[7] += zv*w1[3];
    }
    #pragma unroll
    for (int o = 32; o > 0; o >>= 1){
        #pragma unroll
        for (int e = 0; e < 8; ++e) acc[e] += __shfl_xor(acc[e], o);
    }
    if (lane == 0){
        float p[8]; float mx = -1e30f;
        #pragma unroll
        for (int e=0;e<8;e++){ p[e] = acc[e] + rb[e]; mx = fmaxf(mx, p[e]); }
        float se = 0.f;
        #pragma unroll
        for (int e=0;e<8;e++){ p[e] = expf(p[e]-mx); se += p[e]; }
        const float sc = 0.9f / se;
        #pragma unroll
        for (int e=0;e<8;e++) p[e] = p[e]*sc + 0.0125f;
        int i1 = 0;
        #pragma unroll
        for (int e=1;e<8;e++) if (p[e] > p[i1]) i1 = e;
        int i2 = (i1 == 0) ? 1 : 0;
        for (int e=i2+1;e<8;e++) if (e != i1 && p[e] > p[i2]) i2 = e;
        idx2[row] = make_int2(i1, i2);
        wts2[row] = make_float2(p[i1], p[i2]);
        #pragma unroll
        for (int e=0;e<8;e++) ps[wave][e] = p[e];
    }
    __syncthreads();
    if (threadIdx.x < 8){
        bsums[blockIdx.x*8 + threadIdx.x] =
            ps[0][threadIdx.x] + ps[1][threadIdx.x] + ps[2][threadIdx.x] + ps[3][threadIdx.x];
    }
}

// ------- histogram / scan / assign (block-local, no global atomics) -------
__global__ void hist_kernel(const int2* __restrict__ idx2, int* __restrict__ blockHist){
    __shared__ int hc[8];
    if (threadIdx.x < 8) hc[threadIdx.x] = 0;
    __syncthreads();
    const int t = blockIdx.x * 256 + threadIdx.x;
    const int2 ii = idx2[t];
    atomicAdd(&hc[ii.x], 1);
    atomicAdd(&hc[ii.y], 1);
    __syncthreads();
    if (threadIdx.x < 8) blockHist[blockIdx.x*8 + threadIdx.x] = hc[threadIdx.x];
}

__global__ void scan_kernel(const int* __restrict__ blockHist, int* __restrict__ offs,
                            int* __restrict__ baseArr){
    if (threadIdx.x == 0){
        int counts[8];
        #pragma unroll
        for (int e=0;e<8;e++) counts[e] = 0;
        for (int b=0;b<NHBLK;b++)
            #pragma unroll
            for (int e=0;e<8;e++) counts[e] += blockHist[b*8+e];
        int o = 0; offs[0] = 0;
        int start[8];
        #pragma unroll
        for (int e=0;e<8;e++){ start[e] = o; o += (counts[e]+255)&~255; offs[e+1] = o; }
        for (int e=0;e<8;e++){
            int cur = start[e];
            for (int b=0;b<NHBLK;b++){ baseArr[b*8+e] = cur; cur += blockHist[b*8+e]; }
        }
    }
}

__global__ void assign_kernel(const int2* __restrict__ idx2, const float2* __restrict__ wts2,
                              const int* __restrict__ baseArr, int2* __restrict__ slot_map,
                              float* __restrict__ gslot, int* __restrict__ tok)
{
    __shared__ int cur[8];
    if (threadIdx.x < 8) cur[threadIdx.x] = 0;
    __syncthreads();
    const int t = blockIdx.x * 256 + threadIdx.x;
    const int2 ii = idx2[t];
    const float2 ww = wts2[t];
    const int r1 = atomicAdd(&cur[ii.x], 1);
    const int r2 = atomicAdd(&cur[ii.y], 1);
    const int s1 = baseArr[blockIdx.x*8 + ii.x] + r1;
    const int s2 = baseArr[blockIdx.x*8 + ii.y] + r2;
    slot_map[t] = make_int2(s1, s2);
    gslot[s1] = ww.x; gslot[s2] = ww.y;
    tok[s1] = t; tok[s2] = t;
}

// ---------------- aux loss ------------------------------------------------
__global__ void aux_kernel(const float* __restrict__ bsums, float* __restrict__ out_aux)
{
    __shared__ float part[256];
    const int t = threadIdx.x;
    const int e = t & 7, chunk = t >> 3;
    float s = 0.f;
    for (int blk = chunk*128; blk < chunk*128 + 128; ++blk) s += bsums[blk*8 + e];
    part[t] = s;
    __syncthreads();
    if (t < 8){
        float tot = 0.f;
        for (int c = 0; c < 32; ++c) tot += part[c*8 + t];
        part[t] = tot;
    }
    __syncthreads();
    if (t == 0){
        float aux = 0.f;
        for (int e2 = 0; e2 < 8; ++e2){
            float load = part[e2] * (1.0f/16384.0f);
            aux += load * logf(load * 8.0f + 1e-9f);
        }
        out_aux[0] = aux / 2.0794415416798357f;
    }
}

// -------- head: z = h + eo[s1] + eo[s2]; LN; dot --------------------------
__global__ void head_kernel(const unsigned short* __restrict__ h, const unsigned short* __restrict__ eog,
                            const int2* __restrict__ slot_map,
                            const float* __restrict__ w, const float* __restrict__ b,
                            const float* __restrict__ hw, const float* __restrict__ hb,
                            float* __restrict__ out)
{
    const int lane = threadIdx.x & 63;
    const int wave = threadIdx.x >> 6;
    const int row  = blockIdx.x * 4 + wave;
    const int2 sm = slot_map[row];
    u16x8 hv = *(const u16x8*)(h + (size_t)row * D_DIM + lane*8);
    u16x8 e1 = *(const u16x8*)(eog + (size_t)sm.x * D_DIM + lane*8);
    u16x8 e2 = *(const u16x8*)(eog + (size_t)sm.y * D_DIM + lane*8);
    float v[8];
    #pragma unroll
    for (int j=0;j<8;j++) v[j] = bf2f(hv[j]) + bf2f(e1[j]) + bf2f(e2[j]);
    float s = 0.f, s2 = 0.f;
    #pragma unroll
    for (int j=0;j<8;j++){ s += v[j]; s2 += v[j]*v[j]; }
    #pragma unroll
    for (int o = 32; o > 0; o >>= 1){ s += __shfl_xor(s, o); s2 += __shfl_xor(s2, o); }
    const float mean = s * (1.0f/512.0f);
    const float var  = s2 * (1.0f/512.0f) - mean*mean;
    const float inv  = 1.0f / sqrtf(var + 1e-5f);
    const int k = lane*8;
    float dot = 0.f;
    #pragma unroll
    for (int j=0;j<8;j++) dot += ((v[j]-mean)*inv*w[k+j] + b[k+j]) * hw[k+j];
    #pragma unroll
    for (int o = 32; o > 0; o >>= 1) dot += __shfl_xor(dot, o);
    if (lane == 0) out[row] = dot + hb[0];
}

// ===========================================================================
extern "C" void kernel_launch(void* const* d_in, const int* in_sizes, int n_in,
                              void* d_out, int out_size, void* d_ws, size_t ws_size,
                              hipStream_t stream)
{
    (void)in_sizes; (void)n_in; (void)out_size; (void)ws_size;
    const float* x         = (const float*)d_in[0];
    const float* embed_w   = (const float*)d_in[1];
    const float* embed_b   = (const float*)d_in[2];
    const float* ln1_w     = (const float*)d_in[3];
    const float* ln1_b     = (const float*)d_in[4];
    const float* inproj_w  = (const float*)d_in[5];
    const float* inproj_b  = (const float*)d_in[6];
    const float* outproj_w = (const float*)d_in[7];
    const float* outproj_b = (const float*)d_in[8];
    const float* ln2_w     = (const float*)d_in[9];
    const float* ln2_b     = (const float*)d_in[10];
    const float* ffn_w1    = (const float*)d_in[11];
    const float* ffn_b1    = (const float*)d_in[12];
    const float* ffn_w2    = (const float*)d_in[13];
    const float* ffn_b2    = (const float*)d_in[14];
    const float* router_w  = (const float*)d_in[15];
    const float* router_b  = (const float*)d_in[16];
    const float* exp_w1    = (const float*)d_in[17];
    const float* exp_b1    = (const float*)d_in[18];
    const float* exp_w2    = (const float*)d_in[19];
    const float* exp_b2    = (const float*)d_in[20];
    const float* head_ln_w = (const float*)d_in[21];
    const float* head_ln_b = (const float*)d_in[22];
    const float* head_w    = (const float*)d_in[23];
    const float* head_b    = (const float*)d_in[24];

    char* ws = (char*)d_ws;
    unsigned short* xbf   = (unsigned short*)(ws + 0);            //  4,194,304
    unsigned short* ebf   = (unsigned short*)(ws + 4194304);      //    131,072
    unsigned short* wobf  = (unsigned short*)(ws + 4325376);      //  1,572,864
    unsigned short* wvtbf = (unsigned short*)(ws + 5898240);      //  1,572,864
    unsigned short* wfold = (unsigned short*)(ws + 7471104);      //  1,572,864
    unsigned short* w1t   = (unsigned short*)(ws + 9043968);      //  6,291,456
    unsigned short* w2t   = (unsigned short*)(ws + 15335424);     //  6,291,456
    unsigned short* e1t   = (unsigned short*)(ws + 21626880);     //  2,097,152
    unsigned short* e2t   = (unsigned short*)(ws + 23724032);     //  2,097,152
    unsigned short* h     = (unsigned short*)(ws + 25821184);     // 16,777,216 bf16 residual
    unsigned short* gbf   = (unsigned short*)(ws + 42598400);     // 16,777,216 ln out
    unsigned short* ubf   = (unsigned short*)(ws + 59375616);     // 67,108,864 ffn1 out
    unsigned short* hmidg = ubf;                                  // 17,825,792 MoE hidden
    unsigned short* eog   = (unsigned short*)(ws + 77201408);     // 35,651,584 (inside ubf region)
    char* MISC = ws + 126484480;
    int*    offs     = (int*)(MISC + 0);
    float*  zbias    = (float*)(MISC + 256);
    float*  bfold    = (float*)(MISC + 2304);
    int2*   idx2     = (int2*)(MISC + 8448);
    float2* wts2     = (float2*)(MISC + 139520);
    int2*   slot_map = (int2*)(MISC + 270592);
    float*  gslot    = (float*)(MISC + 401664);
    int*    tok      = (int*)(MISC + 544768);
    float*  bsums    = (float*)(MISC + 684032);
    int*    blockHist= (int*)(MISC + 815104);
    int*    baseArr  = (int*)(MISC + 817152);
    float* out = (float*)d_out;

    zero_kernel<<<(MAXSLOT + 255)/256, 256, 0, stream>>>((int*)zbias, 512, tok, MAXSLOT);

    ConvArgs ca;
    ca.seg[0] = { x, xbf, B_TOK*IN_DIM/4 };
    ca.seg[1] = { outproj_w, wobf, DEPTH*D_DIM*D_DIM/4 };
    convert_kernel<<<1024, 256, 0, stream>>>(ca);

    TArgs ta;
    int tcur = 0, ti = 0;
    ta.seg[ti] = { embed_w, ebf, IN_DIM, D_DIM, tcur };
    tcur += (IN_DIM/32)*(D_DIM/32); ++ti;
    for (int l = 0; l < DEPTH; ++l){
        ta.seg[ti] = { ffn_w1 + (size_t)l*D_DIM*FF_DIM, w1t + (size_t)l*FF_DIM*D_DIM, D_DIM, FF_DIM, tcur };
        tcur += (D_DIM/32)*(FF_DIM/32); ++ti;
    }
    for (int l = 0; l < DEPTH; ++l){
        ta.seg[ti] = { ffn_w2 + (size_t)l*FF_DIM*D_DIM, w2t + (size_t)l*D_DIM*FF_DIM, FF_DIM, D_DIM, tcur };
        tcur += (FF_DIM/32)*(D_DIM/32); ++ti;
    }
    for (int e = 0; e < NEXP; ++e){
        ta.seg[ti] = { exp_w1 + (size_t)e*D_DIM*EH_DIM, e1t + (size_t)e*EH_DIM*D_DIM, D_DIM, EH_DIM, tcur };
        tcur += (D_DIM/32)*(EH_DIM/32); ++ti;
    }
    for (int e = 0; e < NEXP; ++e){
        ta.seg[ti] = { exp_w2 + (size_t)e*EH_DIM*D_DIM, e2t + (size_t)e*D_DIM*EH_DIM, EH_DIM, D_DIM, tcur };
        tcur += (EH_DIM/32)*(D_DIM/32); ++ti;
    }
    for (int l = 0; l < DEPTH; ++l){
        ta.seg[ti] = { inproj_w + (size_t)l*3*D_DIM*D_DIM + 2*D_DIM*D_DIM,
                       wvtbf + (size_t)l*D_DIM*D_DIM, D_DIM, D_DIM, tcur };
        tcur += (D_DIM/32)*(D_DIM/32); ++ti;
    }
    transpose_kernel<<<tcur, 256, 0, stream>>>(ta);

    foldb_kernel<<<DEPTH, D_DIM, 0, stream>>>(outproj_w, outproj_b, inproj_b, bfold);

    for (int l = 0; l < DEPTH; ++l){
        gemm_bt<<<16, 256, 0, stream>>>(
            wobf + (size_t)l*D_DIM*D_DIM, wvtbf + (size_t)l*D_DIM*D_DIM,
            zbias, wfold + (size_t)l*D_DIM*D_DIM, 4, D_DIM, D_DIM);
    }

    // embed: h(bf16) = x @ embed_w + embed_b
    gemm_bt<<<(D_DIM/128)*(B_TOK/128), 256, 0, stream>>>(
        xbf, ebf, embed_b, h, D_DIM/128, D_DIM, IN_DIM);

    for (int l = 0; l < DEPTH; ++l){
        ln_kernel<<<B_TOK/4, 256, 0, stream>>>(h, ln1_w + l*D_DIM, ln1_b + l*D_DIM, gbf);
        gemm256<G_BF16_RESID,0,0><<<(B_TOK/256)*(D_DIM/128), 512, 0, stream>>>(
            gbf, wfold + (size_t)l*D_DIM*D_DIM, bfold + l*D_DIM, h,
            nullptr, nullptr, 0, 0, nullptr, h, D_DIM/128, D_DIM, D_DIM);
        ln_kernel<<<B_TOK/4, 256, 0, stream>>>(h, ln2_w + l*D_DIM, ln2_b + l*D_DIM, gbf);
        gemm256sq<<<(B_TOK/256)*(FF_DIM/256), 512, 0, stream>>>(
            gbf, w1t + (size_t)l*FF_DIM*D_DIM, ffn_b1 + l*FF_DIM, ubf, FF_DIM/256, FF_DIM, D_DIM);
        gemm256<G_BF16_RESID,0,0><<<(B_TOK/256)*(D_DIM/128), 512, 0, stream>>>(
            ubf, w2t + (size_t)l*D_DIM*FF_DIM, ffn_b2 + l*D_DIM, h,
            nullptr, nullptr, 0, 0, nullptr, h, D_DIM/128, D_DIM, FF_DIM);
    }

    router_kernel<<<B_TOK/4, 256, 0, stream>>>(h, router_w, router_b, idx2, wts2, bsums);
    aux_kernel<<<1, 256, 0, stream>>>(bsums, out + B_TOK);
    hist_kernel<<<NHBLK, 256, 0, stream>>>(idx2, blockHist);
    scan_kernel<<<1, 64, 0, stream>>>(blockHist, offs, baseArr);
    assign_kernel<<<B_TOK/256, 256, 0, stream>>>(idx2, wts2, baseArr, slot_map, gslot, tok);

    gemm256<G_GELU_BF16,1,1><<<MAXT256*(EH_DIM/128), 512, 0, stream>>>(
        h, e1t, exp_b1, nullptr, tok, offs, EH_DIM*D_DIM, EH_DIM, nullptr,
        hmidg, EH_DIM/128, EH_DIM, D_DIM);
    gemm256<G_GATED_BF16,1,0><<<MAXT256*(D_DIM/128), 512, 0, stream>>>(
        hmidg, e2t, exp_b2, nullptr, nullptr, offs, D_DIM*EH_DIM, D_DIM, gslot,
        eog, D_DIM/128, D_DIM, EH_DIM);

    head_kernel<<<B_TOK/4, 256, 0, stream>>>(h, eog, slot_map, head_ln_w, head_ln_b, head_w, head_b, out);
}

// Round 8
// 624.005 us; speedup vs baseline: 1.8742x; 1.0070x over previous
//
#include <hip/hip_runtime.h>
#include <hip/hip_bf16.h>

#define B_TOK 16384
#define IN_DIM 128
#define D_DIM 512
#define DEPTH 3
#define NEXP 8
#define FF_DIM 2048
#define EH_DIM 256
#define MAXSLOT 34816
#define MAXT256 136
#define NHBLK 64

typedef __attribute__((ext_vector_type(8))) __bf16 bf16x8;
typedef __attribute__((ext_vector_type(4))) float f32x4;
typedef __attribute__((ext_vector_type(4))) unsigned short u16x4;
typedef __attribute__((ext_vector_type(8))) unsigned short u16x8;

__device__ __forceinline__ unsigned short f2bf(float f){
    unsigned int u = __float_as_uint(f);
    u += 0x7fffu + ((u >> 16) & 1u);
    return (unsigned short)(u >> 16);
}
__device__ __forceinline__ float bf2f(unsigned short u){
    return __uint_as_float(((unsigned int)u) << 16);
}
__device__ __forceinline__ float geluf(float x){
    float x2 = x * x;
    float y  = x * (0.79788456080287f + 0.03567740814183f * x2);
    y = fminf(fmaxf(y, -15.0f), 15.0f);
    float e = __expf(2.0f * y);
    float th = 1.0f - 2.0f / (e + 1.0f);
    return 0.5f * x * (1.0f + th);
}
__device__ __forceinline__ void gload_lds16(const void* g, void* l){
    __builtin_amdgcn_global_load_lds((const __attribute__((address_space(1))) unsigned int*)g,
                                     (__attribute__((address_space(3))) unsigned int*)l,
                                     16, 0, 0);
}
__device__ __forceinline__ int xcd_swizzle(int orig, int nwg){
    const int q = nwg >> 3, r = nwg & 7;
    const int xcd = orig & 7;
    const int idx = orig >> 3;
    return (xcd < r ? xcd*(q+1) : r*(q+1) + (xcd-r)*q) + idx;
}
__device__ __forceinline__ void wgbar(){
    asm volatile("" ::: "memory");
    __builtin_amdgcn_s_barrier();
    asm volatile("" ::: "memory");
}

// ---------------- zero scratch control state ------------------------------
__global__ void zero_kernel(int* a, int na, int* b, int nb){
    const int i = blockIdx.x * blockDim.x + threadIdx.x;
    if (i < na) a[i] = 0;
    if (i < nb) b[i] = 0;
}

// ---------------- fp32 -> bf16 convert ------------------------------------
struct ConvSeg { const float* src; unsigned short* dst; int n4; };
struct ConvArgs { ConvSeg seg[2]; };

__global__ void convert_kernel(ConvArgs a){
    const int stride = gridDim.x * blockDim.x;
    const int tid = blockIdx.x * blockDim.x + threadIdx.x;
    for (int s = 0; s < 2; ++s){
        const f32x4* src = (const f32x4*)a.seg[s].src;
        u16x4* dst = (u16x4*)a.seg[s].dst;
        const int n4 = a.seg[s].n4;
        for (int i = tid; i < n4; i += stride){
            f32x4 v = src[i];
            u16x4 o;
            o[0] = f2bf(v[0]); o[1] = f2bf(v[1]); o[2] = f2bf(v[2]); o[3] = f2bf(v[3]);
            dst[i] = o;
        }
    }
}

// ------------- weight transpose-convert: (K,N) fp32 -> (N,K) bf16 ---------
struct TSeg { const float* src; unsigned short* dst; int K; int N; int tileStart; };
struct TArgs { TSeg seg[26]; };

__global__ void transpose_kernel(TArgs a){
    __shared__ float t[32][33];
    const int tile = blockIdx.x;
    int s = 0;
    #pragma unroll 1
    while (s < 25 && tile >= a.seg[s+1].tileStart) ++s;
    const TSeg sg = a.seg[s];
    const int local = tile - sg.tileStart;
    const int tilesN = sg.N >> 5;
    const int k0 = (local / tilesN) << 5;
    const int n0 = (local % tilesN) << 5;
    const int tx = threadIdx.x & 31;
    const int ty = threadIdx.x >> 5;
    #pragma unroll
    for (int j = 0; j < 4; ++j)
        t[ty + j*8][tx] = sg.src[(size_t)(k0 + ty + j*8) * sg.N + n0 + tx];
    __syncthreads();
    #pragma unroll
    for (int j = 0; j < 4; ++j){
        const int n = ty + j*8;
        sg.dst[(size_t)(n0 + n) * sg.K + k0 + tx] = f2bf(t[tx][n]);
    }
}

// ---------------- folded attention bias: bfold = Wo@bv + bo ---------------
__global__ void foldb_kernel(const float* __restrict__ outproj_w, const float* __restrict__ outproj_b,
                             const float* __restrict__ inproj_b, float* __restrict__ bfold){
    const int l = blockIdx.x, n = threadIdx.x;
    const float* Wo = outproj_w + ((size_t)l*D_DIM + n)*D_DIM;
    const float* bv = inproj_b + l*3*D_DIM + 2*D_DIM;
    float acc = outproj_b[l*D_DIM + n];
    for (int j = 0; j < D_DIM; ++j) acc += Wo[j]*bv[j];
    bfold[l*D_DIM + n] = acc;
}

// ---------------- small GEMM (embed/fold): 128x128, dbuf, bf16 out --------
__global__ void __launch_bounds__(256, 2)
gemm_bt(const unsigned short* __restrict__ A, const unsigned short* __restrict__ Bt,
        const float* __restrict__ bias, unsigned short* __restrict__ out, int NB, int N, int K)
{
    __shared__ unsigned short sh[32768];
    const int nwg = gridDim.x;
    const int wg  = xcd_swizzle(blockIdx.x, nwg);
    const int bn  = wg % NB;
    const int bm  = wg / NB;

    const int tid  = threadIdx.x;
    const int lane = tid & 63;
    const int wave = tid >> 6;
    const int wm = (wave >> 1) << 6;
    const int wn = (wave & 1) << 6;

    f32x4 acc[4][4] = {};

    const unsigned short* Abase = A + (size_t)bm * 128 * K;
    const unsigned short* Bbase = Bt + (size_t)bn * 128 * K;
    const int soff = tid * 16;

    auto STAGE = [&](int b, int kt){
        char* Ab = (char*)(sh + b*16384);
        char* Bb = (char*)(sh + b*16384 + 8192);
        #pragma unroll
        for (int s = 0; s < 4; ++s){
            const int off = s*4096 + soff;
            const int row = off >> 7, colb = off & 127;
            gload_lds16((const char*)(Abase + (size_t)row*K + kt) + colb, Ab + off);
        }
        #pragma unroll
        for (int s = 0; s < 4; ++s){
            const int off = s*4096 + soff;
            const int row = off >> 7, colb = off & 127;
            gload_lds16((const char*)(Bbase + (size_t)row*K + kt) + colb, Bb + off);
        }
    };
    auto COMPUTE = [&](int b){
        const unsigned short* Ab = sh + b*16384;
        const unsigned short* Bb = sh + b*16384 + 8192;
        #pragma unroll
        for (int ks = 0; ks < 2; ++ks){
            const int k0 = ks*32 + ((lane>>4)<<3);
            bf16x8 af[4], bfr[4];
            #pragma unroll
            for (int i=0;i<4;i++) af[i]  = *(const bf16x8*)&Ab[(wm + i*16 + (lane&15))*64 + k0];
            #pragma unroll
            for (int j=0;j<4;j++) bfr[j] = *(const bf16x8*)&Bb[(wn + j*16 + (lane&15))*64 + k0];
            #pragma unroll
            for (int i=0;i<4;i++)
                #pragma unroll
                for (int j=0;j<4;j++)
                    acc[i][j] = __builtin_amdgcn_mfma_f32_16x16x32_bf16(af[i], bfr[j], acc[i][j], 0, 0, 0);
        }
    };

    STAGE(0, 0);
    __syncthreads();
    const int nk = K >> 6;
    int cur = 0;
    for (int i = 0; i < nk; ++i){
        if (i + 1 < nk) STAGE(cur ^ 1, (i + 1) << 6);
        COMPUTE(cur);
        __syncthreads();
        cur ^= 1;
    }

    const int r0 = ((lane>>4)<<2);
    const int cc = lane & 15;
    unsigned short* Ct = sh;
    float bcol[4];
    #pragma unroll
    for (int j=0;j<4;j++) bcol[j] = bias[bn*128 + wn + j*16 + cc];
    #pragma unroll
    for (int i=0;i<4;i++)
        #pragma unroll
        for (int r=0;r<4;r++){
            const int rl = wm + i*16 + r0 + r;
            #pragma unroll
            for (int j=0;j<4;j++)
                Ct[rl*128 + wn + j*16 + cc] = f2bf(acc[i][j][r] + bcol[j]);
        }
    __syncthreads();
    const int orow = tid >> 4;
    const int ocol = (tid & 15) * 8;
    #pragma unroll
    for (int p = 0; p < 8; ++p){
        const int row = p*16 + orow;
        *(u16x8*)(&out[(size_t)(bm*128 + row)*N + bn*128 + ocol]) = *(u16x8*)&Ct[row*128 + ocol];
    }
}

// ========== 256x256 8-phase GEMM (T2+T3+T4+T5), per-wave 128x64 ==========
// 512 thr, 8 waves (2M x 4N). LDS 128KB: A buf*32768 (+half*16384),
// B 65536 + buf*32768 (+half*16384). Row-major 128B rows, chunk-XOR swizzle.
// Half-tile units (16KB, 2 gloads/thr): issue order B0,B1,Alo,Ahi of t+1
// during t's 4 phases; counted vmcnt(4)@q0, vmcnt(6)@q2; raw s_barrier.
__global__ void __launch_bounds__(512, 2)
gemm256sq(const unsigned short* __restrict__ A, const unsigned short* __restrict__ Bt,
          const float* __restrict__ bias, unsigned short* __restrict__ out,
          int NB, int N, int K)
{
    __shared__ __align__(16) char sh[131072];
    const int nwg = gridDim.x;
    const int wg  = xcd_swizzle(blockIdx.x, nwg);
    const int bn  = wg % NB;
    const int bm  = wg / NB;
    const int m0  = bm * 256;
    const int n0  = bn * 256;

    const int tid = threadIdx.x, lane = tid & 63, wave = tid >> 6;
    const int wr = wave >> 2;      // 0..1
    const int wc = wave & 3;       // 0..3

    const int scol = ((lane & 7) ^ (lane >> 3)) * 8;   // inverse-swizzle source chunk

    // ---- staging pointers: unit = 16KB = 16 wave-loads (idx = wave*2+l) ---
    const unsigned short* apt[2]; int adst[2];
    const unsigned short* bpt[2]; int bdst[2];
    #pragma unroll
    for (int l = 0; l < 2; ++l){
        const int idx  = wave*2 + l;
        const int half = idx >> 3;          // A: which 128-row half
        const int rb   = idx & 7;           // 8-row block within unit-half
        apt[l]  = A  + (size_t)(m0 + half*128 + rb*8 + (lane>>3)) * K + scol;
        adst[l] = half*16384 + rb*1024 + lane*16;          // + unit*8192 + buf*32768
        bpt[l]  = Bt + (size_t)(n0 + idx*8 + (lane>>3)) * K + scol;
        bdst[l] = 65536 + idx*1024 + lane*16;              // + u*16384 + buf*32768
    }

    auto STA = [&](int buf, int unit, int kt){
        #pragma unroll
        for (int l = 0; l < 2; ++l)
            gload_lds16(apt[l] + (size_t)unit*64*K + kt, sh + buf*32768 + adst[l] + unit*8192);
    };
    auto STB = [&](int buf, int u, int kt){
        #pragma unroll
        for (int l = 0; l < 2; ++l)
            gload_lds16(bpt[l] + (size_t)u*128*K + kt, sh + buf*32768 + bdst[l] + u*16384);
    };

    // ---- swizzled read offsets -------------------------------------------
    int ch[2];
    #pragma unroll
    for (int ks = 0; ks < 2; ++ks)
        ch[ks] = ((((ks<<2) + (lane>>4)) ^ (lane & 7)) << 4);
    const int arow = wr*128 + (lane & 15);
    const int brow = wc*64  + (lane & 15);

    f32x4 acc[8][4] = {};
    bf16x8 bfr[4][2];

    // ---- prologue: tile0 units in ledger order B0,B1,Alo,Ahi -------------
    STB(0, 0, 0); STB(0, 1, 0); STA(0, 0, 0); STA(0, 1, 0);

    const int nk = K >> 6;
    for (int t = 0; t < nk; ++t){
        const int buf = t & 1, nbuf = buf ^ 1;
        const bool more = (t + 1) < nk;
        const int ktn = (t + 1) << 6;

        // ---------------- q0: B frags + A rows 0..31 ----------------------
        if (more) STB(nbuf, 0, ktn);
        if (more) asm volatile("s_waitcnt vmcnt(4)" ::: "memory");
        else      asm volatile("s_waitcnt vmcnt(2)" ::: "memory");
        wgbar();
        #pragma unroll
        for (int nf = 0; nf < 4; ++nf)
            #pragma unroll
            for (int ks = 0; ks < 2; ++ks)
                bfr[nf][ks] = *(const bf16x8*)(sh + 65536 + buf*32768 + (brow + nf*16)*128 + ch[ks]);
        {
            bf16x8 af[2][2];
            #pragma unroll
            for (int m2 = 0; m2 < 2; ++m2)
                #pragma unroll
                for (int ks = 0; ks < 2; ++ks)
                    af[m2][ks] = *(const bf16x8*)(sh + buf*32768 + (arow + (0+m2)*16)*128 + ch[ks]);
            __builtin_amdgcn_s_setprio(1);
            #pragma unroll
            for (int m2 = 0; m2 < 2; ++m2)
                #pragma unroll
                for (int nf = 0; nf < 4; ++nf)
                    #pragma unroll
                    for (int ks = 0; ks < 2; ++ks)
                        acc[0+m2][nf] = __builtin_amdgcn_mfma_f32_16x16x32_bf16(af[m2][ks], bfr[nf][ks], acc[0+m2][nf], 0,0,0);
            __builtin_amdgcn_s_setprio(0);
        }

        // ---------------- q1: A rows 32..63 -------------------------------
        if (more) STB(nbuf, 1, ktn);
        wgbar();
        {
            bf16x8 af[2][2];
            #pragma unroll
            for (int m2 = 0; m2 < 2; ++m2)
                #pragma unroll
                for (int ks = 0; ks < 2; ++ks)
                    af[m2][ks] = *(const bf16x8*)(sh + buf*32768 + (arow + (2+m2)*16)*128 + ch[ks]);
            __builtin_amdgcn_s_setprio(1);
            #pragma unroll
            for (int m2 = 0; m2 < 2; ++m2)
                #pragma unroll
                for (int nf = 0; nf < 4; ++nf)
                    #pragma unroll
                    for (int ks = 0; ks < 2; ++ks)
                        acc[2+m2][nf] = __builtin_amdgcn_mfma_f32_16x16x32_bf16(af[m2][ks], bfr[nf][ks], acc[2+m2][nf], 0,0,0);
            __builtin_amdgcn_s_setprio(0);
        }

        // ---------------- q2: A rows 64..95 -------------------------------
        if (more) STA(nbuf, 0, ktn);
        if (more) asm volatile("s_waitcnt vmcnt(6)" ::: "memory");
        else      asm volatile("s_waitcnt vmcnt(0)" ::: "memory");
        wgbar();
        {
            bf16x8 af[2][2];
            #pragma unroll
            for (int m2 = 0; m2 < 2; ++m2)
                #pragma unroll
                for (int ks = 0; ks < 2; ++ks)
                    af[m2][ks] = *(const bf16x8*)(sh + buf*32768 + (arow + (4+m2)*16)*128 + ch[ks]);
            __builtin_amdgcn_s_setprio(1);
            #pragma unroll
            for (int m2 = 0; m2 < 2; ++m2)
                #pragma unroll
                for (int nf = 0; nf < 4; ++nf)
                    #pragma unroll
                    for (int ks = 0; ks < 2; ++ks)
                        acc[4+m2][nf] = __builtin_amdgcn_mfma_f32_16x16x32_bf16(af[m2][ks], bfr[nf][ks], acc[4+m2][nf], 0,0,0);
            __builtin_amdgcn_s_setprio(0);
        }

        // ---------------- q3: A rows 96..127 ------------------------------
        if (more) STA(nbuf, 1, ktn);
        wgbar();
        {
            bf16x8 af[2][2];
            #pragma unroll
            for (int m2 = 0; m2 < 2; ++m2)
                #pragma unroll
                for (int ks = 0; ks < 2; ++ks)
                    af[m2][ks] = *(const bf16x8*)(sh + buf*32768 + (arow + (6+m2)*16)*128 + ch[ks]);
            __builtin_amdgcn_s_setprio(1);
            #pragma unroll
            for (int m2 = 0; m2 < 2; ++m2)
                #pragma unroll
                for (int nf = 0; nf < 4; ++nf)
                    #pragma unroll
                    for (int ks = 0; ks < 2; ++ks)
                        acc[6+m2][nf] = __builtin_amdgcn_mfma_f32_16x16x32_bf16(af[m2][ks], bfr[nf][ks], acc[6+m2][nf], 0,0,0);
            __builtin_amdgcn_s_setprio(0);
        }
    }
    asm volatile("s_waitcnt vmcnt(0)" ::: "memory");
    wgbar();

    // ---- epilogue: bias + GELU -> Ct(256x256 bf16) -> coalesced store ----
    unsigned short* Ct = (unsigned short*)sh;
    const int r4 = (lane >> 4) * 4;
    const int cc = lane & 15;
    #pragma unroll
    for (int nf = 0; nf < 4; ++nf){
        const int col = wc*64 + nf*16 + cc;
        const float bv = bias[n0 + col];
        #pragma unroll
        for (int mf = 0; mf < 8; ++mf)
            #pragma unroll
            for (int r = 0; r < 4; ++r){
                const int row = wr*128 + mf*16 + r4 + r;
                Ct[row*256 + col] = f2bf(geluf(acc[mf][nf][r] + bv));
            }
    }
    __syncthreads();
    #pragma unroll
    for (int p = 0; p < 16; ++p){
        const int uidx = p*512 + tid;
        const int row = uidx >> 5;
        const int cu  = uidx & 31;
        *(u16x8*)(out + (size_t)(m0 + row)*N + n0 + cu*8) = *(const u16x8*)(Ct + row*256 + cu*8);
    }
}

// =================== 256x128 2-phase GEMM (from r7) =======================
#define G_GELU_BF16 0
#define G_BF16_RESID 1
#define G_GATED_BF16 2

template<int EPI, int MOE, int INDIRECT>
__global__ void __launch_bounds__(512, 2)
gemm256(const unsigned short* __restrict__ A, const unsigned short* __restrict__ BtG,
        const float* __restrict__ biasG, const unsigned short* __restrict__ resid,
        const int* __restrict__ tok, const int* __restrict__ offs,
        int wstride, int bstride, const float* __restrict__ gslot,
        unsigned short* __restrict__ out, int NB, int N, int K)
{
    __shared__ __align__(16) char sh[147456];
    const int nwg = gridDim.x;
    const int wg  = xcd_swizzle(blockIdx.x, nwg);
    const int bn  = wg % NB;
    const int bm  = wg / NB;
    const int m0  = bm * 256;

    const unsigned short* Bt = BtG;
    const float* bias = biasG;
    if (MOE){
        if (m0 >= offs[8]) return;
        int e = 0;
        #pragma unroll 1
        while (offs[e+1] <= m0) ++e;
        Bt   += (size_t)e * wstride;
        bias += (size_t)e * bstride;
    }

    const int tid = threadIdx.x, lane = tid & 63, wave = tid >> 6;
    const int wm = (wave >> 1) * 64;
    const int wn = (wave & 1) * 64;

    const int srow = wave*16 + (lane >> 3);
    const int scol = ((lane & 7) ^ (lane >> 3)) * 8;
    const unsigned short* aptr[2][2];
    #pragma unroll
    for (int u = 0; u < 2; ++u)
        #pragma unroll
        for (int l = 0; l < 2; ++l){
            const int r = u*128 + srow + l*8;
            const int gr = INDIRECT ? tok[m0 + r] : (m0 + r);
            aptr[u][l] = A + (size_t)gr * K + scol;
        }
    const unsigned short* bptr[2];
    #pragma unroll
    for (int l = 0; l < 2; ++l)
        bptr[l] = Bt + (size_t)(bn*128 + srow + l*8) * K + scol;
    const int sdst = wave*2048 + lane*16;

    int aoff[2], boff[2];
    #pragma unroll
    for (int ks = 0; ks < 2; ++ks){
        const int ch = (((ks<<2) + (lane>>4)) ^ (lane & 7)) << 4;
        aoff[ks] = (wm + (lane & 15))*128 + ch;
        boff[ks] = (wn + (lane & 15))*128 + ch;
    }

    f32x4 acc[4][4] = {};

    auto STAGE = [&](int buf, int kt){
        #pragma unroll
        for (int u = 0; u < 2; ++u)
            #pragma unroll
            for (int l = 0; l < 2; ++l)
                gload_lds16(aptr[u][l] + kt, sh + buf*32768 + u*16384 + l*1024 + sdst);
        #pragma unroll
        for (int l = 0; l < 2; ++l)
            gload_lds16(bptr[l] + kt, sh + 98304 + buf*16384 + l*1024 + sdst);
    };
    auto COMPUTE = [&](int buf){
        bf16x8 bfr[4][2];
        #pragma unroll
        for (int nf = 0; nf < 4; ++nf)
            #pragma unroll
            for (int ks = 0; ks < 2; ++ks)
                bfr[nf][ks] = *(const bf16x8*)(sh + 98304 + buf*16384 + nf*2048 + boff[ks]);
        #pragma unroll
        for (int mf = 0; mf < 4; ++mf){
            bf16x8 af[2];
            #pragma unroll
            for (int ks = 0; ks < 2; ++ks)
                af[ks] = *(const bf16x8*)(sh + buf*32768 + mf*2048 + aoff[ks]);
            #pragma unroll
            for (int nf = 0; nf < 4; ++nf)
                #pragma unroll
                for (int ks = 0; ks < 2; ++ks)
                    acc[mf][nf] = __builtin_amdgcn_mfma_f32_16x16x32_bf16(af[ks], bfr[nf][ks], acc[mf][nf], 0,0,0);
        }
    };

    STAGE(0, 0);
    __syncthreads();
    const int nk = K >> 6;
    int cur = 0;
    for (int i = 0; i < nk; ++i){
        if (i + 1 < nk) STAGE(cur ^ 1, (i + 1) << 6);
        COMPUTE(cur);
        __syncthreads();
        cur ^= 1;
    }

    const int r4 = (lane >> 4) * 4;
    const int cc = lane & 15;
    if (EPI == G_BF16_RESID){
        float* ctf = (float*)sh;
        #pragma unroll
        for (int nf = 0; nf < 4; ++nf){
            const float bv = bias[bn*128 + wn + nf*16 + cc];
            #pragma unroll
            for (int mf = 0; mf < 4; ++mf)
                #pragma unroll
                for (int r = 0; r < 4; ++r){
                    const int row = wm + mf*16 + r4 + r;
                    ctf[row*128 + wn + nf*16 + cc] = acc[mf][nf][r] + bv;
                }
        }
        __syncthreads();
        #pragma unroll
        for (int p = 0; p < 8; ++p){
            const int uidx = p*512 + tid;
            const int row = uidx >> 4;
            const int cu  = uidx & 15;
            const size_t gidx = (size_t)(m0 + row)*N + bn*128 + cu*8;
            u16x8 hv = *(const u16x8*)(resid + gidx);
            u16x8 o;
            #pragma unroll
            for (int j = 0; j < 8; ++j)
                o[j] = f2bf(bf2f(hv[j]) + ctf[row*128 + cu*8 + j]);
            *(u16x8*)(out + gidx) = o;
        }
    } else {
        unsigned short* ct = (unsigned short*)sh;
        #pragma unroll
        for (int nf = 0; nf < 4; ++nf){
            const float bv = bias[bn*128 + wn + nf*16 + cc];
            #pragma unroll
            for (int mf = 0; mf < 4; ++mf)
                #pragma unroll
                for (int r = 0; r < 4; ++r){
                    const int row = wm + mf*16 + r4 + r;
                    float v = acc[mf][nf][r] + bv;
                    if (EPI == G_GELU_BF16) v = geluf(v);
                    else                    v *= gslot[m0 + row];
                    ct[row*128 + wn + nf*16 + cc] = f2bf(v);
                }
        }
        __syncthreads();
        #pragma unroll
        for (int p = 0; p < 8; ++p){
            const int uidx = p*512 + tid;
            const int row = uidx >> 4;
            const int cu  = uidx & 15;
            *(u16x8*)(out + (size_t)(m0 + row)*N + bn*128 + cu*8) =
                *(const u16x8*)(ct + row*128 + cu*8);
        }
    }
}

// ---------------- LayerNorm (bf16 in, bf16 out), one wave per row ---------
__global__ void ln_kernel(const unsigned short* __restrict__ x, const float* __restrict__ w,
                          const float* __restrict__ b, unsigned short* __restrict__ out)
{
    const int lane = threadIdx.x & 63;
    const int wave = threadIdx.x >> 6;
    const int row  = blockIdx.x * 4 + wave;
    u16x8 hv = *(const u16x8*)(x + (size_t)row * D_DIM + lane*8);
    float v[8];
    #pragma unroll
    for (int j = 0; j < 8; ++j) v[j] = bf2f(hv[j]);
    float s = 0.f, s2 = 0.f;
    #pragma unroll
    for (int j = 0; j < 8; ++j){ s += v[j]; s2 += v[j]*v[j]; }
    #pragma unroll
    for (int o = 32; o > 0; o >>= 1){ s += __shfl_xor(s, o); s2 += __shfl_xor(s2, o); }
    const float mean = s * (1.0f/512.0f);
    const float var  = s2 * (1.0f/512.0f) - mean*mean;
    const float inv  = 1.0f / sqrtf(var + 1e-5f);
    const int k = lane*8;
    u16x8 o;
    #pragma unroll
    for (int j = 0; j < 8; ++j) o[j] = f2bf((v[j]-mean)*inv*w[k+j] + b[k+j]);
    *(u16x8*)(out + (size_t)row*D_DIM + k) = o;
}

// ------- Router: softmax+eps-mix+top2 (bf16 z in, no global atomics) ------
__global__ void router_kernel(const unsigned short* __restrict__ z, const float* __restrict__ rw,
                              const float* __restrict__ rb,
                              int2* __restrict__ idx2, float2* __restrict__ wts2,
                              float* __restrict__ bsums)
{
    __shared__ float ps[4][8];
    const int lane = threadIdx.x & 63;
    const int wave = threadIdx.x >> 6;
    const int row  = blockIdx.x * 4 + wave;
    u16x8 hv = *(const u16x8*)(z + (size_t)row * D_DIM + lane*8);
    float acc[8] = {0,0,0,0,0,0,0,0};
    #pragma unroll
    for (int j = 0; j < 8; ++j){
        const float zv = bf2f(hv[j]);
        const float* wr = rw + (size_t)(lane*8 + j) * 8;
        f32x4 w0 = *(const f32x4*)wr;
        f32x4 w1 = *(const f32x4*)(wr + 4);
        acc[0] += zv*w0[0]; acc[1] += zv*w0[1]; acc[2] += zv*w0[2]; acc[3] += zv*w0[3];
        acc[4] += zv*w1[0]; acc[5] += zv*w1[1]; acc[6] += zv*w1[2]; acc[7] += zv*w1[3];
    }
    #pragma unroll
    for (int o = 32; o > 0; o >>= 1){
        #pragma unroll
        for (int e = 0; e < 8; ++e) acc[e] += __shfl_xor(acc[e], o);
    }
    if (lane == 0){
        float p[8]; float mx = -1e30f;
        #pragma unroll
        for (int e=0;e<8;e++){ p[e] = acc[e] + rb[e]; mx = fmaxf(mx, p[e]); }
        float se = 0.f;
        #pragma unroll
        for (int e=0;e<8;e++){ p[e] = expf(p[e]-mx); se += p[e]; }
        const float sc = 0.9f / se;
        #pragma unroll
        for (int e=0;e<8;e++) p[e] = p[e]*sc + 0.0125f;
        int i1 = 0;
        #pragma unroll
        for (int e=1;e<8;e++) if (p[e] > p[i1]) i1 = e;
        int i2 = (i1 == 0) ? 1 : 0;
        for (int e=i2+1;e<8;e++) if (e != i1 && p[e] > p[i2]) i2 = e;
        idx2[row] = make_int2(i1, i2);
        wts2[row] = make_float2(p[i1], p[i2]);
        #pragma unroll
        for (int e=0;e<8;e++) ps[wave][e] = p[e];
    }
    __syncthreads();
    if (threadIdx.x < 8){
        bsums[blockIdx.x*8 + threadIdx.x] =
            ps[0][threadIdx.x] + ps[1][threadIdx.x] + ps[2][threadIdx.x] + ps[3][threadIdx.x];
    }
}

// ------- histogram / scan / assign (block-local, no global atomics) -------
__global__ void hist_kernel(const int2* __restrict__ idx2, int* __restrict__ blockHist){
    __shared__ int hc[8];
    if (threadIdx.x < 8) hc[threadIdx.x] = 0;
    __syncthreads();
    const int t = blockIdx.x * 256 + threadIdx.x;
    const int2 ii = idx2[t];
    atomicAdd(&hc[ii.x], 1);
    atomicAdd(&hc[ii.y], 1);
    __syncthreads();
    if (threadIdx.x < 8) blockHist[blockIdx.x*8 + threadIdx.x] = hc[threadIdx.x];
}

__global__ void scan_kernel(const int* __restrict__ blockHist, int* __restrict__ offs,
                            int* __restrict__ baseArr){
    if (threadIdx.x == 0){
        int counts[8];
        #pragma unroll
        for (int e=0;e<8;e++) counts[e] = 0;
        for (int b=0;b<NHBLK;b++)
            #pragma unroll
            for (int e=0;e<8;e++) counts[e] += blockHist[b*8+e];
        int o = 0; offs[0] = 0;
        int start[8];
        #pragma unroll
        for (int e=0;e<8;e++){ start[e] = o; o += (counts[e]+255)&~255; offs[e+1] = o; }
        for (int e=0;e<8;e++){
            int cur = start[e];
            for (int b=0;b<NHBLK;b++){ baseArr[b*8+e] = cur; cur += blockHist[b*8+e]; }
        }
    }
}

__global__ void assign_kernel(const int2* __restrict__ idx2, const float2* __restrict__ wts2,
                              const int* __restrict__ baseArr, int2* __restrict__ slot_map,
                              float* __restrict__ gslot, int* __restrict__ tok)
{
    __shared__ int cur[8];
    if (threadIdx.x < 8) cur[threadIdx.x] = 0;
    __syncthreads();
    const int t = blockIdx.x * 256 + threadIdx.x;
    const int2 ii = idx2[t];
    const float2 ww = wts2[t];
    const int r1 = atomicAdd(&cur[ii.x], 1);
    const int r2 = atomicAdd(&cur[ii.y], 1);
    const int s1 = baseArr[blockIdx.x*8 + ii.x] + r1;
    const int s2 = baseArr[blockIdx.x*8 + ii.y] + r2;
    slot_map[t] = make_int2(s1, s2);
    gslot[s1] = ww.x; gslot[s2] = ww.y;
    tok[s1] = t; tok[s2] = t;
}

// ---------------- aux loss ------------------------------------------------
__global__ void aux_kernel(const float* __restrict__ bsums, float* __restrict__ out_aux)
{
    __shared__ float part[256];
    const int t = threadIdx.x;
    const int e = t & 7, chunk = t >> 3;
    float s = 0.f;
    for (int blk = chunk*128; blk < chunk*128 + 128; ++blk) s += bsums[blk*8 + e];
    part[t] = s;
    __syncthreads();
    if (t < 8){
        float tot = 0.f;
        for (int c = 0; c < 32; ++c) tot += part[c*8 + t];
        part[t] = tot;
    }
    __syncthreads();
    if (t == 0){
        float aux = 0.f;
        for (int e2 = 0; e2 < 8; ++e2){
            float load = part[e2] * (1.0f/16384.0f);
            aux += load * logf(load * 8.0f + 1e-9f);
        }
        out_aux[0] = aux / 2.0794415416798357f;
    }
}

// -------- head: z = h + eo[s1] + eo[s2]; LN; dot --------------------------
__global__ void head_kernel(const unsigned short* __restrict__ h, const unsigned short* __restrict__ eog,
                            const int2* __restrict__ slot_map,
                            const float* __restrict__ w, const float* __restrict__ b,
                            const float* __restrict__ hw, const float* __restrict__ hb,
                            float* __restrict__ out)
{
    const int lane = threadIdx.x & 63;
    const int wave = threadIdx.x >> 6;
    const int row  = blockIdx.x * 4 + wave;
    const int2 sm = slot_map[row];
    u16x8 hv = *(const u16x8*)(h + (size_t)row * D_DIM + lane*8);
    u16x8 e1 = *(const u16x8*)(eog + (size_t)sm.x * D_DIM + lane*8);
    u16x8 e2 = *(const u16x8*)(eog + (size_t)sm.y * D_DIM + lane*8);
    float v[8];
    #pragma unroll
    for (int j=0;j<8;j++) v[j] = bf2f(hv[j]) + bf2f(e1[j]) + bf2f(e2[j]);
    float s = 0.f, s2 = 0.f;
    #pragma unroll
    for (int j=0;j<8;j++){ s += v[j]; s2 += v[j]*v[j]; }
    #pragma unroll
    for (int o = 32; o > 0; o >>= 1){ s += __shfl_xor(s, o); s2 += __shfl_xor(s2, o); }
    const float mean = s * (1.0f/512.0f);
    const float var  = s2 * (1.0f/512.0f) - mean*mean;
    const float inv  = 1.0f / sqrtf(var + 1e-5f);
    const int k = lane*8;
    float dot = 0.f;
    #pragma unroll
    for (int j=0;j<8;j++) dot += ((v[j]-mean)*inv*w[k+j] + b[k+j]) * hw[k+j];
    #pragma unroll
    for (int o = 32; o > 0; o >>= 1) dot += __shfl_xor(dot, o);
    if (lane == 0) out[row] = dot + hb[0];
}

// ===========================================================================
extern "C" void kernel_launch(void* const* d_in, const int* in_sizes, int n_in,
                              void* d_out, int out_size, void* d_ws, size_t ws_size,
                              hipStream_t stream)
{
    (void)in_sizes; (void)n_in; (void)out_size; (void)ws_size;
    const float* x         = (const float*)d_in[0];
    const float* embed_w   = (const float*)d_in[1];
    const float* embed_b   = (const float*)d_in[2];
    const float* ln1_w     = (const float*)d_in[3];
    const float* ln1_b     = (const float*)d_in[4];
    const float* inproj_w  = (const float*)d_in[5];
    const float* inproj_b  = (const float*)d_in[6];
    const float* outproj_w = (const float*)d_in[7];
    const float* outproj_b = (const float*)d_in[8];
    const float* ln2_w     = (const float*)d_in[9];
    const float* ln2_b     = (const float*)d_in[10];
    const float* ffn_w1    = (const float*)d_in[11];
    const float* ffn_b1    = (const float*)d_in[12];
    const float* ffn_w2    = (const float*)d_in[13];
    const float* ffn_b2    = (const float*)d_in[14];
    const float* router_w  = (const float*)d_in[15];
    const float* router_b  = (const float*)d_in[16];
    const float* exp_w1    = (const float*)d_in[17];
    const float* exp_b1    = (const float*)d_in[18];
    const float* exp_w2    = (const float*)d_in[19];
    const float* exp_b2    = (const float*)d_in[20];
    const float* head_ln_w = (const float*)d_in[21];
    const float* head_ln_b = (const float*)d_in[22];
    const float* head_w    = (const float*)d_in[23];
    const float* head_b    = (const float*)d_in[24];

    char* ws = (char*)d_ws;
    unsigned short* xbf   = (unsigned short*)(ws + 0);
    unsigned short* ebf   = (unsigned short*)(ws + 4194304);
    unsigned short* wobf  = (unsigned short*)(ws + 4325376);
    unsigned short* wvtbf = (unsigned short*)(ws + 5898240);
    unsigned short* wfold = (unsigned short*)(ws + 7471104);
    unsigned short* w1t   = (unsigned short*)(ws + 9043968);
    unsigned short* w2t   = (unsigned short*)(ws + 15335424);
    unsigned short* e1t   = (unsigned short*)(ws + 21626880);
    unsigned short* e2t   = (unsigned short*)(ws + 23724032);
    unsigned short* h     = (unsigned short*)(ws + 25821184);
    unsigned short* gbf   = (unsigned short*)(ws + 42598400);
    unsigned short* ubf   = (unsigned short*)(ws + 59375616);
    unsigned short* hmidg = ubf;
    unsigned short* eog   = (unsigned short*)(ws + 77201408);
    char* MISC = ws + 126484480;
    int*    offs     = (int*)(MISC + 0);
    float*  zbias    = (float*)(MISC + 256);
    float*  bfold    = (float*)(MISC + 2304);
    int2*   idx2     = (int2*)(MISC + 8448);
    float2* wts2     = (float2*)(MISC + 139520);
    int2*   slot_map = (int2*)(MISC + 270592);
    float*  gslot    = (float*)(MISC + 401664);
    int*    tok      = (int*)(MISC + 544768);
    float*  bsums    = (float*)(MISC + 684032);
    int*    blockHist= (int*)(MISC + 815104);
    int*    baseArr  = (int*)(MISC + 817152);
    float* out = (float*)d_out;

    zero_kernel<<<(MAXSLOT + 255)/256, 256, 0, stream>>>((int*)zbias, 512, tok, MAXSLOT);

    ConvArgs ca;
    ca.seg[0] = { x, xbf, B_TOK*IN_DIM/4 };
    ca.seg[1] = { outproj_w, wobf, DEPTH*D_DIM*D_DIM/4 };
    convert_kernel<<<1024, 256, 0, stream>>>(ca);

    TArgs ta;
    int tcur = 0, ti = 0;
    ta.seg[ti] = { embed_w, ebf, IN_DIM, D_DIM, tcur };
    tcur += (IN_DIM/32)*(D_DIM/32); ++ti;
    for (int l = 0; l < DEPTH; ++l){
        ta.seg[ti] = { ffn_w1 + (size_t)l*D_DIM*FF_DIM, w1t + (size_t)l*FF_DIM*D_DIM, D_DIM, FF_DIM, tcur };
        tcur += (D_DIM/32)*(FF_DIM/32); ++ti;
    }
    for (int l = 0; l < DEPTH; ++l){
        ta.seg[ti] = { ffn_w2 + (size_t)l*FF_DIM*D_DIM, w2t + (size_t)l*D_DIM*FF_DIM, FF_DIM, D_DIM, tcur };
        tcur += (FF_DIM/32)*(D_DIM/32); ++ti;
    }
    for (int e = 0; e < NEXP; ++e){
        ta.seg[ti] = { exp_w1 + (size_t)e*D_DIM*EH_DIM, e1t + (size_t)e*EH_DIM*D_DIM, D_DIM, EH_DIM, tcur };
        tcur += (D_DIM/32)*(EH_DIM/32); ++ti;
    }
    for (int e = 0; e < NEXP; ++e){
        ta.seg[ti] = { exp_w2 + (size_t)e*EH_DIM*D_DIM, e2t + (size_t)e*D_DIM*EH_DIM, EH_DIM, D_DIM, tcur };
        tcur += (EH_DIM/32)*(D_DIM/32); ++ti;
    }
    for (int l = 0; l < DEPTH; ++l){
        ta.seg[ti] = { inproj_w + (size_t)l*3*D_DIM*D_DIM + 2*D_DIM*D_DIM,
                       wvtbf + (size_t)l*D_DIM*D_DIM, D_DIM, D_DIM, tcur };
        tcur += (D_DIM/32)*(D_DIM/32); ++ti;
    }
    transpose_kernel<<<tcur, 256, 0, stream>>>(ta);

    foldb_kernel<<<DEPTH, D_DIM, 0, stream>>>(outproj_w, outproj_b, inproj_b, bfold);

    for (int l = 0; l < DEPTH; ++l){
        gemm_bt<<<16, 256, 0, stream>>>(
            wobf + (size_t)l*D_DIM*D_DIM, wvtbf + (size_t)l*D_DIM*D_DIM,
            zbias, wfold + (size_t)l*D_DIM*D_DIM, 4, D_DIM, D_DIM);
    }

    gemm_bt<<<(D_DIM/128)*(B_TOK/128), 256, 0, stream>>>(
        xbf, ebf, embed_b, h, D_DIM/128, D_DIM, IN_DIM);

    for (int l = 0; l < DEPTH; ++l){
        ln_kernel<<<B_TOK/4, 256, 0, stream>>>(h, ln1_w + l*D_DIM, ln1_b + l*D_DIM, gbf);
        gemm256<G_BF16_RESID,0,0><<<(B_TOK/256)*(D_DIM/128), 512, 0, stream>>>(
            gbf, wfold + (size_t)l*D_DIM*D_DIM, bfold + l*D_DIM, h,
            nullptr, nullptr, 0, 0, nullptr, h, D_DIM/128, D_DIM, D_DIM);
        ln_kernel<<<B_TOK/4, 256, 0, stream>>>(h, ln2_w + l*D_DIM, ln2_b + l*D_DIM, gbf);
        gemm256sq<<<(B_TOK/256)*(FF_DIM/256), 512, 0, stream>>>(
            gbf, w1t + (size_t)l*FF_DIM*D_DIM, ffn_b1 + l*FF_DIM, ubf, FF_DIM/256, FF_DIM, D_DIM);
        gemm256<G_BF16_RESID,0,0><<<(B_TOK/256)*(D_DIM/128), 512, 0, stream>>>(
            ubf, w2t + (size_t)l*D_DIM*FF_DIM, ffn_b2 + l*D_DIM, h,
            nullptr, nullptr, 0, 0, nullptr, h, D_DIM/128, D_DIM, FF_DIM);
    }

    router_kernel<<<B_TOK/4, 256, 0, stream>>>(h, router_w, router_b, idx2, wts2, bsums);
    aux_kernel<<<1, 256, 0, stream>>>(bsums, out + B_TOK);
    hist_kernel<<<NHBLK, 256, 0, stream>>>(idx2, blockHist);
    scan_kernel<<<1, 64, 0, stream>>>(blockHist, offs, baseArr);
    assign_kernel<<<B_TOK/256, 256, 0, stream>>>(idx2, wts2, baseArr, slot_map, gslot, tok);

    gemm256<G_GELU_BF16,1,1><<<MAXT256*(EH_DIM/128), 512, 0, stream>>>(
        h, e1t, exp_b1, nullptr, tok, offs, EH_DIM*D_DIM, EH_DIM, nullptr,
        hmidg, EH_DIM/128, EH_DIM, D_DIM);
    gemm256<G_GATED_BF16,1,0><<<MAXT256*(D_DIM/128), 512, 0, stream>>>(
        hmidg, e2t, exp_b2, nullptr, nullptr, offs, D_DIM*EH_DIM, D_DIM, gslot,
        eog, D_DIM/128, D_DIM, EH_DIM);

    head_kernel<<<B_TOK/4, 256, 0, stream>>>(h, eog, slot_map, head_ln_w, head_ln_b, head_w, head_b, out);
}

// Round 9
// 570.987 us; speedup vs baseline: 2.0482x; 1.0929x over previous
//
#include <hip/hip_runtime.h>
#include <hip/hip_bf16.h>

#define B_TOK 16384
#define IN_DIM 128
#define D_DIM 512
#define DEPTH 3
#define NEXP 8
#define FF_DIM 2048
#define EH_DIM 256
#define MAXSLOT 34816
#define MAXT256 136
#define NHBLK 64

typedef __attribute__((ext_vector_type(8))) __bf16 bf16x8;
typedef __attribute__((ext_vector_type(4))) float f32x4;
typedef __attribute__((ext_vector_type(4))) unsigned short u16x4;
typedef __attribute__((ext_vector_type(8))) unsigned short u16x8;

__device__ __forceinline__ unsigned short f2bf(float f){
    unsigned int u = __float_as_uint(f);
    u += 0x7fffu + ((u >> 16) & 1u);
    return (unsigned short)(u >> 16);
}
__device__ __forceinline__ float bf2f(unsigned short u){
    return __uint_as_float(((unsigned int)u) << 16);
}
__device__ __forceinline__ float geluf(float x){
    float x2 = x * x;
    float y  = x * (0.79788456080287f + 0.03567740814183f * x2);
    y = fminf(fmaxf(y, -15.0f), 15.0f);
    float e = __expf(2.0f * y);
    float th = 1.0f - 2.0f / (e + 1.0f);
    return 0.5f * x * (1.0f + th);
}
__device__ __forceinline__ void gload_lds16(const void* g, void* l){
    __builtin_amdgcn_global_load_lds((const __attribute__((address_space(1))) unsigned int*)g,
                                     (__attribute__((address_space(3))) unsigned int*)l,
                                     16, 0, 0);
}
__device__ __forceinline__ int xcd_swizzle(int orig, int nwg){
    const int q = nwg >> 3, r = nwg & 7;
    const int xcd = orig & 7;
    const int idx = orig >> 3;
    return (xcd < r ? xcd*(q+1) : r*(q+1) + (xcd-r)*q) + idx;
}
__device__ __forceinline__ void wgbar(){
    asm volatile("" ::: "memory");
    __builtin_amdgcn_s_barrier();
    asm volatile("" ::: "memory");
}

// ---------------- zero scratch control state ------------------------------
__global__ void zero_kernel(int* a, int na, int* b, int nb){
    const int i = blockIdx.x * blockDim.x + threadIdx.x;
    if (i < na) a[i] = 0;
    if (i < nb) b[i] = 0;
}

// ---------------- fp32 -> bf16 convert ------------------------------------
struct ConvSeg { const float* src; unsigned short* dst; int n4; };
struct ConvArgs { ConvSeg seg[2]; };

__global__ void convert_kernel(ConvArgs a){
    const int stride = gridDim.x * blockDim.x;
    const int tid = blockIdx.x * blockDim.x + threadIdx.x;
    for (int s = 0; s < 2; ++s){
        const f32x4* src = (const f32x4*)a.seg[s].src;
        u16x4* dst = (u16x4*)a.seg[s].dst;
        const int n4 = a.seg[s].n4;
        for (int i = tid; i < n4; i += stride){
            f32x4 v = src[i];
            u16x4 o;
            o[0] = f2bf(v[0]); o[1] = f2bf(v[1]); o[2] = f2bf(v[2]); o[3] = f2bf(v[3]);
            dst[i] = o;
        }
    }
}

// ------------- weight transpose-convert: (K,N) fp32 -> (N,K) bf16 ---------
struct TSeg { const float* src; unsigned short* dst; int K; int N; int tileStart; };
struct TArgs { TSeg seg[26]; };

__global__ void transpose_kernel(TArgs a){
    __shared__ float t[32][33];
    const int tile = blockIdx.x;
    int s = 0;
    #pragma unroll 1
    while (s < 25 && tile >= a.seg[s+1].tileStart) ++s;
    const TSeg sg = a.seg[s];
    const int local = tile - sg.tileStart;
    const int tilesN = sg.N >> 5;
    const int k0 = (local / tilesN) << 5;
    const int n0 = (local % tilesN) << 5;
    const int tx = threadIdx.x & 31;
    const int ty = threadIdx.x >> 5;
    #pragma unroll
    for (int j = 0; j < 4; ++j)
        t[ty + j*8][tx] = sg.src[(size_t)(k0 + ty + j*8) * sg.N + n0 + tx];
    __syncthreads();
    #pragma unroll
    for (int j = 0; j < 4; ++j){
        const int n = ty + j*8;
        sg.dst[(size_t)(n0 + n) * sg.K + k0 + tx] = f2bf(t[tx][n]);
    }
}

// ------- folded attention bias: bfold = Wo@bv + bo (wave per output) ------
__global__ void foldb_kernel(const float* __restrict__ outproj_w, const float* __restrict__ outproj_b,
                             const float* __restrict__ inproj_b, float* __restrict__ bfold){
    const int wave = threadIdx.x >> 6, lane = threadIdx.x & 63;
    const int o = blockIdx.x * 4 + wave;          // 0..1535
    const int l = o >> 9, n = o & 511;
    const float* Wo = outproj_w + ((size_t)l*D_DIM + n)*D_DIM;
    const float* bv = inproj_b + l*3*D_DIM + 2*D_DIM;
    float s = 0.f;
    #pragma unroll
    for (int j = 0; j < 8; ++j) s += Wo[lane + j*64] * bv[lane + j*64];
    #pragma unroll
    for (int off = 32; off > 0; off >>= 1) s += __shfl_xor(s, off);
    if (lane == 0) bfold[o] = s + outproj_b[o];
}

// ---------------- small GEMM: 128x128, dbuf, bf16 out, layer-batched ------
__global__ void __launch_bounds__(256, 2)
gemm_bt(const unsigned short* __restrict__ A0, const unsigned short* __restrict__ Bt0,
        const float* __restrict__ bias, unsigned short* __restrict__ out0,
        int NB, int N, int K, int nper, size_t lsa, size_t lsb, size_t lsc)
{
    __shared__ unsigned short sh[32768];
    const int nwg = gridDim.x;
    int wg  = xcd_swizzle(blockIdx.x, nwg);
    const int layer = wg / nper;
    wg -= layer * nper;
    const unsigned short* A  = A0  + (size_t)layer * lsa;
    const unsigned short* Bt = Bt0 + (size_t)layer * lsb;
    unsigned short* out = out0 + (size_t)layer * lsc;
    const int bn  = wg % NB;
    const int bm  = wg / NB;

    const int tid  = threadIdx.x;
    const int lane = tid & 63;
    const int wave = tid >> 6;
    const int wm = (wave >> 1) << 6;
    const int wn = (wave & 1) << 6;

    f32x4 acc[4][4] = {};

    const unsigned short* Abase = A + (size_t)bm * 128 * K;
    const unsigned short* Bbase = Bt + (size_t)bn * 128 * K;
    const int soff = tid * 16;

    auto STAGE = [&](int b, int kt){
        char* Ab = (char*)(sh + b*16384);
        char* Bb = (char*)(sh + b*16384 + 8192);
        #pragma unroll
        for (int s = 0; s < 4; ++s){
            const int off = s*4096 + soff;
            const int row = off >> 7, colb = off & 127;
            gload_lds16((const char*)(Abase + (size_t)row*K + kt) + colb, Ab + off);
        }
        #pragma unroll
        for (int s = 0; s < 4; ++s){
            const int off = s*4096 + soff;
            const int row = off >> 7, colb = off & 127;
            gload_lds16((const char*)(Bbase + (size_t)row*K + kt) + colb, Bb + off);
        }
    };
    auto COMPUTE = [&](int b){
        const unsigned short* Ab = sh + b*16384;
        const unsigned short* Bb = sh + b*16384 + 8192;
        #pragma unroll
        for (int ks = 0; ks < 2; ++ks){
            const int k0 = ks*32 + ((lane>>4)<<3);
            bf16x8 af[4], bfr[4];
            #pragma unroll
            for (int i=0;i<4;i++) af[i]  = *(const bf16x8*)&Ab[(wm + i*16 + (lane&15))*64 + k0];
            #pragma unroll
            for (int j=0;j<4;j++) bfr[j] = *(const bf16x8*)&Bb[(wn + j*16 + (lane&15))*64 + k0];
            #pragma unroll
            for (int i=0;i<4;i++)
                #pragma unroll
                for (int j=0;j<4;j++)
                    acc[i][j] = __builtin_amdgcn_mfma_f32_16x16x32_bf16(af[i], bfr[j], acc[i][j], 0, 0, 0);
        }
    };

    STAGE(0, 0);
    __syncthreads();
    const int nk = K >> 6;
    int cur = 0;
    for (int i = 0; i < nk; ++i){
        if (i + 1 < nk) STAGE(cur ^ 1, (i + 1) << 6);
        COMPUTE(cur);
        __syncthreads();
        cur ^= 1;
    }

    const int r0 = ((lane>>4)<<2);
    const int cc = lane & 15;
    unsigned short* Ct = sh;
    float bcol[4];
    #pragma unroll
    for (int j=0;j<4;j++) bcol[j] = bias[bn*128 + wn + j*16 + cc];
    #pragma unroll
    for (int i=0;i<4;i++)
        #pragma unroll
        for (int r=0;r<4;r++){
            const int rl = wm + i*16 + r0 + r;
            #pragma unroll
            for (int j=0;j<4;j++)
                Ct[rl*128 + wn + j*16 + cc] = f2bf(acc[i][j][r] + bcol[j]);
        }
    __syncthreads();
    const int orow = tid >> 4;
    const int ocol = (tid & 15) * 8;
    #pragma unroll
    for (int p = 0; p < 8; ++p){
        const int row = p*16 + orow;
        *(u16x8*)(&out[(size_t)(bm*128 + row)*N + bn*128 + ocol]) = *(u16x8*)&Ct[row*128 + ocol];
    }
}

// ===== 256x256 m201-style 8-phase GEMM (reads-before-barrier, 2 bar/phase,
//       vmcnt(4) @ p4/p8, unit schedule derived for per-wave 128x64) =======
__global__ void __launch_bounds__(512, 2)
gemm256sq(const unsigned short* __restrict__ A, const unsigned short* __restrict__ Bt,
          const float* __restrict__ bias, unsigned short* __restrict__ out,
          int NB, int N, int K)
{
    __shared__ __align__(16) char sh[131072];   // A: slot*32768; B: 65536 + slot*32768
    const int nwg = gridDim.x;
    const int wg  = xcd_swizzle(blockIdx.x, nwg);
    const int bn  = wg % NB;
    const int bm  = wg / NB;
    const int m0  = bm * 256;
    const int n0  = bn * 256;

    const int tid = threadIdx.x, lane = tid & 63, wave = tid >> 6;
    const int wr = wave >> 2;
    const int wc = wave & 3;

    // ---- staging (unit = 128 rows x 64 cols = 16KB, 2 loads/thread) ------
    const int srow8  = tid >> 3;                        // 0..63
    const int schunk = (tid & 7) ^ (srow8 & 7);         // inverse-swizzled source chunk
    const unsigned short* Ab = A  + (size_t)m0 * K + schunk*8;
    const unsigned short* Bb = Bt + (size_t)n0 * K + schunk*8;
    const int ldst = (tid & 7) * 16;

    auto STA = [&](int slot, int half, int kt){
        #pragma unroll
        for (int l = 0; l < 2; ++l){
            const int r = half*128 + srow8 + l*64;
            gload_lds16(Ab + (size_t)r*K + kt, sh + slot*32768 + r*128 + ldst);
        }
    };
    auto STB = [&](int slot, int half, int kt){
        #pragma unroll
        for (int l = 0; l < 2; ++l){
            const int r = half*128 + srow8 + l*64;
            gload_lds16(Bb + (size_t)r*K + kt, sh + 65536 + slot*32768 + r*128 + ldst);
        }
    };

    // ---- swizzled read offsets -------------------------------------------
    int ch[2];
    #pragma unroll
    for (int ks = 0; ks < 2; ++ks)
        ch[ks] = ((((ks<<2) + (lane>>4)) ^ (lane & 7)) << 4);
    const int arow = wr*128 + (lane & 15);
    const int brow = wc*64  + (lane & 15);

    f32x4 acc[8][4] = {};
    bf16x8 bfr[4][2];

    auto PHASE = [&](int slot, int mfb, bool rb, auto&& issue, int wait){
        if (rb){
            #pragma unroll
            for (int nf = 0; nf < 4; ++nf)
                #pragma unroll
                for (int ks = 0; ks < 2; ++ks)
                    bfr[nf][ks] = *(const bf16x8*)(sh + 65536 + slot*32768 + (brow + nf*16)*128 + ch[ks]);
        }
        bf16x8 af[2][2];
        #pragma unroll
        for (int m2 = 0; m2 < 2; ++m2)
            #pragma unroll
            for (int ks = 0; ks < 2; ++ks)
                af[m2][ks] = *(const bf16x8*)(sh + slot*32768 + (arow + (mfb+m2)*16)*128 + ch[ks]);
        issue();
        if (wait == 4)      asm volatile("s_waitcnt vmcnt(4)" ::: "memory");
        else if (wait == 0) asm volatile("s_waitcnt vmcnt(0)" ::: "memory");
        wgbar();
        __builtin_amdgcn_s_setprio(1);
        #pragma unroll
        for (int m2 = 0; m2 < 2; ++m2)
            #pragma unroll
            for (int nf = 0; nf < 4; ++nf)
                #pragma unroll
                for (int ks = 0; ks < 2; ++ks)
                    acc[mfb+m2][nf] = __builtin_amdgcn_mfma_f32_16x16x32_bf16(af[m2][ks], bfr[nf][ks], acc[mfb+m2][nf], 0,0,0);
        __builtin_amdgcn_s_setprio(0);
        wgbar();
    };

    // ---- prologue: B0lo,B0hi,A0lo,A0hi, B1lo,B1hi; tile0 resident --------
    STB(0,0,0); STB(0,1,0);
    STA(0,0,0); STA(0,1,0);
    STB(1,0,64); STB(1,1,64);
    asm volatile("s_waitcnt vmcnt(4)" ::: "memory");
    wgbar();

    const int nk = K >> 6;     // even
    const int NT = nk >> 1;
    for (int it = 0; it < NT; ++it){
        const bool mp = (it + 1 < NT);
        const int k1 = (2*it + 1) << 6;
        const int k2 = (2*it + 2) << 6;
        const int k3 = (2*it + 3) << 6;
        // p1: B(slot0) + A mf0,1; issue A(t+1)lo -> slot1
        PHASE(0, 0, true,  [&]{ STA(1,0,k1); }, -1);
        // p2: mf2,3; issue A(t+1)hi + B(t+2)lo
        PHASE(0, 2, false, [&]{ STA(1,1,k1); if (mp) STB(0,0,k2); }, -1);
        // p3: mf4,5; issue B(t+2)hi
        PHASE(0, 4, false, [&]{ if (mp) STB(0,1,k2); }, -1);
        // p4: mf6,7; wait -> tile t+1 resident
        PHASE(0, 6, false, [&]{}, mp ? 4 : 0);
        // p5: B(slot1) + A mf0,1; issue A(t+2)lo
        PHASE(1, 0, true,  [&]{ if (mp) STA(0,0,k2); }, -1);
        // p6: mf2,3; issue A(t+2)hi
        PHASE(1, 2, false, [&]{ if (mp) STA(0,1,k2); }, -1);
        // p7: mf4,5; issue B(t+3)lo
        PHASE(1, 4, false, [&]{ if (mp) STB(1,0,k3); }, -1);
        // p8: mf6,7; issue B(t+3)hi; wait -> tile t+2 resident
        PHASE(1, 6, false, [&]{ if (mp) STB(1,1,k3); }, mp ? 4 : 0);
    }

    // ---- epilogue: bias + GELU -> Ct(256x256 bf16) -> coalesced store ----
    unsigned short* Ct = (unsigned short*)sh;
    const int r4 = (lane >> 4) * 4;
    const int cc = lane & 15;
    #pragma unroll
    for (int nf = 0; nf < 4; ++nf){
        const int col = wc*64 + nf*16 + cc;
        const float bv = bias[n0 + col];
        #pragma unroll
        for (int mf = 0; mf < 8; ++mf)
            #pragma unroll
            for (int r = 0; r < 4; ++r){
                const int row = wr*128 + mf*16 + r4 + r;
                Ct[row*256 + col] = f2bf(geluf(acc[mf][nf][r] + bv));
            }
    }
    __syncthreads();
    #pragma unroll
    for (int p = 0; p < 16; ++p){
        const int uidx = p*512 + tid;
        const int row = uidx >> 5;
        const int cu  = uidx & 31;
        *(u16x8*)(out + (size_t)(m0 + row)*N + n0 + cu*8) = *(const u16x8*)(Ct + row*256 + cu*8);
    }
}

// =================== 256x128 2-phase GEMM (unchanged, passing) ============
#define G_GELU_BF16 0
#define G_BF16_RESID 1
#define G_GATED_BF16 2

template<int EPI, int MOE, int INDIRECT>
__global__ void __launch_bounds__(512, 2)
gemm256(const unsigned short* __restrict__ A, const unsigned short* __restrict__ BtG,
        const float* __restrict__ biasG, const unsigned short* __restrict__ resid,
        const int* __restrict__ tok, const int* __restrict__ offs,
        int wstride, int bstride, const float* __restrict__ gslot,
        unsigned short* __restrict__ out, int NB, int N, int K)
{
    __shared__ __align__(16) char sh[147456];
    const int nwg = gridDim.x;
    const int wg  = xcd_swizzle(blockIdx.x, nwg);
    const int bn  = wg % NB;
    const int bm  = wg / NB;
    const int m0  = bm * 256;

    const unsigned short* Bt = BtG;
    const float* bias = biasG;
    if (MOE){
        if (m0 >= offs[8]) return;
        int e = 0;
        #pragma unroll 1
        while (offs[e+1] <= m0) ++e;
        Bt   += (size_t)e * wstride;
        bias += (size_t)e * bstride;
    }

    const int tid = threadIdx.x, lane = tid & 63, wave = tid >> 6;
    const int wm = (wave >> 1) * 64;
    const int wn = (wave & 1) * 64;

    const int srow = wave*16 + (lane >> 3);
    const int scol = ((lane & 7) ^ (lane >> 3)) * 8;
    const unsigned short* aptr[2][2];
    #pragma unroll
    for (int u = 0; u < 2; ++u)
        #pragma unroll
        for (int l = 0; l < 2; ++l){
            const int r = u*128 + srow + l*8;
            const int gr = INDIRECT ? tok[m0 + r] : (m0 + r);
            aptr[u][l] = A + (size_t)gr * K + scol;
        }
    const unsigned short* bptr[2];
    #pragma unroll
    for (int l = 0; l < 2; ++l)
        bptr[l] = Bt + (size_t)(bn*128 + srow + l*8) * K + scol;
    const int sdst = wave*2048 + lane*16;

    int aoff[2], boff[2];
    #pragma unroll
    for (int ks = 0; ks < 2; ++ks){
        const int ch = (((ks<<2) + (lane>>4)) ^ (lane & 7)) << 4;
        aoff[ks] = (wm + (lane & 15))*128 + ch;
        boff[ks] = (wn + (lane & 15))*128 + ch;
    }

    f32x4 acc[4][4] = {};

    auto STAGE = [&](int buf, int kt){
        #pragma unroll
        for (int u = 0; u < 2; ++u)
            #pragma unroll
            for (int l = 0; l < 2; ++l)
                gload_lds16(aptr[u][l] + kt, sh + buf*32768 + u*16384 + l*1024 + sdst);
        #pragma unroll
        for (int l = 0; l < 2; ++l)
            gload_lds16(bptr[l] + kt, sh + 98304 + buf*16384 + l*1024 + sdst);
    };
    auto COMPUTE = [&](int buf){
        bf16x8 bfr[4][2];
        #pragma unroll
        for (int nf = 0; nf < 4; ++nf)
            #pragma unroll
            for (int ks = 0; ks < 2; ++ks)
                bfr[nf][ks] = *(const bf16x8*)(sh + 98304 + buf*16384 + nf*2048 + boff[ks]);
        #pragma unroll
        for (int mf = 0; mf < 4; ++mf){
            bf16x8 af[2];
            #pragma unroll
            for (int ks = 0; ks < 2; ++ks)
                af[ks] = *(const bf16x8*)(sh + buf*32768 + mf*2048 + aoff[ks]);
            #pragma unroll
            for (int nf = 0; nf < 4; ++nf)
                #pragma unroll
                for (int ks = 0; ks < 2; ++ks)
                    acc[mf][nf] = __builtin_amdgcn_mfma_f32_16x16x32_bf16(af[ks], bfr[nf][ks], acc[mf][nf], 0,0,0);
        }
    };

    STAGE(0, 0);
    __syncthreads();
    const int nk = K >> 6;
    int cur = 0;
    for (int i = 0; i < nk; ++i){
        if (i + 1 < nk) STAGE(cur ^ 1, (i + 1) << 6);
        COMPUTE(cur);
        __syncthreads();
        cur ^= 1;
    }

    const int r4 = (lane >> 4) * 4;
    const int cc = lane & 15;
    if (EPI == G_BF16_RESID){
        float* ctf = (float*)sh;
        #pragma unroll
        for (int nf = 0; nf < 4; ++nf){
            const float bv = bias[bn*128 + wn + nf*16 + cc];
            #pragma unroll
            for (int mf = 0; mf < 4; ++mf)
                #pragma unroll
                for (int r = 0; r < 4; ++r){
                    const int row = wm + mf*16 + r4 + r;
                    ctf[row*128 + wn + nf*16 + cc] = acc[mf][nf][r] + bv;
                }
        }
        __syncthreads();
        #pragma unroll
        for (int p = 0; p < 8; ++p){
            const int uidx = p*512 + tid;
            const int row = uidx >> 4;
            const int cu  = uidx & 15;
            const size_t gidx = (size_t)(m0 + row)*N + bn*128 + cu*8;
            u16x8 hv = *(const u16x8*)(resid + gidx);
            u16x8 o;
            #pragma unroll
            for (int j = 0; j < 8; ++j)
                o[j] = f2bf(bf2f(hv[j]) + ctf[row*128 + cu*8 + j]);
            *(u16x8*)(out + gidx) = o;
        }
    } else {
        unsigned short* ct = (unsigned short*)sh;
        #pragma unroll
        for (int nf = 0; nf < 4; ++nf){
            const float bv = bias[bn*128 + wn + nf*16 + cc];
            #pragma unroll
            for (int mf = 0; mf < 4; ++mf)
                #pragma unroll
                for (int r = 0; r < 4; ++r){
                    const int row = wm + mf*16 + r4 + r;
                    float v = acc[mf][nf][r] + bv;
                    if (EPI == G_GELU_BF16) v = geluf(v);
                    else                    v *= gslot[m0 + row];
                    ct[row*128 + wn + nf*16 + cc] = f2bf(v);
                }
        }
        __syncthreads();
        #pragma unroll
        for (int p = 0; p < 8; ++p){
            const int uidx = p*512 + tid;
            const int row = uidx >> 4;
            const int cu  = uidx & 15;
            *(u16x8*)(out + (size_t)(m0 + row)*N + bn*128 + cu*8) =
                *(const u16x8*)(ct + row*128 + cu*8);
        }
    }
}

// ---------------- LayerNorm (bf16 in, bf16 out), one wave per row ---------
__global__ void ln_kernel(const unsigned short* __restrict__ x, const float* __restrict__ w,
                          const float* __restrict__ b, unsigned short* __restrict__ out)
{
    const int lane = threadIdx.x & 63;
    const int wave = threadIdx.x >> 6;
    const int row  = blockIdx.x * 4 + wave;
    u16x8 hv = *(const u16x8*)(x + (size_t)row * D_DIM + lane*8);
    float v[8];
    #pragma unroll
    for (int j = 0; j < 8; ++j) v[j] = bf2f(hv[j]);
    float s = 0.f, s2 = 0.f;
    #pragma unroll
    for (int j = 0; j < 8; ++j){ s += v[j]; s2 += v[j]*v[j]; }
    #pragma unroll
    for (int o = 32; o > 0; o >>= 1){ s += __shfl_xor(s, o); s2 += __shfl_xor(s2, o); }
    const float mean = s * (1.0f/512.0f);
    const float var  = s2 * (1.0f/512.0f) - mean*mean;
    const float inv  = 1.0f / sqrtf(var + 1e-5f);
    const int k = lane*8;
    u16x8 o;
    #pragma unroll
    for (int j = 0; j < 8; ++j) o[j] = f2bf((v[j]-mean)*inv*w[k+j] + b[k+j]);
    *(u16x8*)(out + (size_t)row*D_DIM + k) = o;
}

// ------- Router: softmax+eps-mix+top2 (bf16 z in, no global atomics) ------
__global__ void router_kernel(const unsigned short* __restrict__ z, const float* __restrict__ rw,
                              const float* __restrict__ rb,
                              int2* __restrict__ idx2, float2* __restrict__ wts2,
                              float* __restrict__ bsums)
{
    __shared__ float ps[4][8];
    const int lane = threadIdx.x & 63;
    const int wave = threadIdx.x >> 6;
    const int row  = blockIdx.x * 4 + wave;
    u16x8 hv = *(const u16x8*)(z + (size_t)row * D_DIM + lane*8);
    float acc[8] = {0,0,0,0,0,0,0,0};
    #pragma unroll
    for (int j = 0; j < 8; ++j){
        const float zv = bf2f(hv[j]);
        const float* wr = rw + (size_t)(lane*8 + j) * 8;
        f32x4 w0 = *(const f32x4*)wr;
        f32x4 w1 = *(const f32x4*)(wr + 4);
        acc[0] += zv*w0[0]; acc[1] += zv*w0[1]; acc[2] += zv*w0[2]; acc[3] += zv*w0[3];
        acc[4] += zv*w1[0]; acc[5] += zv*w1[1]; acc[6] += zv*w1[2]; acc[7] += zv*w1[3];
    }
    #pragma unroll
    for (int o = 32; o > 0; o >>= 1){
        #pragma unroll
        for (int e = 0; e < 8; ++e) acc[e] += __shfl_xor(acc[e], o);
    }
    if (lane == 0){
        float p[8]; float mx = -1e30f;
        #pragma unroll
        for (int e=0;e<8;e++){ p[e] = acc[e] + rb[e]; mx = fmaxf(mx, p[e]); }
        float se = 0.f;
        #pragma unroll
        for (int e=0;e<8;e++){ p[e] = expf(p[e]-mx); se += p[e]; }
        const float sc = 0.9f / se;
        #pragma unroll
        for (int e=0;e<8;e++) p[e] = p[e]*sc + 0.0125f;
        int i1 = 0;
        #pragma unroll
        for (int e=1;e<8;e++) if (p[e] > p[i1]) i1 = e;
        int i2 = (i1 == 0) ? 1 : 0;
        for (int e=i2+1;e<8;e++) if (e != i1 && p[e] > p[i2]) i2 = e;
        idx2[row] = make_int2(i1, i2);
        wts2[row] = make_float2(p[i1], p[i2]);
        #pragma unroll
        for (int e=0;e<8;e++) ps[wave][e] = p[e];
    }
    __syncthreads();
    if (threadIdx.x < 8){
        bsums[blockIdx.x*8 + threadIdx.x] =
            ps[0][threadIdx.x] + ps[1][threadIdx.x] + ps[2][threadIdx.x] + ps[3][threadIdx.x];
    }
}

// ------- histogram / scan / assign (block-local, no global atomics) -------
__global__ void hist_kernel(const int2* __restrict__ idx2, int* __restrict__ blockHist){
    __shared__ int hc[8];
    if (threadIdx.x < 8) hc[threadIdx.x] = 0;
    __syncthreads();
    const int t = blockIdx.x * 256 + threadIdx.x;
    const int2 ii = idx2[t];
    atomicAdd(&hc[ii.x], 1);
    atomicAdd(&hc[ii.y], 1);
    __syncthreads();
    if (threadIdx.x < 8) blockHist[blockIdx.x*8 + threadIdx.x] = hc[threadIdx.x];
}

// parallel scan: 512 threads, all LDS-resident
__global__ void scan_kernel(const int* __restrict__ blockHist, int* __restrict__ offs,
                            int* __restrict__ baseArr){
    __shared__ int hist[NHBLK*8];
    __shared__ int cnt[8];
    __shared__ int start[8];
    const int t = threadIdx.x;
    hist[t] = blockHist[t];            // 512 threads, 512 ints
    __syncthreads();
    if (t < 8){
        int c = 0;
        #pragma unroll 1
        for (int b = 0; b < NHBLK; ++b) c += hist[b*8 + t];
        cnt[t] = c;
    }
    __syncthreads();
    if (t == 0){
        int o = 0; offs[0] = 0;
        for (int e = 0; e < 8; ++e){ start[e] = o; o += (cnt[e]+255)&~255; offs[e+1] = o; }
    }
    __syncthreads();
    if (t < 8){
        int cur = start[t];
        #pragma unroll 1
        for (int b = 0; b < NHBLK; ++b){ baseArr[b*8 + t] = cur; cur += hist[b*8 + t]; }
    }
}

__global__ void assign_kernel(const int2* __restrict__ idx2, const float2* __restrict__ wts2,
                              const int* __restrict__ baseArr, int2* __restrict__ slot_map,
                              float* __restrict__ gslot, int* __restrict__ tok)
{
    __shared__ int cur[8];
    if (threadIdx.x < 8) cur[threadIdx.x] = 0;
    __syncthreads();
    const int t = blockIdx.x * 256 + threadIdx.x;
    const int2 ii = idx2[t];
    const float2 ww = wts2[t];
    const int r1 = atomicAdd(&cur[ii.x], 1);
    const int r2 = atomicAdd(&cur[ii.y], 1);
    const int s1 = baseArr[blockIdx.x*8 + ii.x] + r1;
    const int s2 = baseArr[blockIdx.x*8 + ii.y] + r2;
    slot_map[t] = make_int2(s1, s2);
    gslot[s1] = ww.x; gslot[s2] = ww.y;
    tok[s1] = t; tok[s2] = t;
}

// ---------------- aux loss ------------------------------------------------
__global__ void aux_kernel(const float* __restrict__ bsums, float* __restrict__ out_aux)
{
    __shared__ float part[256];
    const int t = threadIdx.x;
    const int e = t & 7, chunk = t >> 3;
    float s = 0.f;
    for (int blk = chunk*128; blk < chunk*128 + 128; ++blk) s += bsums[blk*8 + e];
    part[t] = s;
    __syncthreads();
    if (t < 8){
        float tot = 0.f;
        for (int c = 0; c < 32; ++c) tot += part[c*8 + t];
        part[t] = tot;
    }
    __syncthreads();
    if (t == 0){
        float aux = 0.f;
        for (int e2 = 0; e2 < 8; ++e2){
            float load = part[e2] * (1.0f/16384.0f);
            aux += load * logf(load * 8.0f + 1e-9f);
        }
        out_aux[0] = aux / 2.0794415416798357f;
    }
}

// -------- head: z = h + eo[s1] + eo[s2]; LN; dot --------------------------
__global__ void head_kernel(const unsigned short* __restrict__ h, const unsigned short* __restrict__ eog,
                            const int2* __restrict__ slot_map,
                            const float* __restrict__ w, const float* __restrict__ b,
                            const float* __restrict__ hw, const float* __restrict__ hb,
                            float* __restrict__ out)
{
    const int lane = threadIdx.x & 63;
    const int wave = threadIdx.x >> 6;
    const int row  = blockIdx.x * 4 + wave;
    const int2 sm = slot_map[row];
    u16x8 hv = *(const u16x8*)(h + (size_t)row * D_DIM + lane*8);
    u16x8 e1 = *(const u16x8*)(eog + (size_t)sm.x * D_DIM + lane*8);
    u16x8 e2 = *(const u16x8*)(eog + (size_t)sm.y * D_DIM + lane*8);
    float v[8];
    #pragma unroll
    for (int j=0;j<8;j++) v[j] = bf2f(hv[j]) + bf2f(e1[j]) + bf2f(e2[j]);
    float s = 0.f, s2 = 0.f;
    #pragma unroll
    for (int j=0;j<8;j++){ s += v[j]; s2 += v[j]*v[j]; }
    #pragma unroll
    for (int o = 32; o > 0; o >>= 1){ s += __shfl_xor(s, o); s2 += __shfl_xor(s2, o); }
    const float mean = s * (1.0f/512.0f);
    const float var  = s2 * (1.0f/512.0f) - mean*mean;
    const float inv  = 1.0f / sqrtf(var + 1e-5f);
    const int k = lane*8;
    float dot = 0.f;
    #pragma unroll
    for (int j=0;j<8;j++) dot += ((v[j]-mean)*inv*w[k+j] + b[k+j]) * hw[k+j];
    #pragma unroll
    for (int o = 32; o > 0; o >>= 1) dot += __shfl_xor(dot, o);
    if (lane == 0) out[row] = dot + hb[0];
}

// ===========================================================================
extern "C" void kernel_launch(void* const* d_in, const int* in_sizes, int n_in,
                              void* d_out, int out_size, void* d_ws, size_t ws_size,
                              hipStream_t stream)
{
    (void)in_sizes; (void)n_in; (void)out_size; (void)ws_size;
    const float* x         = (const float*)d_in[0];
    const float* embed_w   = (const float*)d_in[1];
    const float* embed_b   = (const float*)d_in[2];
    const float* ln1_w     = (const float*)d_in[3];
    const float* ln1_b     = (const float*)d_in[4];
    const float* inproj_w  = (const float*)d_in[5];
    const float* inproj_b  = (const float*)d_in[6];
    const float* outproj_w = (const float*)d_in[7];
    const float* outproj_b = (const float*)d_in[8];
    const float* ln2_w     = (const float*)d_in[9];
    const float* ln2_b     = (const float*)d_in[10];
    const float* ffn_w1    = (const float*)d_in[11];
    const float* ffn_b1    = (const float*)d_in[12];
    const float* ffn_w2    = (const float*)d_in[13];
    const float* ffn_b2    = (const float*)d_in[14];
    const float* router_w  = (const float*)d_in[15];
    const float* router_b  = (const float*)d_in[16];
    const float* exp_w1    = (const float*)d_in[17];
    const float* exp_b1    = (const float*)d_in[18];
    const float* exp_w2    = (const float*)d_in[19];
    const float* exp_b2    = (const float*)d_in[20];
    const float* head_ln_w = (const float*)d_in[21];
    const float* head_ln_b = (const float*)d_in[22];
    const float* head_w    = (const float*)d_in[23];
    const float* head_b    = (const float*)d_in[24];

    char* ws = (char*)d_ws;
    unsigned short* xbf   = (unsigned short*)(ws + 0);
    unsigned short* ebf   = (unsigned short*)(ws + 4194304);
    unsigned short* wobf  = (unsigned short*)(ws + 4325376);
    unsigned short* wvtbf = (unsigned short*)(ws + 5898240);
    unsigned short* wfold = (unsigned short*)(ws + 7471104);
    unsigned short* w1t   = (unsigned short*)(ws + 9043968);
    unsigned short* w2t   = (unsigned short*)(ws + 15335424);
    unsigned short* e1t   = (unsigned short*)(ws + 21626880);
    unsigned short* e2t   = (unsigned short*)(ws + 23724032);
    unsigned short* h     = (unsigned short*)(ws + 25821184);
    unsigned short* gbf   = (unsigned short*)(ws + 42598400);
    unsigned short* ubf   = (unsigned short*)(ws + 59375616);
    unsigned short* hmidg = ubf;
    unsigned short* eog   = (unsigned short*)(ws + 77201408);
    char* MISC = ws + 126484480;
    int*    offs     = (int*)(MISC + 0);
    float*  zbias    = (float*)(MISC + 256);
    float*  bfold    = (float*)(MISC + 2304);
    int2*   idx2     = (int2*)(MISC + 8448);
    float2* wts2     = (float2*)(MISC + 139520);
    int2*   slot_map = (int2*)(MISC + 270592);
    float*  gslot    = (float*)(MISC + 401664);
    int*    tok      = (int*)(MISC + 544768);
    float*  bsums    = (float*)(MISC + 684032);
    int*    blockHist= (int*)(MISC + 815104);
    int*    baseArr  = (int*)(MISC + 817152);
    float* out = (float*)d_out;

    zero_kernel<<<(MAXSLOT + 255)/256, 256, 0, stream>>>((int*)zbias, 512, tok, MAXSLOT);

    ConvArgs ca;
    ca.seg[0] = { x, xbf, B_TOK*IN_DIM/4 };
    ca.seg[1] = { outproj_w, wobf, DEPTH*D_DIM*D_DIM/4 };
    convert_kernel<<<1024, 256, 0, stream>>>(ca);

    TArgs ta;
    int tcur = 0, ti = 0;
    ta.seg[ti] = { embed_w, ebf, IN_DIM, D_DIM, tcur };
    tcur += (IN_DIM/32)*(D_DIM/32); ++ti;
    for (int l = 0; l < DEPTH; ++l){
        ta.seg[ti] = { ffn_w1 + (size_t)l*D_DIM*FF_DIM, w1t + (size_t)l*FF_DIM*D_DIM, D_DIM, FF_DIM, tcur };
        tcur += (D_DIM/32)*(FF_DIM/32); ++ti;
    }
    for (int l = 0; l < DEPTH; ++l){
        ta.seg[ti] = { ffn_w2 + (size_t)l*FF_DIM*D_DIM, w2t + (size_t)l*D_DIM*FF_DIM, FF_DIM, D_DIM, tcur };
        tcur += (FF_DIM/32)*(D_DIM/32); ++ti;
    }
    for (int e = 0; e < NEXP; ++e){
        ta.seg[ti] = { exp_w1 + (size_t)e*D_DIM*EH_DIM, e1t + (size_t)e*EH_DIM*D_DIM, D_DIM, EH_DIM, tcur };
        tcur += (D_DIM/32)*(EH_DIM/32); ++ti;
    }
    for (int e = 0; e < NEXP; ++e){
        ta.seg[ti] = { exp_w2 + (size_t)e*EH_DIM*D_DIM, e2t + (size_t)e*D_DIM*EH_DIM, EH_DIM, D_DIM, tcur };
        tcur += (EH_DIM/32)*(D_DIM/32); ++ti;
    }
    for (int l = 0; l < DEPTH; ++l){
        ta.seg[ti] = { inproj_w + (size_t)l*3*D_DIM*D_DIM + 2*D_DIM*D_DIM,
                       wvtbf + (size_t)l*D_DIM*D_DIM, D_DIM, D_DIM, tcur };
        tcur += (D_DIM/32)*(D_DIM/32); ++ti;
    }
    transpose_kernel<<<tcur, 256, 0, stream>>>(ta);

    foldb_kernel<<<DEPTH*D_DIM/4, 256, 0, stream>>>(outproj_w, outproj_b, inproj_b, bfold);

    // fold GEMMs for all 3 layers in one launch (layer-strided)
    gemm_bt<<<48, 256, 0, stream>>>(
        wobf, wvtbf, zbias, wfold, 4, D_DIM, D_DIM,
        16, (size_t)D_DIM*D_DIM, (size_t)D_DIM*D_DIM, (size_t)D_DIM*D_DIM);

    gemm_bt<<<(D_DIM/128)*(B_TOK/128), 256, 0, stream>>>(
        xbf, ebf, embed_b, h, D_DIM/128, D_DIM, IN_DIM,
        (D_DIM/128)*(B_TOK/128), 0, 0, 0);

    for (int l = 0; l < DEPTH; ++l){
        ln_kernel<<<B_TOK/4, 256, 0, stream>>>(h, ln1_w + l*D_DIM, ln1_b + l*D_DIM, gbf);
        gemm256<G_BF16_RESID,0,0><<<(B_TOK/256)*(D_DIM/128), 512, 0, stream>>>(
            gbf, wfold + (size_t)l*D_DIM*D_DIM, bfold + l*D_DIM, h,
            nullptr, nullptr, 0, 0, nullptr, h, D_DIM/128, D_DIM, D_DIM);
        ln_kernel<<<B_TOK/4, 256, 0, stream>>>(h, ln2_w + l*D_DIM, ln2_b + l*D_DIM, gbf);
        gemm256sq<<<(B_TOK/256)*(FF_DIM/256), 512, 0, stream>>>(
            gbf, w1t + (size_t)l*FF_DIM*D_DIM, ffn_b1 + l*FF_DIM, ubf, FF_DIM/256, FF_DIM, D_DIM);
        gemm256<G_BF16_RESID,0,0><<<(B_TOK/256)*(D_DIM/128), 512, 0, stream>>>(
            ubf, w2t + (size_t)l*D_DIM*FF_DIM, ffn_b2 + l*D_DIM, h,
            nullptr, nullptr, 0, 0, nullptr, h, D_DIM/128, D_DIM, FF_DIM);
    }

    router_kernel<<<B_TOK/4, 256, 0, stream>>>(h, router_w, router_b, idx2, wts2, bsums);
    aux_kernel<<<1, 256, 0, stream>>>(bsums, out + B_TOK);
    hist_kernel<<<NHBLK, 256, 0, stream>>>(idx2, blockHist);
    scan_kernel<<<1, 512, 0, stream>>>(blockHist, offs, baseArr);
    assign_kernel<<<B_TOK/256, 256, 0, stream>>>(idx2, wts2, baseArr, slot_map, gslot, tok);

    gemm256<G_GELU_BF16,1,1><<<MAXT256*(EH_DIM/128), 512, 0, stream>>>(
        h, e1t, exp_b1, nullptr, tok, offs, EH_DIM*D_DIM, EH_DIM, nullptr,
        hmidg, EH_DIM/128, EH_DIM, D_DIM);
    gemm256<G_GATED_BF16,1,0><<<MAXT256*(D_DIM/128), 512, 0, stream>>>(
        hmidg, e2t, exp_b2, nullptr, nullptr, offs, D_DIM*EH_DIM, D_DIM, gslot,
        eog, D_DIM/128, D_DIM, EH_DIM);

    head_kernel<<<B_TOK/4, 256, 0, stream>>>(h, eog, slot_map, head_ln_w, head_ln_b, head_w, head_b, out);
}